// Round 10
// baseline (616.433 us; speedup 1.0000x reference)
//
#include <hip/hip_runtime.h>
#include <hip/hip_bf16.h>
#include <stdint.h>
#include <math.h>

#define NN   100000
#define EE   3200000
#define FIN  5
#define SHD  32
#define NH   8
#define TCH  21
#define TRH  22
#define SEQL 14

// frontier / filtered-edge capacities (round-10: CSR trio eliminated).
// E[deg]=32 (Binomial(3.2M,1e-5)); caps are >=8x the mean+tails.
#define ECA   1024     // in-edges of tgt (layer-3 row)
#define ECL1  1024     // F1 node list (deg(tgt)+1, dedup)
#define ECB   16384    // edges into F1 (layer-2 aggregation)
#define ECL2  8192     // F2 node list (dedup)
#define ECC   131072   // edges into F2 (layer-1 aggregation)

typedef __hip_bfloat16 bf16;
typedef __attribute__((ext_vector_type(2))) float f32x2;

__device__ __forceinline__ float b2f(bf16 v) { return __bfloat162float(v); }
__device__ __forceinline__ float sigm(float x) { return 1.f / (1.f + __expf(-x)); }
__device__ __forceinline__ float ldw(const void* p, int i, int f) {
    return f ? ((const float*)p)[i] : __bfloat162float(((const bf16*)p)[i]);
}
__device__ __forceinline__ float relu_nan(float v) {
    return (v == v) ? ((v > 0.f) ? v : 0.f) : v;
}
__device__ __forceinline__ unsigned short f2b(float v) {
    bf16 b = __float2bfloat16(v);
    return *reinterpret_cast<unsigned short*>(&b);
}
__device__ __forceinline__ float cvf(float v) { return v; }
__device__ __forceinline__ float cvf(bf16 v) { return __bfloat162float(v); }
__device__ __forceinline__ void cp(float* dst, const void* src, int n,
                                   int t0, int stride, int f) {
    if (f) {
        const float* s = (const float*)src;
        for (int i = t0; i < n; i += stride) dst[i] = s[i];
    } else {
        const bf16* s = (const bf16*)src;
        for (int i = t0; i < n; i += stride) dst[i] = b2f(s[i]);
    }
}

// ---- dtype detect + f32 param pre-convert (identifier-named, 1 wave) ------
__global__ void PatternAwareSTGAT_94489281309_kernel(const unsigned int* xw, int* flag,
        const void* as0, const void* b0, const void* as1, const void* b1,
        const void* as2, const void* b2, float* prm) {
    int tid = threadIdx.x;   // 64
    int sane = 0;
    for (int i = 0; i < 64; i++) {
        unsigned int lo = xw[i] & 0xFFFFu;
        int e = (int)((lo >> 7) & 0xFF);
        if (e >= 110 && e <= 135) sane++;
    }
    int f = (sane >= 32) ? 0 : 1;
    if (tid == 0) flag[0] = f;
    const void* asp[3] = {as0, as1, as2};
    const void* bp[3]  = {b0, b1, b2};
    for (int l = 0; l < 3; l++)
        prm[l * 64 + tid] = (tid < 32) ? ldw(asp[l], tid, f) : ldw(bp[l], tid - 32, f);
}

// ---------------- Filtered edge scans (round-10) ----------------------------
// Only ~1.2k nodes' in-edge lists are ever consumed (round-9 cone pruning),
// so the full-graph CSR counting sort (3 kernels, ~115MB traffic) is replaced
// by 3 streaming scans of the dst array with L2-resident membership maps.
// Within-node edge order is atomic-append (nondeterministic) — same property
// as the old atomic counting sort, tolerated for 9 rounds (absmax 0.0).
__global__ __launch_bounds__(256) void k_scanA(const int* __restrict__ ei,
                                               const int* __restrict__ tgtp,
                                               int* __restrict__ eA, int* __restrict__ cA) {
    int tgt = tgtp[0];
    for (int e = blockIdx.x * 256 + threadIdx.x; e < EE; e += gridDim.x * 256) {
        int d = __builtin_nontemporal_load(ei + EE + e);
        if (d == tgt) {
            int p = atomicAdd(cA, 1);
            if (p < ECA) eA[p] = __builtin_nontemporal_load(ei + e);
        }
    }
}

// build F1 list (dedup) + map1; also seed l3 = {tgt}
__global__ void k_mark1(const int* __restrict__ eA, const int* __restrict__ cA,
                        const int* __restrict__ tgtp,
                        int* __restrict__ map1, int* __restrict__ l1, int* __restrict__ c1,
                        int* __restrict__ l3, int* __restrict__ c3) {
    int n = cA[0]; if (n > ECA) n = ECA;
    for (int i = threadIdx.x; i < n; i += 256) {
        int s = eA[i];
        if (atomicExch(&map1[s], 1) == 0) {
            int p = atomicAdd(c1, 1);
            if (p < ECL1) l1[p] = s;
        }
    }
    if (threadIdx.x == 0) {
        int t = tgtp[0];
        if (atomicExch(&map1[t], 1) == 0) {
            int p = atomicAdd(c1, 1);
            if (p < ECL1) l1[p] = t;
        }
        l3[0] = t; c3[0] = 1;
    }
}

// filter edges whose dst is in map; store pairs + per-dst degree
__global__ __launch_bounds__(256) void k_scanF(const int* __restrict__ ei,
                                               const int* __restrict__ map,
                                               int* __restrict__ es, int* __restrict__ edd,
                                               int* __restrict__ cnt, int* __restrict__ deg,
                                               int cap) {
    for (int e = blockIdx.x * 256 + threadIdx.x; e < EE; e += gridDim.x * 256) {
        int d = __builtin_nontemporal_load(ei + EE + e);
        if (map[d]) {
            int p = atomicAdd(cnt, 1);
            if (p < cap) {
                es[p] = __builtin_nontemporal_load(ei + e);
                edd[p] = d;
                atomicAdd(&deg[d], 1);
            }
        }
    }
}

// exclusive prefix of deg over list -> rstart (LDS-chunked, 1 block);
// optionally seed next-level node set (mapN/lN/cN) with this list.
__global__ void k_prefix(const int* __restrict__ list, const int* __restrict__ cp, int cap,
                         const int* __restrict__ deg, int* __restrict__ rstart,
                         int* __restrict__ mapN, int* __restrict__ lN, int* __restrict__ cN,
                         int capN) {
    __shared__ int sd[256];
    __shared__ int sbase;
    int n = cp[0]; if (n > cap) n = cap;
    if (threadIdx.x == 0) sbase = 0;
    __syncthreads();
    for (int b = 0; b < n; b += 256) {
        int i = b + threadIdx.x;
        int nd = (i < n) ? list[i] : -1;
        sd[threadIdx.x] = (nd >= 0) ? deg[nd] : 0;
        __syncthreads();
        if (threadIdx.x == 0) {
            int acc = sbase;
            for (int j = 0; j < 256; j++) { int v = sd[j]; sd[j] = acc; acc += v; }
            sbase = acc;
        }
        __syncthreads();
        if (nd >= 0) rstart[nd] = sd[threadIdx.x];
        __syncthreads();
    }
    if (mapN) {
        for (int i = threadIdx.x; i < n; i += 256) {
            int nd = list[i];
            if (atomicExch(&mapN[nd], 1) == 0) {
                int p = atomicAdd(cN, 1);
                if (p < capN) lN[p] = nd;
            }
        }
    }
}

// scatter filtered pairs into per-dst rows; optionally collect srcs into
// next-level node set (dedup).
__global__ __launch_bounds__(256) void k_scatter(const int* __restrict__ es,
                                                 const int* __restrict__ edd,
                                                 const int* __restrict__ cp, int cap,
                                                 const int* __restrict__ rstart,
                                                 int* __restrict__ fill, int* __restrict__ csr,
                                                 int* __restrict__ mapN, int* __restrict__ lN,
                                                 int* __restrict__ cN, int capN) {
    int m = cp[0]; if (m > cap) m = cap;
    for (int i = blockIdx.x * 256 + threadIdx.x; i < m; i += gridDim.x * 256) {
        int s = es[i], d = edd[i];
        int p = atomicAdd(&fill[d], 1);
        csr[rstart[d] + p] = s;
        if (mapN) {
            if (atomicExch(&mapN[s], 1) == 0) {
                int q = atomicAdd(cN, 1);
                if (q < capN) lN[q] = s;
            }
        }
    }
}

// ---------------- GAT transform (layer 0: raw input, DIN=5, full N) ---------
__global__ void k_transform0(const void* x, const void* W, const void* ad_,
                             const int* flag, unsigned short* hWb, float* ed) {
    __shared__ float sW[FIN * SHD];
    __shared__ float sad[SHD];
    int tid = threadIdx.x;
    int f = flag[0];
    cp(sW, W, FIN * SHD, tid, 256, f);
    if (tid >= 192 && tid < 192 + SHD) sad[tid - 192] = ldw(ad_, tid - 192, f);
    __syncthreads();
    int n = blockIdx.x * 256 + tid;
    if (n >= NN) return;
    float xr[FIN];
    if (f) {
        const float* xp = (const float*)x + (size_t)n * FIN;
        for (int k = 0; k < FIN; k++) xr[k] = xp[k];
    } else {
        const bf16* xp = (const bf16*)x + (size_t)n * FIN;
        for (int k = 0; k < FIN; k++) xr[k] = b2f(xp[k]);
    }
    float o[SHD];
    for (int j = 0; j < SHD; j++) o[j] = 0.f;
    for (int k = 0; k < FIN; k++) {
        float xv = xr[k];
        for (int j = 0; j < SHD; j++) o[j] += xv * sW[k * SHD + j];
    }
    ushort4* row = (ushort4*)(hWb + (size_t)n * SHD);
    for (int q = 0; q < 8; q++) {
        ushort4 v; v.x = f2b(o[q*4]); v.y = f2b(o[q*4+1]); v.z = f2b(o[q*4+2]); v.w = f2b(o[q*4+3]);
        row[q] = v;
    }
    for (int h = 0; h < NH; h++) {
        float e2 = 0.f;
        for (int c = 0; c < 4; c++) e2 += o[h * 4 + c] * sad[h * 4 + c];
        ed[(size_t)n * NH + h] = e2;
    }
}

// ---------------- GAT transform (layers 2/3: list-driven, DIN=32) -----------
__global__ void k_transform1(const int* __restrict__ list, const int* __restrict__ cntp,
                             int cap,
                             const float* x, const void* W, const void* ad_,
                             const int* flag, unsigned short* hWb, float* ed) {
    __shared__ float sW[SHD * SHD];
    __shared__ float sad[SHD];
    int tid = threadIdx.x;
    int f = flag[0];
    cp(sW, W, SHD * SHD, tid, 256, f);
    if (tid >= 192 && tid < 192 + SHD) sad[tid - 192] = ldw(ad_, tid - 192, f);
    __syncthreads();
    int cnt = cntp[0]; if (cnt > cap) cnt = cap;
    int ii = blockIdx.x * 256 + tid;
    if (ii >= cnt) return;
    int n = list[ii];
    float xr[SHD];
    const float4* xp4 = (const float4*)(x + (size_t)n * SHD);
#pragma unroll
    for (int q = 0; q < 8; q++) {
        float4 v = xp4[q];
        xr[q*4] = v.x; xr[q*4+1] = v.y; xr[q*4+2] = v.z; xr[q*4+3] = v.w;
    }
    float o[SHD];
    for (int j = 0; j < SHD; j++) o[j] = 0.f;
    for (int k = 0; k < SHD; k++) {
        float xv = xr[k];
        for (int j = 0; j < SHD; j++) o[j] += xv * sW[k * SHD + j];
    }
    ushort4* row = (ushort4*)(hWb + (size_t)n * SHD);
    for (int q = 0; q < 8; q++) {
        ushort4 v; v.x = f2b(o[q*4]); v.y = f2b(o[q*4+1]); v.z = f2b(o[q*4+2]); v.w = f2b(o[q*4+3]);
        row[q] = v;
    }
    for (int h = 0; h < NH; h++) {
        float e2 = 0.f;
        for (int c = 0; c < 4; c++) e2 += o[h * 4 + c] * sad[h * 4 + c];
        ed[(size_t)n * NH + h] = e2;
    }
}

// ------- GAT aggregation: list-driven, 2 entries/wave, 6-deep pipeline ------
// ovr != null: single-row mode (base=0, deg=*ovr) for the layer-3 tgt row.
__global__ void k_aggregate(const int* __restrict__ list, const int* __restrict__ cntp,
                            int cap,
                            const int* __restrict__ rstart, const int* __restrict__ rdeg,
                            const int* __restrict__ csr,
                            const int* __restrict__ ovr, int ovrCap,
                            const unsigned short* __restrict__ hWb,
                            const float* __restrict__ ed,
                            const float* __restrict__ prm,
                            float* __restrict__ out) {
    int gid = blockIdx.x * 256 + threadIdx.x;
    int lane = threadIdx.x & 63;
    int cnt = cntp[0]; if (cnt > cap) cnt = cap;
    int idx = (gid >> 6) * 2 + (lane >> 5);
    if (idx >= cnt) return;
    int n = list[idx];
    int l32 = lane & 31;
    int h = l32 & 7, k = l32 >> 3;
    float4 asv = *(const float4*)(prm + h * 4);
    float ednh = ed[(size_t)n * NH + h];
    int base, deg;
    if (ovr) { base = 0; deg = ovr[0]; if (deg > ovrCap) deg = ovrCap; }
    else     { base = rstart[n]; deg = rdeg[n]; }
    float den = 0.f;
    f32x2 acc01 = {0.f, 0.f}, acc23 = {0.f, 0.f};
    int t = k;
    int s0 = -1, s1 = -1, s2 = -1, s3 = -1, s4 = -1, s5 = -1;
    if (t <= deg)      s0 = (t == 0) ? n : __builtin_nontemporal_load(csr + base + t - 1);
    if (t + 4 <= deg)  s1 = __builtin_nontemporal_load(csr + base + t + 3);
    if (t + 8 <= deg)  s2 = __builtin_nontemporal_load(csr + base + t + 7);
    if (t + 12 <= deg) s3 = __builtin_nontemporal_load(csr + base + t + 11);
    if (t + 16 <= deg) s4 = __builtin_nontemporal_load(csr + base + t + 15);
    if (t + 20 <= deg) s5 = __builtin_nontemporal_load(csr + base + t + 19);
    while (s0 >= 0) {
        uint2 hv0 = *(const uint2*)(hWb + (size_t)s0 * SHD + h * 4);
        bool b1 = (s1 >= 0), b2 = (s2 >= 0), b3 = (s3 >= 0), b4 = (s4 >= 0), b5 = (s5 >= 0);
        uint2 hv1, hv2, hv3, hv4, hv5;
        if (b1) hv1 = *(const uint2*)(hWb + (size_t)s1 * SHD + h * 4);
        if (b2) hv2 = *(const uint2*)(hWb + (size_t)s2 * SHD + h * 4);
        if (b3) hv3 = *(const uint2*)(hWb + (size_t)s3 * SHD + h * 4);
        if (b4) hv4 = *(const uint2*)(hWb + (size_t)s4 * SHD + h * 4);
        if (b5) hv5 = *(const uint2*)(hWb + (size_t)s5 * SHD + h * 4);
        int tn = t + 24;
        int p0 = -1, p1 = -1, p2 = -1, p3 = -1, p4 = -1, p5 = -1;
        if (tn <= deg)      p0 = __builtin_nontemporal_load(csr + base + tn - 1);
        if (tn + 4 <= deg)  p1 = __builtin_nontemporal_load(csr + base + tn + 3);
        if (tn + 8 <= deg)  p2 = __builtin_nontemporal_load(csr + base + tn + 7);
        if (tn + 12 <= deg) p3 = __builtin_nontemporal_load(csr + base + tn + 11);
        if (tn + 16 <= deg) p4 = __builtin_nontemporal_load(csr + base + tn + 15);
        if (tn + 20 <= deg) p5 = __builtin_nontemporal_load(csr + base + tn + 19);
        {
            f32x2 h01, h23;
            h01.x = __uint_as_float(hv0.x << 16);
            h01.y = __uint_as_float(hv0.x & 0xffff0000u);
            h23.x = __uint_as_float(hv0.y << 16);
            h23.y = __uint_as_float(hv0.y & 0xffff0000u);
            f32x2 d2 = h01 * (f32x2){asv.x, asv.y} + h23 * (f32x2){asv.z, asv.w};
            float e = d2.x + d2.y + ednh;
            e = fmaxf(e, 0.2f * e);
            float a = __expf(e);
            den += a;
            f32x2 av = {a, a};
            acc01 += av * h01;
            acc23 += av * h23;
        }
        if (b1) {
            f32x2 h01, h23;
            h01.x = __uint_as_float(hv1.x << 16);
            h01.y = __uint_as_float(hv1.x & 0xffff0000u);
            h23.x = __uint_as_float(hv1.y << 16);
            h23.y = __uint_as_float(hv1.y & 0xffff0000u);
            f32x2 d2 = h01 * (f32x2){asv.x, asv.y} + h23 * (f32x2){asv.z, asv.w};
            float e = d2.x + d2.y + ednh;
            e = fmaxf(e, 0.2f * e);
            float a = __expf(e);
            den += a;
            f32x2 av = {a, a};
            acc01 += av * h01;
            acc23 += av * h23;
        }
        if (b2) {
            f32x2 h01, h23;
            h01.x = __uint_as_float(hv2.x << 16);
            h01.y = __uint_as_float(hv2.x & 0xffff0000u);
            h23.x = __uint_as_float(hv2.y << 16);
            h23.y = __uint_as_float(hv2.y & 0xffff0000u);
            f32x2 d2 = h01 * (f32x2){asv.x, asv.y} + h23 * (f32x2){asv.z, asv.w};
            float e = d2.x + d2.y + ednh;
            e = fmaxf(e, 0.2f * e);
            float a = __expf(e);
            den += a;
            f32x2 av = {a, a};
            acc01 += av * h01;
            acc23 += av * h23;
        }
        if (b3) {
            f32x2 h01, h23;
            h01.x = __uint_as_float(hv3.x << 16);
            h01.y = __uint_as_float(hv3.x & 0xffff0000u);
            h23.x = __uint_as_float(hv3.y << 16);
            h23.y = __uint_as_float(hv3.y & 0xffff0000u);
            f32x2 d2 = h01 * (f32x2){asv.x, asv.y} + h23 * (f32x2){asv.z, asv.w};
            float e = d2.x + d2.y + ednh;
            e = fmaxf(e, 0.2f * e);
            float a = __expf(e);
            den += a;
            f32x2 av = {a, a};
            acc01 += av * h01;
            acc23 += av * h23;
        }
        if (b4) {
            f32x2 h01, h23;
            h01.x = __uint_as_float(hv4.x << 16);
            h01.y = __uint_as_float(hv4.x & 0xffff0000u);
            h23.x = __uint_as_float(hv4.y << 16);
            h23.y = __uint_as_float(hv4.y & 0xffff0000u);
            f32x2 d2 = h01 * (f32x2){asv.x, asv.y} + h23 * (f32x2){asv.z, asv.w};
            float e = d2.x + d2.y + ednh;
            e = fmaxf(e, 0.2f * e);
            float a = __expf(e);
            den += a;
            f32x2 av = {a, a};
            acc01 += av * h01;
            acc23 += av * h23;
        }
        if (b5) {
            f32x2 h01, h23;
            h01.x = __uint_as_float(hv5.x << 16);
            h01.y = __uint_as_float(hv5.x & 0xffff0000u);
            h23.x = __uint_as_float(hv5.y << 16);
            h23.y = __uint_as_float(hv5.y & 0xffff0000u);
            f32x2 d2 = h01 * (f32x2){asv.x, asv.y} + h23 * (f32x2){asv.z, asv.w};
            float e = d2.x + d2.y + ednh;
            e = fmaxf(e, 0.2f * e);
            float a = __expf(e);
            den += a;
            f32x2 av = {a, a};
            acc01 += av * h01;
            acc23 += av * h23;
        }
        s0 = p0; s1 = p1; s2 = p2; s3 = p3; s4 = p4; s5 = p5; t = tn;
    }
    for (int off = 16; off >= 8; off >>= 1) {
        den      += __shfl_down(den, off, 32);
        acc01.x  += __shfl_down(acc01.x, off, 32);
        acc01.y  += __shfl_down(acc01.y, off, 32);
        acc23.x  += __shfl_down(acc23.x, off, 32);
        acc23.y  += __shfl_down(acc23.y, off, 32);
    }
    if (k == 0) {
        float inv = 1.f / (den + 1e-16f);
        float4 bv = *(const float4*)(prm + 32 + h * 4);
        float v0 = acc01.x * inv + bv.x;
        float v1 = acc01.y * inv + bv.y;
        float v2 = acc23.x * inv + bv.z;
        float v3 = acc23.y * inv + bv.w;
        v0 = (v0 > 0.f) ? v0 : expm1f(v0);
        v1 = (v1 > 0.f) ? v1 : expm1f(v1);
        v2 = (v2 > 0.f) ? v2 : expm1f(v2);
        v3 = (v3 > 0.f) ? v3 : expm1f(v3);
        *(float4*)(out + (size_t)n * SHD + h * 4) = make_float4(v0, v1, v2, v3);
    }
}

// ---------------- Temporal tail ---------------------------------------------
// Round-5-verified design. LSTM weights pinned in registers via asm("+v")
// (defeats remat); L2 warm sweep + MLP matvecs use 8-wide batched loads.
template<typename T>
__device__ __forceinline__ void lstm_load_regs(
        const T* Wih0, const T* Whh0, const T* bih0, const T* bhh0,
        const T* Wih1, const T* Whh1, const T* bih1, const T* bhh1,
        const T* xin, int l, bool bl, float* xs,
        float& wa, float& ba, float& wb, float& bb, float& ba2, float& bb2,
        float* Wa, float* Wb, float* Ua, float* Va, float* Ub, float* Vb) {
#pragma unroll
    for (int t = 0; t < SEQL; t++) xs[t] = cvf(xin[t]);
    wa = cvf(Wih0[l]);
    ba = cvf(bih0[l]) + cvf(bhh0[l]);
    wb = bl ? cvf(Wih0[64 + l]) : 0.f;
    bb = bl ? (cvf(bih0[64 + l]) + cvf(bhh0[64 + l])) : 0.f;
    ba2 = cvf(bih1[l]) + cvf(bhh1[l]);
    bb2 = bl ? (cvf(bih1[64 + l]) + cvf(bhh1[64 + l])) : 0.f;
#pragma unroll
    for (int j = 0; j < 21; j++) {
        Wa[j] = cvf(Whh0[l * 21 + j]);
        Wb[j] = bl ? cvf(Whh0[(64 + l) * 21 + j]) : 0.f;
        Ua[j] = cvf(Wih1[l * 21 + j]);
        Va[j] = cvf(Whh1[l * 21 + j]);
        Ub[j] = bl ? cvf(Wih1[(64 + l) * 21 + j]) : 0.f;
        Vb[j] = bl ? cvf(Whh1[(64 + l) * 21 + j]) : 0.f;
    }
}

__device__ __forceinline__ void warm_sweep(const void* p, int nbytes, int t2) {
    const uint4* s = (const uint4*)p;
    int nv = nbytes >> 4;
    unsigned acc = 0;
    for (int i = t2; i < nv; i += 1024) {
        uint4 v0 = s[i];
        uint4 v1 = (i + 128 < nv) ? s[i + 128] : make_uint4(0,0,0,0);
        uint4 v2 = (i + 256 < nv) ? s[i + 256] : make_uint4(0,0,0,0);
        uint4 v3 = (i + 384 < nv) ? s[i + 384] : make_uint4(0,0,0,0);
        uint4 v4 = (i + 512 < nv) ? s[i + 512] : make_uint4(0,0,0,0);
        uint4 v5 = (i + 640 < nv) ? s[i + 640] : make_uint4(0,0,0,0);
        uint4 v6 = (i + 768 < nv) ? s[i + 768] : make_uint4(0,0,0,0);
        uint4 v7 = (i + 896 < nv) ? s[i + 896] : make_uint4(0,0,0,0);
        acc ^= v0.x ^ v1.x ^ v2.x ^ v3.x ^ v4.x ^ v5.x ^ v6.x ^ v7.x;
    }
    asm volatile("" :: "v"(acc));
}

template<typename T>
__device__ __forceinline__ float matvec_t(const T* W, const float* vin,
                                          float bias, int n, int col, int ncol) {
    float acc = bias;
    int k2 = 0;
    for (; k2 + 8 <= n; k2 += 8) {
        float w0 = cvf(W[(k2 + 0) * ncol + col]);
        float w1 = cvf(W[(k2 + 1) * ncol + col]);
        float w2 = cvf(W[(k2 + 2) * ncol + col]);
        float w3 = cvf(W[(k2 + 3) * ncol + col]);
        float w4 = cvf(W[(k2 + 4) * ncol + col]);
        float w5 = cvf(W[(k2 + 5) * ncol + col]);
        float w6 = cvf(W[(k2 + 6) * ncol + col]);
        float w7 = cvf(W[(k2 + 7) * ncol + col]);
        acc += vin[k2 + 0] * w0; acc += vin[k2 + 1] * w1;
        acc += vin[k2 + 2] * w2; acc += vin[k2 + 3] * w3;
        acc += vin[k2 + 4] * w4; acc += vin[k2 + 5] * w5;
        acc += vin[k2 + 6] * w6; acc += vin[k2 + 7] * w7;
    }
    for (; k2 < n; k2++) acc += vin[k2] * cvf(W[k2 * ncol + col]);
    return acc;
}
__device__ __forceinline__ float matvec(const void* W, const float* vin,
                                        float bias, int n, int col, int ncol, int f) {
    return f ? matvec_t<float>((const float*)W, vin, bias, n, col, ncol)
             : matvec_t<bf16>((const bf16*)W, vin, bias, n, col, ncol);
}

__global__ __launch_bounds__(256, 1)
void k_tail(const void* trend, const void* seasonal, const void* residual,
                       const void* cv, const int* tgtp,
                       const void* tWih0, const void* tWhh0, const void* tbih0, const void* tbhh0,
                       const void* tWih1, const void* tWhh1, const void* tbih1, const void* tbhh1,
                       const void* sWih0, const void* sWhh0, const void* sbih0, const void* sbhh0,
                       const void* sWih1, const void* sWhh1, const void* sbih1, const void* sbhh1,
                       const void* res_W, const void* res_b,
                       const void* pg_W, const void* pg_b,
                       const void* f1_W, const void* f1_b,
                       const void* ln_g, const void* ln_b,
                       const void* f2_W, const void* f2_b,
                       const void* f3_W, const void* f3_b,
                       const int* flag, const float* A, void* out) {
    __shared__ __align__(16) float SH1[2][24];
    __shared__ __align__(16) float SH2[2][24];
    __shared__ float comb[97];
    __shared__ float gf[96];
    __shared__ float h1v[64];
    __shared__ float h2s[32];
    __shared__ float sbias[336];  // pg_b@0 f1_b@96 f2_b@160 f3_b@192 ln_g@208 ln_b@272
    __shared__ float stats[2];
    const int tid = threadIdx.x;
    const int f = flag[0];
    const int w = tid >> 6, l = tid & 63;

    if (tid < 96) {
        if (tid < 48) SH1[tid / 24][tid % 24] = 0.f;
        else { int u = tid - 48; SH2[u / 24][u % 24] = 0.f; }
    }
    __syncthreads();

    if (w < 2) {
        const void* Wih0 = w ? sWih0 : tWih0;
        const void* Whh0 = w ? sWhh0 : tWhh0;
        const void* bih0 = w ? sbih0 : tbih0;
        const void* bhh0 = w ? sbhh0 : tbhh0;
        const void* Wih1 = w ? sWih1 : tWih1;
        const void* Whh1 = w ? sWhh1 : tWhh1;
        const void* bih1 = w ? sbih1 : tbih1;
        const void* bhh1 = w ? sbhh1 : tbhh1;
        const void* xin  = w ? seasonal : trend;
        const bool bl = (l < 20);
        float xs[SEQL];
        float wa, ba, wb, bb, ba2, bb2;
        float Wa[21], Wb[21], Ua[21], Va[21], Ub[21], Vb[21];
        if (f) {
            lstm_load_regs<float>((const float*)Wih0, (const float*)Whh0,
                (const float*)bih0, (const float*)bhh0,
                (const float*)Wih1, (const float*)Whh1,
                (const float*)bih1, (const float*)bhh1,
                (const float*)xin, l, bl, xs, wa, ba, wb, bb, ba2, bb2,
                Wa, Wb, Ua, Va, Ub, Vb);
        } else {
            lstm_load_regs<bf16>((const bf16*)Wih0, (const bf16*)Whh0,
                (const bf16*)bih0, (const bf16*)bhh0,
                (const bf16*)Wih1, (const bf16*)Whh1,
                (const bf16*)bih1, (const bf16*)bhh1,
                (const bf16*)xin, l, bl, xs, wa, ba, wb, bb, ba2, bb2,
                Wa, Wb, Ua, Va, Ub, Vb);
        }
#pragma unroll
        for (int j = 0; j < 21; j++) {
            asm volatile("" : "+v"(Wa[j]), "+v"(Wb[j]));
            asm volatile("" : "+v"(Ua[j]), "+v"(Va[j]));
            asm volatile("" : "+v"(Ub[j]), "+v"(Vb[j]));
        }
#pragma unroll
        for (int t = 0; t < SEQL; t++) asm volatile("" : "+v"(xs[t]));
        asm volatile("" : "+v"(wa), "+v"(ba));
        asm volatile("" : "+v"(wb), "+v"(bb));
        asm volatile("" : "+v"(ba2), "+v"(bb2));

        float h1r = 0.f, c1 = 0.f, h2r = 0.f, c2 = 0.f;
#pragma unroll 1
        for (int t = 0; t < SEQL; t++) {
            float aa = ba + xs[t] * wa;
            float ab = bb + xs[t] * wb;
#pragma unroll
            for (int q = 0; q < 5; q++) {
                float4 v = *(const float4*)&SH1[w][q * 4];
                aa += v.x * Wa[q*4];   ab += v.x * Wb[q*4];
                aa += v.y * Wa[q*4+1]; ab += v.y * Wb[q*4+1];
                aa += v.z * Wa[q*4+2]; ab += v.z * Wb[q*4+2];
                aa += v.w * Wa[q*4+3]; ab += v.w * Wb[q*4+3];
            }
            { float v20 = SH1[w][20]; aa += v20 * Wa[20]; ab += v20 * Wb[20]; }
            float fj = __shfl(aa, 21 + l);
            float gj = __shfl(aa, 42 + l);
            float oa = __shfl(aa, 63);
            float ob = __shfl(ab, (l == 0) ? 0 : (l - 1));
            float oj = (l == 0) ? oa : ob;
            if (l < 21) {
                c1 = sigm(fj) * c1 + sigm(aa) * tanhf(gj);
                h1r = sigm(oj) * tanhf(c1);
                SH1[w][l] = h1r;
            }
            __threadfence_block();
            float a2 = ba2, b2v = bb2;
#pragma unroll
            for (int q = 0; q < 5; q++) {
                float4 u = *(const float4*)&SH1[w][q * 4];
                float4 v = *(const float4*)&SH2[w][q * 4];
                a2  += u.x * Ua[q*4]   + v.x * Va[q*4];
                b2v += u.x * Ub[q*4]   + v.x * Vb[q*4];
                a2  += u.y * Ua[q*4+1] + v.y * Va[q*4+1];
                b2v += u.y * Ub[q*4+1] + v.y * Vb[q*4+1];
                a2  += u.z * Ua[q*4+2] + v.z * Va[q*4+2];
                b2v += u.z * Ub[q*4+2] + v.z * Vb[q*4+2];
                a2  += u.w * Ua[q*4+3] + v.w * Va[q*4+3];
                b2v += u.w * Ub[q*4+3] + v.w * Vb[q*4+3];
            }
            { float u20 = SH1[w][20], v20 = SH2[w][20];
              a2  += u20 * Ua[20] + v20 * Va[20];
              b2v += u20 * Ub[20] + v20 * Vb[20]; }
            float fj2 = __shfl(a2, 21 + l);
            float gj2 = __shfl(a2, 42 + l);
            float oa2 = __shfl(a2, 63);
            float ob2 = __shfl(b2v, (l == 0) ? 0 : (l - 1));
            float oj2 = (l == 0) ? oa2 : ob2;
            if (l < 21) {
                c2 = sigm(fj2) * c2 + sigm(a2) * tanhf(gj2);
                h2r = sigm(oj2) * tanhf(c2);
                SH2[w][l] = h2r;
            }
            __threadfence_block();
        }
        if (l < 21) comb[(w == 0 ? 32 : 53) + l] = h2r;
    } else {
        int t2 = tid - 128;   // 0..127
        if (t2 < TRH)
            comb[74 + t2] = relu_nan(ldw(residual, SEQL - 1, f) * ldw(res_W, t2, f)
                                     + ldw(res_b, t2, f));
        if (t2 == TRH) comb[96] = ldw(cv, 0, f);
        if (t2 >= 32 && t2 < 64) {
            int tgt = tgtp[0];
            comb[t2 - 32] = A[(size_t)tgt * SHD + (t2 - 32)];
        }
        for (int i = t2; i < 336; i += 128) {
            float v;
            if (i < 96)       v = ldw(pg_b, i, f);
            else if (i < 160) v = ldw(f1_b, i - 96, f);
            else if (i < 192) v = ldw(f2_b, i - 160, f);
            else if (i < 206) v = ldw(f3_b, i - 192, f);
            else if (i < 208) v = 0.f;
            else if (i < 272) v = ldw(ln_g, i - 208, f);
            else              v = ldw(ln_b, i - 272, f);
            sbias[i] = v;
        }
        int esz = f ? 4 : 2;
        warm_sweep(pg_W, 9312 * esz, t2);
        warm_sweep(f1_W, 6144 * esz, t2);
        warm_sweep(f2_W, 2048 * esz, t2);
        warm_sweep(f3_W,  448 * esz, t2);
    }
    __syncthreads();

    if (tid < 96)
        gf[tid] = comb[tid] * sigm(matvec(pg_W, comb, sbias[tid], 97, tid, 96, f));
    __syncthreads();
    if (tid < 64)
        h1v[tid] = matvec(f1_W, gf, sbias[96 + tid], 96, tid, 64, f);
    __syncthreads();
    if (tid == 0) {
        float mu = 0.f;
        for (int j = 0; j < 64; j++) mu += h1v[j];
        mu /= 64.f;
        float var = 0.f;
        for (int j = 0; j < 64; j++) { float d = h1v[j] - mu; var += d * d; }
        var /= 64.f;
        stats[0] = mu; stats[1] = rsqrtf(var + 1e-5f);
    }
    __syncthreads();
    if (tid < 64)
        h1v[tid] = relu_nan((h1v[tid] - stats[0]) * stats[1] * sbias[208 + tid] + sbias[272 + tid]);
    __syncthreads();
    if (tid < 32)
        h2s[tid] = relu_nan(matvec(f2_W, h1v, sbias[160 + tid], 64, tid, 32, f));
    __syncthreads();
    if (tid < SEQL) {
        float acc = matvec(f3_W, h2s, sbias[192 + tid], 32, tid, 14, f);
        if (acc != acc) acc = 3333.0f;
        if (f) ((float*)out)[tid] = acc;
        else   ((bf16*)out)[tid] = __float2bfloat16(acc);
    }
}

// ---------------- host helpers ----------------
static inline unsigned short h_f2bf(float f) {
    union { float f; unsigned u; } x; x.f = f;
    return (unsigned short)(x.u >> 16);
}
static unsigned short g_diag[SEQL];

// ---------------- launch ----------------
extern "C" void kernel_launch(void* const* d_in, const int* in_sizes, int n_in,
                              void* d_out, int out_size, void* d_ws, size_t ws_size,
                              hipStream_t stream) {
    const int* ei  = (const int*)d_in[1];
    const int* tgt = (const int*)d_in[6];

    const size_t HWB  = sizeof(unsigned short) * (size_t)NN * SHD;
    const size_t EDB  = sizeof(float) * (size_t)NN * NH;
    const size_t AB   = sizeof(float) * (size_t)NN * SHD;
    // zeroed region: cnts(16) + map1,map2,degB,fillB,degC,fillC (6N ints)
    const size_t ZER  = sizeof(int) * (size_t)(16 + 6 * NN);
    const size_t RSTB = sizeof(int) * (size_t)(2 * NN);
    const size_t LSTB = sizeof(int) * (size_t)(ECA + ECL1 + 8 + ECL2
                                               + 3 * ECB + 3 * ECC);
    const size_t NEED = 256 + 1024 + ZER + RSTB + LSTB + 512 + HWB + EDB + AB;
    if (ws_size < NEED) {
        for (int i = 0; i < SEQL; i++) g_diag[i] = h_f2bf(7777.0f);
        hipMemcpyAsync(d_out, g_diag, SEQL * sizeof(unsigned short),
                       hipMemcpyHostToDevice, stream);
        return;
    }

    char* p = (char*)d_ws;
    int*   flag = (int*)p;   p += 256;
    float* prm  = (float*)p; p += 1024;
    int* cnts  = (int*)p; p += sizeof(int) * 16;   // cA,c1,cB,c2,cC,c3
    int* map1  = (int*)p; p += sizeof(int) * NN;
    int* map2  = (int*)p; p += sizeof(int) * NN;
    int* degB  = (int*)p; p += sizeof(int) * NN;
    int* fillB = (int*)p; p += sizeof(int) * NN;
    int* degC  = (int*)p; p += sizeof(int) * NN;
    int* fillC = (int*)p; p += sizeof(int) * NN;
    int* rstartB = (int*)p; p += sizeof(int) * NN;
    int* rstartC = (int*)p; p += sizeof(int) * NN;
    int* eA   = (int*)p; p += sizeof(int) * ECA;
    int* l1   = (int*)p; p += sizeof(int) * ECL1;
    int* l3   = (int*)p; p += sizeof(int) * 8;
    int* l2   = (int*)p; p += sizeof(int) * ECL2;
    int* eBs  = (int*)p; p += sizeof(int) * ECB;
    int* eBd  = (int*)p; p += sizeof(int) * ECB;
    int* csrB = (int*)p; p += sizeof(int) * ECB;
    int* eCs  = (int*)p; p += sizeof(int) * ECC;
    int* eCd  = (int*)p; p += sizeof(int) * ECC;
    int* csrC = (int*)p; p += sizeof(int) * ECC;
    p = (char*)(((uintptr_t)p + 255) & ~(uintptr_t)255);
    unsigned short* hWb = (unsigned short*)p; p += HWB;
    float* ed = (float*)p; p += EDB;
    float* A  = (float*)p; p += AB;
    int* cA = cnts; int* c1 = cnts + 1; int* cB = cnts + 2;
    int* c2 = cnts + 3; int* cC = cnts + 4; int* c3 = cnts + 5;

    dim3 b256(256);
    dim3 gN((NN + 255) / 256);
    dim3 gScan(2048);

    PatternAwareSTGAT_94489281309_kernel<<<dim3(1), dim3(64), 0, stream>>>(
        (const unsigned int*)d_in[0], flag,
        d_in[8], d_in[10], d_in[12], d_in[14], d_in[16], d_in[18], prm);

    hipMemsetAsync(cnts, 0, ZER, stream);

    // filtered-edge frontier build (replaces full-graph CSR sort)
    k_scanA<<<gScan, b256, 0, stream>>>(ei, tgt, eA, cA);
    k_mark1<<<dim3(1), b256, 0, stream>>>(eA, cA, tgt, map1, l1, c1, l3, c3);
    k_scanF<<<gScan, b256, 0, stream>>>(ei, map1, eBs, eBd, cB, degB, ECB);
    k_prefix<<<dim3(1), b256, 0, stream>>>(l1, c1, ECL1, degB, rstartB,
                                           map2, l2, c2, ECL2);
    k_scatter<<<dim3(64), b256, 0, stream>>>(eBs, eBd, cB, ECB, rstartB, fillB, csrB,
                                             map2, l2, c2, ECL2);
    k_scanF<<<gScan, b256, 0, stream>>>(ei, map2, eCs, eCd, cC, degC, ECC);
    k_prefix<<<dim3(1), b256, 0, stream>>>(l2, c2, ECL2, degC, rstartC,
                                           (int*)nullptr, (int*)nullptr, (int*)nullptr, 0);
    k_scatter<<<dim3(512), b256, 0, stream>>>(eCs, eCd, cC, ECC, rstartC, fillC, csrC,
                                              (int*)nullptr, (int*)nullptr, (int*)nullptr, 0);

    // GAT layers over the dependency cone
    k_transform0<<<gN, b256, 0, stream>>>(d_in[0], d_in[7], d_in[9], flag, hWb, ed);
    k_aggregate<<<dim3(ECL2 * 32 / 256), b256, 0, stream>>>(l2, c2, ECL2,
        rstartC, degC, csrC, (const int*)nullptr, 0, hWb, ed, prm, A);
    k_transform1<<<dim3(ECL2 / 256), b256, 0, stream>>>(l2, c2, ECL2,
        A, d_in[11], d_in[13], flag, hWb, ed);
    k_aggregate<<<dim3(ECL1 * 32 / 256), b256, 0, stream>>>(l1, c1, ECL1,
        rstartB, degB, csrB, (const int*)nullptr, 0, hWb, ed, prm + 64, A);
    k_transform1<<<dim3((ECL1 + 255) / 256), b256, 0, stream>>>(l1, c1, ECL1,
        A, d_in[15], d_in[17], flag, hWb, ed);
    k_aggregate<<<dim3(1), b256, 0, stream>>>(l3, c3, 8,
        (const int*)nullptr, (const int*)nullptr, eA, cA, ECA, hWb, ed, prm + 128, A);

    k_tail<<<dim3(1), b256, 0, stream>>>(
        d_in[2], d_in[3], d_in[4], d_in[5], tgt,
        d_in[19], d_in[20], d_in[21], d_in[22],
        d_in[23], d_in[24], d_in[25], d_in[26],
        d_in[27], d_in[28], d_in[29], d_in[30],
        d_in[31], d_in[32], d_in[33], d_in[34],
        d_in[35], d_in[36],
        d_in[37], d_in[38],
        d_in[39], d_in[40],
        d_in[41], d_in[42],
        d_in[43], d_in[44],
        d_in[45], d_in[46],
        flag, A, d_out);
}

// Round 12
// 343.812 us; speedup vs baseline: 1.7929x; 1.7929x over previous
//
#include <hip/hip_runtime.h>
#include <hip/hip_bf16.h>
#include <stdint.h>
#include <math.h>

#define NN   100000
#define EE   3200000
#define FIN  5
#define SHD  32
#define NH   8
#define TCH  21
#define TRH  22
#define SEQL 14

// frontier / filtered-edge capacities (dependency-cone pruning)
#define ECA   1024     // in-edges of tgt (layer-3 row)
#define ECL1  1024     // F1 node list
#define ECB   16384    // edges into F1 (layer-2 aggregation)
#define ECL2  8192     // F2 node list
#define ECC   131072   // edges into F2 (layer-1 aggregation)

// chunked scan geometry (k_p1-proven skeleton)
#define BCHK2 4096
#define NBC2  ((EE + BCHK2 - 1) / BCHK2)
#define NBW   ((NN + 31) / 32)    // 3125 bitmap words
#define NBWP  3200                // padded

typedef __hip_bfloat16 bf16;
typedef __attribute__((ext_vector_type(2))) float f32x2;

__device__ __forceinline__ float b2f(bf16 v) { return __bfloat162float(v); }
__device__ __forceinline__ float sigm(float x) { return 1.f / (1.f + __expf(-x)); }
__device__ __forceinline__ float ldw(const void* p, int i, int f) {
    return f ? ((const float*)p)[i] : __bfloat162float(((const bf16*)p)[i]);
}
__device__ __forceinline__ float relu_nan(float v) {
    return (v == v) ? ((v > 0.f) ? v : 0.f) : v;
}
__device__ __forceinline__ unsigned short f2b(float v) {
    bf16 b = __float2bfloat16(v);
    return *reinterpret_cast<unsigned short*>(&b);
}
__device__ __forceinline__ float cvf(float v) { return v; }
__device__ __forceinline__ float cvf(bf16 v) { return __bfloat162float(v); }
__device__ __forceinline__ void cp(float* dst, const void* src, int n,
                                   int t0, int stride, int f) {
    if (f) {
        const float* s = (const float*)src;
        for (int i = t0; i < n; i += stride) dst[i] = s[i];
    } else {
        const bf16* s = (const bf16*)src;
        for (int i = t0; i < n; i += stride) dst[i] = b2f(s[i]);
    }
}

// ---- dtype detect + f32 param pre-convert (identifier-named, 1 wave) ------
__global__ void PatternAwareSTGAT_94489281309_kernel(const unsigned int* xw, int* flag,
        const void* as0, const void* b0, const void* as1, const void* b1,
        const void* as2, const void* b2, float* prm) {
    int tid = threadIdx.x;   // 64
    int sane = 0;
    for (int i = 0; i < 64; i++) {
        unsigned int lo = xw[i] & 0xFFFFu;
        int e = (int)((lo >> 7) & 0xFF);
        if (e >= 110 && e <= 135) sane++;
    }
    int f = (sane >= 32) ? 0 : 1;
    if (tid == 0) flag[0] = f;
    const void* asp[3] = {as0, as1, as2};
    const void* bp[3]  = {b0, b1, b2};
    for (int l = 0; l < 3; l++)
        prm[l * 64 + tid] = (tid < 32) ? ldw(asp[l], tid, f) : ldw(bp[l], tid - 32, f);
}

// ---------------- Chunked filtered edge scan (round-11/12) ------------------
// Round-10's grid-stride scan with a per-edge GLOBAL map[d] gather ran at
// 298us with all pipes idle (un-unrolled dependent-load chain + divergent
// 64-addr gather). This is the k_p1-proven skeleton instead: contiguous
// 4096-edge chunk per block, membership BITMAP staged to LDS (12.5KB),
// matches staged in LDS, ONE global atomicAdd per block to commit.
// bm == nullptr -> predicate is (d == tgt) (scan A).
__global__ __launch_bounds__(256) void k_scan2(
        const int* __restrict__ ei, const unsigned* __restrict__ bm,
        const int* __restrict__ tgtp,
        int* __restrict__ es, int* __restrict__ edd,
        int* __restrict__ cnt, int* __restrict__ deg, int cap) {
    __shared__ unsigned sbm[NBWP];
    __shared__ int ss[BCHK2], sd[BCHK2];
    __shared__ int scnt, sbase;
    int tid = threadIdx.x;
    const bool useBm = (bm != nullptr);
    int tgtv = useBm ? -1 : tgtp[0];
    if (useBm) {
        for (int i = tid; i < NBW; i += 256) sbm[i] = bm[i];
    }
    if (tid == 0) scnt = 0;
    __syncthreads();
    int e0 = blockIdx.x * BCHK2;
    int e1 = e0 + BCHK2; if (e1 > EE) e1 = EE;
    for (int e = e0 + tid; e < e1; e += 256) {
        int d = __builtin_nontemporal_load(ei + EE + e);
        bool m = useBm ? (((sbm[d >> 5] >> (d & 31)) & 1u) != 0u) : (d == tgtv);
        if (m) {
            int s = __builtin_nontemporal_load(ei + e);
            int p = atomicAdd(&scnt, 1);        // LDS atomic, p < BCHK2
            ss[p] = s; sd[p] = d;
            if (deg) atomicAdd(&deg[d], 1);     // scattered, low contention
        }
    }
    __syncthreads();
    if (tid == 0) sbase = atomicAdd(cnt, scnt); // one global atomic per block
    __syncthreads();
    for (int i = tid; i < scnt; i += 256) {
        int p = sbase + i;
        if (p < cap) { es[p] = ss[i]; edd[p] = sd[i]; }
    }
}

// build F1 list (dedup via bitmap atomicOr) + seed l3 = {tgt}
__global__ void k_mark1(const int* __restrict__ eA, const int* __restrict__ cA,
                        const int* __restrict__ tgtp,
                        unsigned* __restrict__ bm1, int* __restrict__ l1,
                        int* __restrict__ c1,
                        int* __restrict__ l3, int* __restrict__ c3) {
    int n = cA[0]; if (n > ECA) n = ECA;
    for (int i = threadIdx.x; i < n; i += 256) {
        int s = eA[i];
        unsigned bit = 1u << (s & 31);
        unsigned old = atomicOr(&bm1[s >> 5], bit);
        if (!(old & bit)) {
            int p = atomicAdd(c1, 1);
            if (p < ECL1) l1[p] = s;
        }
    }
    if (threadIdx.x == 0) {
        int t = tgtp[0];
        unsigned bit = 1u << (t & 31);
        unsigned old = atomicOr(&bm1[t >> 5], bit);
        if (!(old & bit)) {
            int p = atomicAdd(c1, 1);
            if (p < ECL1) l1[p] = t;
        }
        l3[0] = t; c3[0] = 1;
    }
}

// exclusive prefix of deg over list -> rstart (LDS-chunked, 1 block);
// optionally seed next-level node set (bitmap + list).
__global__ void k_prefix(const int* __restrict__ list, const int* __restrict__ cp, int cap,
                         const int* __restrict__ deg, int* __restrict__ rstart,
                         unsigned* __restrict__ bmN, int* __restrict__ lN,
                         int* __restrict__ cN, int capN) {
    __shared__ int sdd[256];
    __shared__ int sbase;
    int n = cp[0]; if (n > cap) n = cap;
    if (threadIdx.x == 0) sbase = 0;
    __syncthreads();
    for (int b = 0; b < n; b += 256) {
        int i = b + threadIdx.x;
        int nd = (i < n) ? list[i] : -1;
        sdd[threadIdx.x] = (nd >= 0) ? deg[nd] : 0;
        __syncthreads();
        if (threadIdx.x == 0) {
            int acc = sbase;
            for (int j = 0; j < 256; j++) { int v = sdd[j]; sdd[j] = acc; acc += v; }
            sbase = acc;
        }
        __syncthreads();
        if (nd >= 0) rstart[nd] = sdd[threadIdx.x];
        __syncthreads();
    }
    if (bmN) {
        for (int i = threadIdx.x; i < n; i += 256) {
            int nd = list[i];
            unsigned bit = 1u << (nd & 31);
            unsigned old = atomicOr(&bmN[nd >> 5], bit);
            if (!(old & bit)) {
                int p = atomicAdd(cN, 1);
                if (p < capN) lN[p] = nd;
            }
        }
    }
}

// scatter filtered pairs into per-dst rows; optionally collect srcs into
// next-level node set (bitmap dedup).
__global__ __launch_bounds__(256) void k_scatter(const int* __restrict__ es,
                                                 const int* __restrict__ edd,
                                                 const int* __restrict__ cp, int cap,
                                                 const int* __restrict__ rstart,
                                                 int* __restrict__ fill, int* __restrict__ csr,
                                                 unsigned* __restrict__ bmN,
                                                 int* __restrict__ lN,
                                                 int* __restrict__ cN, int capN) {
    int m = cp[0]; if (m > cap) m = cap;
    for (int i = blockIdx.x * 256 + threadIdx.x; i < m; i += gridDim.x * 256) {
        int s = es[i], d = edd[i];
        int p = atomicAdd(&fill[d], 1);
        csr[rstart[d] + p] = s;
        if (bmN) {
            unsigned bit = 1u << (s & 31);
            unsigned old = atomicOr(&bmN[s >> 5], bit);
            if (!(old & bit)) {
                int q = atomicAdd(cN, 1);
                if (q < capN) lN[q] = s;
            }
        }
    }
}

// ---------------- GAT transform (layer 0: raw input, DIN=5, full N) ---------
__global__ void k_transform0(const void* x, const void* W, const void* ad_,
                             const int* flag, unsigned short* hWb, float* ed) {
    __shared__ float sW[FIN * SHD];
    __shared__ float sad[SHD];
    int tid = threadIdx.x;
    int f = flag[0];
    cp(sW, W, FIN * SHD, tid, 256, f);
    if (tid >= 192 && tid < 192 + SHD) sad[tid - 192] = ldw(ad_, tid - 192, f);
    __syncthreads();
    int n = blockIdx.x * 256 + tid;
    if (n >= NN) return;
    float xr[FIN];
    if (f) {
        const float* xp = (const float*)x + (size_t)n * FIN;
        for (int k = 0; k < FIN; k++) xr[k] = xp[k];
    } else {
        const bf16* xp = (const bf16*)x + (size_t)n * FIN;
        for (int k = 0; k < FIN; k++) xr[k] = b2f(xp[k]);
    }
    float o[SHD];
    for (int j = 0; j < SHD; j++) o[j] = 0.f;
    for (int k = 0; k < FIN; k++) {
        float xv = xr[k];
        for (int j = 0; j < SHD; j++) o[j] += xv * sW[k * SHD + j];
    }
    ushort4* row = (ushort4*)(hWb + (size_t)n * SHD);
    for (int q = 0; q < 8; q++) {
        ushort4 v; v.x = f2b(o[q*4]); v.y = f2b(o[q*4+1]); v.z = f2b(o[q*4+2]); v.w = f2b(o[q*4+3]);
        row[q] = v;
    }
    for (int h = 0; h < NH; h++) {
        float e2 = 0.f;
        for (int c = 0; c < 4; c++) e2 += o[h * 4 + c] * sad[h * 4 + c];
        ed[(size_t)n * NH + h] = e2;
    }
}

// ---------------- GAT transform (layers 2/3: list-driven, DIN=32) -----------
__global__ void k_transform1(const int* __restrict__ list, const int* __restrict__ cntp,
                             int cap,
                             const float* x, const void* W, const void* ad_,
                             const int* flag, unsigned short* hWb, float* ed) {
    __shared__ float sW[SHD * SHD];
    __shared__ float sad[SHD];
    int tid = threadIdx.x;
    int f = flag[0];
    cp(sW, W, SHD * SHD, tid, 256, f);
    if (tid >= 192 && tid < 192 + SHD) sad[tid - 192] = ldw(ad_, tid - 192, f);
    __syncthreads();
    int cnt = cntp[0]; if (cnt > cap) cnt = cap;
    int ii = blockIdx.x * 256 + tid;
    if (ii >= cnt) return;
    int n = list[ii];
    float xr[SHD];
    const float4* xp4 = (const float4*)(x + (size_t)n * SHD);
#pragma unroll
    for (int q = 0; q < 8; q++) {
        float4 v = xp4[q];
        xr[q*4] = v.x; xr[q*4+1] = v.y; xr[q*4+2] = v.z; xr[q*4+3] = v.w;
    }
    float o[SHD];
    for (int j = 0; j < SHD; j++) o[j] = 0.f;
    for (int k = 0; k < SHD; k++) {
        float xv = xr[k];
        for (int j = 0; j < SHD; j++) o[j] += xv * sW[k * SHD + j];
    }
    ushort4* row = (ushort4*)(hWb + (size_t)n * SHD);
    for (int q = 0; q < 8; q++) {
        ushort4 v; v.x = f2b(o[q*4]); v.y = f2b(o[q*4+1]); v.z = f2b(o[q*4+2]); v.w = f2b(o[q*4+3]);
        row[q] = v;
    }
    for (int h = 0; h < NH; h++) {
        float e2 = 0.f;
        for (int c = 0; c < 4; c++) e2 += o[h * 4 + c] * sad[h * 4 + c];
        ed[(size_t)n * NH + h] = e2;
    }
}

// ------- GAT aggregation: list-driven, 2 entries/wave, 6-deep pipeline ------
// ovr != null: single-row mode (base=0, deg=*ovr) for the layer-3 tgt row.
__global__ void k_aggregate(const int* __restrict__ list, const int* __restrict__ cntp,
                            int cap,
                            const int* __restrict__ rstart, const int* __restrict__ rdeg,
                            const int* __restrict__ csr,
                            const int* __restrict__ ovr, int ovrCap,
                            const unsigned short* __restrict__ hWb,
                            const float* __restrict__ ed,
                            const float* __restrict__ prm,
                            float* __restrict__ out) {
    int gid = blockIdx.x * 256 + threadIdx.x;
    int lane = threadIdx.x & 63;
    int cnt = cntp[0]; if (cnt > cap) cnt = cap;
    int idx = (gid >> 6) * 2 + (lane >> 5);
    if (idx >= cnt) return;
    int n = list[idx];
    int l32 = lane & 31;
    int h = l32 & 7, k = l32 >> 3;
    float4 asv = *(const float4*)(prm + h * 4);
    float ednh = ed[(size_t)n * NH + h];
    int base, deg;
    if (ovr) { base = 0; deg = ovr[0]; if (deg > ovrCap) deg = ovrCap; }
    else     { base = rstart[n]; deg = rdeg[n]; }
    float den = 0.f;
    f32x2 acc01 = {0.f, 0.f}, acc23 = {0.f, 0.f};
    int t = k;
    int s0 = -1, s1 = -1, s2 = -1, s3 = -1, s4 = -1, s5 = -1;
    if (t <= deg)      s0 = (t == 0) ? n : __builtin_nontemporal_load(csr + base + t - 1);
    if (t + 4 <= deg)  s1 = __builtin_nontemporal_load(csr + base + t + 3);
    if (t + 8 <= deg)  s2 = __builtin_nontemporal_load(csr + base + t + 7);
    if (t + 12 <= deg) s3 = __builtin_nontemporal_load(csr + base + t + 11);
    if (t + 16 <= deg) s4 = __builtin_nontemporal_load(csr + base + t + 15);
    if (t + 20 <= deg) s5 = __builtin_nontemporal_load(csr + base + t + 19);
    while (s0 >= 0) {
        uint2 hv0 = *(const uint2*)(hWb + (size_t)s0 * SHD + h * 4);
        bool b1 = (s1 >= 0), b2 = (s2 >= 0), b3 = (s3 >= 0), b4 = (s4 >= 0), b5 = (s5 >= 0);
        uint2 hv1, hv2, hv3, hv4, hv5;
        if (b1) hv1 = *(const uint2*)(hWb + (size_t)s1 * SHD + h * 4);
        if (b2) hv2 = *(const uint2*)(hWb + (size_t)s2 * SHD + h * 4);
        if (b3) hv3 = *(const uint2*)(hWb + (size_t)s3 * SHD + h * 4);
        if (b4) hv4 = *(const uint2*)(hWb + (size_t)s4 * SHD + h * 4);
        if (b5) hv5 = *(const uint2*)(hWb + (size_t)s5 * SHD + h * 4);
        int tn = t + 24;
        int p0 = -1, p1 = -1, p2 = -1, p3 = -1, p4 = -1, p5 = -1;
        if (tn <= deg)      p0 = __builtin_nontemporal_load(csr + base + tn - 1);
        if (tn + 4 <= deg)  p1 = __builtin_nontemporal_load(csr + base + tn + 3);
        if (tn + 8 <= deg)  p2 = __builtin_nontemporal_load(csr + base + tn + 7);
        if (tn + 12 <= deg) p3 = __builtin_nontemporal_load(csr + base + tn + 11);
        if (tn + 16 <= deg) p4 = __builtin_nontemporal_load(csr + base + tn + 15);
        if (tn + 20 <= deg) p5 = __builtin_nontemporal_load(csr + base + tn + 19);
        {
            f32x2 h01, h23;
            h01.x = __uint_as_float(hv0.x << 16);
            h01.y = __uint_as_float(hv0.x & 0xffff0000u);
            h23.x = __uint_as_float(hv0.y << 16);
            h23.y = __uint_as_float(hv0.y & 0xffff0000u);
            f32x2 d2 = h01 * (f32x2){asv.x, asv.y} + h23 * (f32x2){asv.z, asv.w};
            float e = d2.x + d2.y + ednh;
            e = fmaxf(e, 0.2f * e);
            float a = __expf(e);
            den += a;
            f32x2 av = {a, a};
            acc01 += av * h01;
            acc23 += av * h23;
        }
        if (b1) {
            f32x2 h01, h23;
            h01.x = __uint_as_float(hv1.x << 16);
            h01.y = __uint_as_float(hv1.x & 0xffff0000u);
            h23.x = __uint_as_float(hv1.y << 16);
            h23.y = __uint_as_float(hv1.y & 0xffff0000u);
            f32x2 d2 = h01 * (f32x2){asv.x, asv.y} + h23 * (f32x2){asv.z, asv.w};
            float e = d2.x + d2.y + ednh;
            e = fmaxf(e, 0.2f * e);
            float a = __expf(e);
            den += a;
            f32x2 av = {a, a};
            acc01 += av * h01;
            acc23 += av * h23;
        }
        if (b2) {
            f32x2 h01, h23;
            h01.x = __uint_as_float(hv2.x << 16);
            h01.y = __uint_as_float(hv2.x & 0xffff0000u);
            h23.x = __uint_as_float(hv2.y << 16);
            h23.y = __uint_as_float(hv2.y & 0xffff0000u);
            f32x2 d2 = h01 * (f32x2){asv.x, asv.y} + h23 * (f32x2){asv.z, asv.w};
            float e = d2.x + d2.y + ednh;
            e = fmaxf(e, 0.2f * e);
            float a = __expf(e);
            den += a;
            f32x2 av = {a, a};
            acc01 += av * h01;
            acc23 += av * h23;
        }
        if (b3) {
            f32x2 h01, h23;
            h01.x = __uint_as_float(hv3.x << 16);
            h01.y = __uint_as_float(hv3.x & 0xffff0000u);
            h23.x = __uint_as_float(hv3.y << 16);
            h23.y = __uint_as_float(hv3.y & 0xffff0000u);
            f32x2 d2 = h01 * (f32x2){asv.x, asv.y} + h23 * (f32x2){asv.z, asv.w};
            float e = d2.x + d2.y + ednh;
            e = fmaxf(e, 0.2f * e);
            float a = __expf(e);
            den += a;
            f32x2 av = {a, a};
            acc01 += av * h01;
            acc23 += av * h23;
        }
        if (b4) {
            f32x2 h01, h23;
            h01.x = __uint_as_float(hv4.x << 16);
            h01.y = __uint_as_float(hv4.x & 0xffff0000u);
            h23.x = __uint_as_float(hv4.y << 16);
            h23.y = __uint_as_float(hv4.y & 0xffff0000u);
            f32x2 d2 = h01 * (f32x2){asv.x, asv.y} + h23 * (f32x2){asv.z, asv.w};
            float e = d2.x + d2.y + ednh;
            e = fmaxf(e, 0.2f * e);
            float a = __expf(e);
            den += a;
            f32x2 av = {a, a};
            acc01 += av * h01;
            acc23 += av * h23;
        }
        if (b5) {
            f32x2 h01, h23;
            h01.x = __uint_as_float(hv5.x << 16);
            h01.y = __uint_as_float(hv5.x & 0xffff0000u);
            h23.x = __uint_as_float(hv5.y << 16);
            h23.y = __uint_as_float(hv5.y & 0xffff0000u);
            f32x2 d2 = h01 * (f32x2){asv.x, asv.y} + h23 * (f32x2){asv.z, asv.w};
            float e = d2.x + d2.y + ednh;
            e = fmaxf(e, 0.2f * e);
            float a = __expf(e);
            den += a;
            f32x2 av = {a, a};
            acc01 += av * h01;
            acc23 += av * h23;
        }
        s0 = p0; s1 = p1; s2 = p2; s3 = p3; s4 = p4; s5 = p5; t = tn;
    }
    for (int off = 16; off >= 8; off >>= 1) {
        den      += __shfl_down(den, off, 32);
        acc01.x  += __shfl_down(acc01.x, off, 32);
        acc01.y  += __shfl_down(acc01.y, off, 32);
        acc23.x  += __shfl_down(acc23.x, off, 32);
        acc23.y  += __shfl_down(acc23.y, off, 32);
    }
    if (k == 0) {
        float inv = 1.f / (den + 1e-16f);
        float4 bv = *(const float4*)(prm + 32 + h * 4);
        float v0 = acc01.x * inv + bv.x;
        float v1 = acc01.y * inv + bv.y;
        float v2 = acc23.x * inv + bv.z;
        float v3 = acc23.y * inv + bv.w;
        v0 = (v0 > 0.f) ? v0 : expm1f(v0);
        v1 = (v1 > 0.f) ? v1 : expm1f(v1);
        v2 = (v2 > 0.f) ? v2 : expm1f(v2);
        v3 = (v3 > 0.f) ? v3 : expm1f(v3);
        *(float4*)(out + (size_t)n * SHD + h * 4) = make_float4(v0, v1, v2, v3);
    }
}

// ---------------- Temporal tail ---------------------------------------------
// Round-5-verified design. LSTM weights pinned in registers via asm("+v")
// (defeats remat); L2 warm sweep + MLP matvecs use 8-wide batched loads.
template<typename T>
__device__ __forceinline__ void lstm_load_regs(
        const T* Wih0, const T* Whh0, const T* bih0, const T* bhh0,
        const T* Wih1, const T* Whh1, const T* bih1, const T* bhh1,
        const T* xin, int l, bool bl, float* xs,
        float& wa, float& ba, float& wb, float& bb, float& ba2, float& bb2,
        float* Wa, float* Wb, float* Ua, float* Va, float* Ub, float* Vb) {
#pragma unroll
    for (int t = 0; t < SEQL; t++) xs[t] = cvf(xin[t]);
    wa = cvf(Wih0[l]);
    ba = cvf(bih0[l]) + cvf(bhh0[l]);
    wb = bl ? cvf(Wih0[64 + l]) : 0.f;
    bb = bl ? (cvf(bih0[64 + l]) + cvf(bhh0[64 + l])) : 0.f;
    ba2 = cvf(bih1[l]) + cvf(bhh1[l]);
    bb2 = bl ? (cvf(bih1[64 + l]) + cvf(bhh1[64 + l])) : 0.f;
#pragma unroll
    for (int j = 0; j < 21; j++) {
        Wa[j] = cvf(Whh0[l * 21 + j]);
        Wb[j] = bl ? cvf(Whh0[(64 + l) * 21 + j]) : 0.f;
        Ua[j] = cvf(Wih1[l * 21 + j]);
        Va[j] = cvf(Whh1[l * 21 + j]);
        Ub[j] = bl ? cvf(Wih1[(64 + l) * 21 + j]) : 0.f;
        Vb[j] = bl ? cvf(Whh1[(64 + l) * 21 + j]) : 0.f;
    }
}

__device__ __forceinline__ void warm_sweep(const void* p, int nbytes, int t2) {
    const uint4* s = (const uint4*)p;
    int nv = nbytes >> 4;
    unsigned acc = 0;
    for (int i = t2; i < nv; i += 1024) {
        uint4 v0 = s[i];
        uint4 v1 = (i + 128 < nv) ? s[i + 128] : make_uint4(0,0,0,0);
        uint4 v2 = (i + 256 < nv) ? s[i + 256] : make_uint4(0,0,0,0);
        uint4 v3 = (i + 384 < nv) ? s[i + 384] : make_uint4(0,0,0,0);
        uint4 v4 = (i + 512 < nv) ? s[i + 512] : make_uint4(0,0,0,0);
        uint4 v5 = (i + 640 < nv) ? s[i + 640] : make_uint4(0,0,0,0);
        uint4 v6 = (i + 768 < nv) ? s[i + 768] : make_uint4(0,0,0,0);
        uint4 v7 = (i + 896 < nv) ? s[i + 896] : make_uint4(0,0,0,0);
        acc ^= v0.x ^ v1.x ^ v2.x ^ v3.x ^ v4.x ^ v5.x ^ v6.x ^ v7.x;
    }
    asm volatile("" :: "v"(acc));
}

template<typename T>
__device__ __forceinline__ float matvec_t(const T* W, const float* vin,
                                          float bias, int n, int col, int ncol) {
    float acc = bias;
    int k2 = 0;
    for (; k2 + 8 <= n; k2 += 8) {
        float w0 = cvf(W[(k2 + 0) * ncol + col]);
        float w1 = cvf(W[(k2 + 1) * ncol + col]);
        float w2 = cvf(W[(k2 + 2) * ncol + col]);
        float w3 = cvf(W[(k2 + 3) * ncol + col]);
        float w4 = cvf(W[(k2 + 4) * ncol + col]);
        float w5 = cvf(W[(k2 + 5) * ncol + col]);
        float w6 = cvf(W[(k2 + 6) * ncol + col]);
        float w7 = cvf(W[(k2 + 7) * ncol + col]);
        acc += vin[k2 + 0] * w0; acc += vin[k2 + 1] * w1;
        acc += vin[k2 + 2] * w2; acc += vin[k2 + 3] * w3;
        acc += vin[k2 + 4] * w4; acc += vin[k2 + 5] * w5;
        acc += vin[k2 + 6] * w6; acc += vin[k2 + 7] * w7;
    }
    for (; k2 < n; k2++) acc += vin[k2] * cvf(W[k2 * ncol + col]);
    return acc;
}
__device__ __forceinline__ float matvec(const void* W, const float* vin,
                                        float bias, int n, int col, int ncol, int f) {
    return f ? matvec_t<float>((const float*)W, vin, bias, n, col, ncol)
             : matvec_t<bf16>((const bf16*)W, vin, bias, n, col, ncol);
}

__global__ __launch_bounds__(256, 1)
void k_tail(const void* trend, const void* seasonal, const void* residual,
                       const void* cv, const int* tgtp,
                       const void* tWih0, const void* tWhh0, const void* tbih0, const void* tbhh0,
                       const void* tWih1, const void* tWhh1, const void* tbih1, const void* tbhh1,
                       const void* sWih0, const void* sWhh0, const void* sbih0, const void* sbhh0,
                       const void* sWih1, const void* sWhh1, const void* sbih1, const void* sbhh1,
                       const void* res_W, const void* res_b,
                       const void* pg_W, const void* pg_b,
                       const void* f1_W, const void* f1_b,
                       const void* ln_g, const void* ln_b,
                       const void* f2_W, const void* f2_b,
                       const void* f3_W, const void* f3_b,
                       const int* flag, const float* A, void* out) {
    __shared__ __align__(16) float SH1[2][24];
    __shared__ __align__(16) float SH2[2][24];
    __shared__ float comb[97];
    __shared__ float gf[96];
    __shared__ float h1v[64];
    __shared__ float h2s[32];
    __shared__ float sbias[336];  // pg_b@0 f1_b@96 f2_b@160 f3_b@192 ln_g@208 ln_b@272
    __shared__ float stats[2];
    const int tid = threadIdx.x;
    const int f = flag[0];
    const int w = tid >> 6, l = tid & 63;

    if (tid < 96) {
        if (tid < 48) SH1[tid / 24][tid % 24] = 0.f;
        else { int u = tid - 48; SH2[u / 24][u % 24] = 0.f; }
    }
    __syncthreads();

    if (w < 2) {
        const void* Wih0 = w ? sWih0 : tWih0;
        const void* Whh0 = w ? sWhh0 : tWhh0;
        const void* bih0 = w ? sbih0 : tbih0;
        const void* bhh0 = w ? sbhh0 : tbhh0;
        const void* Wih1 = w ? sWih1 : tWih1;
        const void* Whh1 = w ? sWhh1 : tWhh1;
        const void* bih1 = w ? sbih1 : tbih1;
        const void* bhh1 = w ? sbhh1 : tbhh1;
        const void* xin  = w ? seasonal : trend;
        const bool bl = (l < 20);
        float xs[SEQL];
        float wa, ba, wb, bb, ba2, bb2;
        float Wa[21], Wb[21], Ua[21], Va[21], Ub[21], Vb[21];
        if (f) {
            lstm_load_regs<float>((const float*)Wih0, (const float*)Whh0,
                (const float*)bih0, (const float*)bhh0,
                (const float*)Wih1, (const float*)Whh1,
                (const float*)bih1, (const float*)bhh1,
                (const float*)xin, l, bl, xs, wa, ba, wb, bb, ba2, bb2,
                Wa, Wb, Ua, Va, Ub, Vb);
        } else {
            lstm_load_regs<bf16>((const bf16*)Wih0, (const bf16*)Whh0,
                (const bf16*)bih0, (const bf16*)bhh0,
                (const bf16*)Wih1, (const bf16*)Whh1,
                (const bf16*)bih1, (const bf16*)bhh1,
                (const bf16*)xin, l, bl, xs, wa, ba, wb, bb, ba2, bb2,
                Wa, Wb, Ua, Va, Ub, Vb);
        }
#pragma unroll
        for (int j = 0; j < 21; j++) {
            asm volatile("" : "+v"(Wa[j]), "+v"(Wb[j]));
            asm volatile("" : "+v"(Ua[j]), "+v"(Va[j]));
            asm volatile("" : "+v"(Ub[j]), "+v"(Vb[j]));
        }
#pragma unroll
        for (int t = 0; t < SEQL; t++) asm volatile("" : "+v"(xs[t]));
        asm volatile("" : "+v"(wa), "+v"(ba));
        asm volatile("" : "+v"(wb), "+v"(bb));
        asm volatile("" : "+v"(ba2), "+v"(bb2));

        float h1r = 0.f, c1v = 0.f, h2r = 0.f, c2v = 0.f;
#pragma unroll 1
        for (int t = 0; t < SEQL; t++) {
            float aa = ba + xs[t] * wa;
            float ab = bb + xs[t] * wb;
#pragma unroll
            for (int q = 0; q < 5; q++) {
                float4 v = *(const float4*)&SH1[w][q * 4];
                aa += v.x * Wa[q*4];   ab += v.x * Wb[q*4];
                aa += v.y * Wa[q*4+1]; ab += v.y * Wb[q*4+1];
                aa += v.z * Wa[q*4+2]; ab += v.z * Wb[q*4+2];
                aa += v.w * Wa[q*4+3]; ab += v.w * Wb[q*4+3];
            }
            { float v20 = SH1[w][20]; aa += v20 * Wa[20]; ab += v20 * Wb[20]; }
            float fj = __shfl(aa, 21 + l);
            float gj = __shfl(aa, 42 + l);
            float oa = __shfl(aa, 63);
            float ob = __shfl(ab, (l == 0) ? 0 : (l - 1));
            float oj = (l == 0) ? oa : ob;
            if (l < 21) {
                c1v = sigm(fj) * c1v + sigm(aa) * tanhf(gj);
                h1r = sigm(oj) * tanhf(c1v);
                SH1[w][l] = h1r;
            }
            __threadfence_block();
            float a2 = ba2, b2v = bb2;
#pragma unroll
            for (int q = 0; q < 5; q++) {
                float4 u = *(const float4*)&SH1[w][q * 4];
                float4 v = *(const float4*)&SH2[w][q * 4];
                a2  += u.x * Ua[q*4]   + v.x * Va[q*4];
                b2v += u.x * Ub[q*4]   + v.x * Vb[q*4];
                a2  += u.y * Ua[q*4+1] + v.y * Va[q*4+1];
                b2v += u.y * Ub[q*4+1] + v.y * Vb[q*4+1];
                a2  += u.z * Ua[q*4+2] + v.z * Va[q*4+2];
                b2v += u.z * Ub[q*4+2] + v.z * Vb[q*4+2];
                a2  += u.w * Ua[q*4+3] + v.w * Va[q*4+3];
                b2v += u.w * Ub[q*4+3] + v.w * Vb[q*4+3];
            }
            { float u20 = SH1[w][20], v20 = SH2[w][20];
              a2  += u20 * Ua[20] + v20 * Va[20];
              b2v += u20 * Ub[20] + v20 * Vb[20]; }
            float fj2 = __shfl(a2, 21 + l);
            float gj2 = __shfl(a2, 42 + l);
            float oa2 = __shfl(a2, 63);
            float ob2 = __shfl(b2v, (l == 0) ? 0 : (l - 1));
            float oj2 = (l == 0) ? oa2 : ob2;
            if (l < 21) {
                c2v = sigm(fj2) * c2v + sigm(a2) * tanhf(gj2);
                h2r = sigm(oj2) * tanhf(c2v);
                SH2[w][l] = h2r;
            }
            __threadfence_block();
        }
        if (l < 21) comb[(w == 0 ? 32 : 53) + l] = h2r;
    } else {
        int t2 = tid - 128;   // 0..127
        if (t2 < TRH)
            comb[74 + t2] = relu_nan(ldw(residual, SEQL - 1, f) * ldw(res_W, t2, f)
                                     + ldw(res_b, t2, f));
        if (t2 == TRH) comb[96] = ldw(cv, 0, f);
        if (t2 >= 32 && t2 < 64) {
            int tgt = tgtp[0];
            comb[t2 - 32] = A[(size_t)tgt * SHD + (t2 - 32)];
        }
        for (int i = t2; i < 336; i += 128) {
            float v;
            if (i < 96)       v = ldw(pg_b, i, f);
            else if (i < 160) v = ldw(f1_b, i - 96, f);
            else if (i < 192) v = ldw(f2_b, i - 160, f);
            else if (i < 206) v = ldw(f3_b, i - 192, f);
            else if (i < 208) v = 0.f;
            else if (i < 272) v = ldw(ln_g, i - 208, f);
            else              v = ldw(ln_b, i - 272, f);
            sbias[i] = v;
        }
        int esz = f ? 4 : 2;
        warm_sweep(pg_W, 9312 * esz, t2);
        warm_sweep(f1_W, 6144 * esz, t2);
        warm_sweep(f2_W, 2048 * esz, t2);
        warm_sweep(f3_W,  448 * esz, t2);
    }
    __syncthreads();

    if (tid < 96)
        gf[tid] = comb[tid] * sigm(matvec(pg_W, comb, sbias[tid], 97, tid, 96, f));
    __syncthreads();
    if (tid < 64)
        h1v[tid] = matvec(f1_W, gf, sbias[96 + tid], 96, tid, 64, f);
    __syncthreads();
    if (tid == 0) {
        float mu = 0.f;
        for (int j = 0; j < 64; j++) mu += h1v[j];
        mu /= 64.f;
        float var = 0.f;
        for (int j = 0; j < 64; j++) { float d = h1v[j] - mu; var += d * d; }
        var /= 64.f;
        stats[0] = mu; stats[1] = rsqrtf(var + 1e-5f);
    }
    __syncthreads();
    if (tid < 64)
        h1v[tid] = relu_nan((h1v[tid] - stats[0]) * stats[1] * sbias[208 + tid] + sbias[272 + tid]);
    __syncthreads();
    if (tid < 32)
        h2s[tid] = relu_nan(matvec(f2_W, h1v, sbias[160 + tid], 64, tid, 32, f));
    __syncthreads();
    if (tid < SEQL) {
        float acc = matvec(f3_W, h2s, sbias[192 + tid], 32, tid, 14, f);
        if (acc != acc) acc = 3333.0f;
        if (f) ((float*)out)[tid] = acc;
        else   ((bf16*)out)[tid] = __float2bfloat16(acc);
    }
}

// ---------------- host helpers ----------------
static inline unsigned short h_f2bf(float f) {
    union { float f; unsigned u; } x; x.f = f;
    return (unsigned short)(x.u >> 16);
}
static unsigned short g_diag[SEQL];

// ---------------- launch ----------------
extern "C" void kernel_launch(void* const* d_in, const int* in_sizes, int n_in,
                              void* d_out, int out_size, void* d_ws, size_t ws_size,
                              hipStream_t stream) {
    const int* ei  = (const int*)d_in[1];
    const int* tgt = (const int*)d_in[6];

    const size_t HWB  = sizeof(unsigned short) * (size_t)NN * SHD;
    const size_t EDB  = sizeof(float) * (size_t)NN * NH;
    const size_t AB   = sizeof(float) * (size_t)NN * SHD;
    // zeroed region: cnts(16) + bm1,bm2 (2*NBWP) + degB,fillB,degC,fillC (4N)
    const size_t ZER  = sizeof(int) * (size_t)(16 + 2 * NBWP + 4 * NN);
    const size_t RSTB = sizeof(int) * (size_t)(2 * NN);
    const size_t LSTB = sizeof(int) * (size_t)(2 * ECA + ECL1 + 8 + ECL2
                                               + 3 * ECB + 3 * ECC);
    const size_t NEED = 256 + 1024 + ZER + RSTB + LSTB + 512 + HWB + EDB + AB;
    if (ws_size < NEED) {
        for (int i = 0; i < SEQL; i++) g_diag[i] = h_f2bf(7777.0f);
        hipMemcpyAsync(d_out, g_diag, SEQL * sizeof(unsigned short),
                       hipMemcpyHostToDevice, stream);
        return;
    }

    char* p = (char*)d_ws;
    int*   flag = (int*)p;   p += 256;
    float* prm  = (float*)p; p += 1024;
    int* cnts  = (int*)p; p += sizeof(int) * 16;   // cA,c1,cB,c2,cC,c3
    unsigned* bm1 = (unsigned*)p; p += sizeof(int) * NBWP;
    unsigned* bm2 = (unsigned*)p; p += sizeof(int) * NBWP;
    int* degB  = (int*)p; p += sizeof(int) * NN;
    int* fillB = (int*)p; p += sizeof(int) * NN;
    int* degC  = (int*)p; p += sizeof(int) * NN;
    int* fillC = (int*)p; p += sizeof(int) * NN;
    int* rstartB = (int*)p; p += sizeof(int) * NN;
    int* rstartC = (int*)p; p += sizeof(int) * NN;
    int* eA   = (int*)p; p += sizeof(int) * ECA;
    int* eAd  = (int*)p; p += sizeof(int) * ECA;
    int* l1   = (int*)p; p += sizeof(int) * ECL1;
    int* l3   = (int*)p; p += sizeof(int) * 8;
    int* l2   = (int*)p; p += sizeof(int) * ECL2;
    int* eBs  = (int*)p; p += sizeof(int) * ECB;
    int* eBd  = (int*)p; p += sizeof(int) * ECB;
    int* csrB = (int*)p; p += sizeof(int) * ECB;
    int* eCs  = (int*)p; p += sizeof(int) * ECC;
    int* eCd  = (int*)p; p += sizeof(int) * ECC;
    int* csrC = (int*)p; p += sizeof(int) * ECC;
    p = (char*)(((uintptr_t)p + 255) & ~(uintptr_t)255);
    unsigned short* hWb = (unsigned short*)p; p += HWB;
    float* ed = (float*)p; p += EDB;
    float* A  = (float*)p; p += AB;
    int* cA = cnts; int* c1 = cnts + 1; int* cB = cnts + 2;
    int* c2 = cnts + 3; int* cC = cnts + 4; int* c3 = cnts + 5;

    dim3 b256(256);
    dim3 gN((NN + 255) / 256);
    dim3 gScan(NBC2);

    PatternAwareSTGAT_94489281309_kernel<<<dim3(1), dim3(64), 0, stream>>>(
        (const unsigned int*)d_in[0], flag,
        d_in[8], d_in[10], d_in[12], d_in[14], d_in[16], d_in[18], prm);

    hipMemsetAsync(cnts, 0, ZER, stream);

    // frontier build: chunked scans w/ LDS bitmap membership (k_p1 skeleton)
    k_scan2<<<gScan, b256, 0, stream>>>(ei, (const unsigned*)nullptr, tgt,
                                        eA, eAd, cA, (int*)nullptr, ECA);
    k_mark1<<<dim3(1), b256, 0, stream>>>(eA, cA, tgt, bm1, l1, c1, l3, c3);
    k_scan2<<<gScan, b256, 0, stream>>>(ei, bm1, tgt, eBs, eBd, cB, degB, ECB);
    k_prefix<<<dim3(1), b256, 0, stream>>>(l1, c1, ECL1, degB, rstartB,
                                           bm2, l2, c2, ECL2);
    k_scatter<<<dim3(64), b256, 0, stream>>>(eBs, eBd, cB, ECB, rstartB, fillB, csrB,
                                             bm2, l2, c2, ECL2);
    k_scan2<<<gScan, b256, 0, stream>>>(ei, bm2, tgt, eCs, eCd, cC, degC, ECC);
    k_prefix<<<dim3(1), b256, 0, stream>>>(l2, c2, ECL2, degC, rstartC,
                                           (unsigned*)nullptr, (int*)nullptr,
                                           (int*)nullptr, 0);
    k_scatter<<<dim3(512), b256, 0, stream>>>(eCs, eCd, cC, ECC, rstartC, fillC, csrC,
                                              (unsigned*)nullptr, (int*)nullptr,
                                              (int*)nullptr, 0);

    // GAT layers over the dependency cone
    k_transform0<<<gN, b256, 0, stream>>>(d_in[0], d_in[7], d_in[9], flag, hWb, ed);
    k_aggregate<<<dim3(ECL2 * 32 / 256), b256, 0, stream>>>(l2, c2, ECL2,
        rstartC, degC, csrC, (const int*)nullptr, 0, hWb, ed, prm, A);
    k_transform1<<<dim3(ECL2 / 256), b256, 0, stream>>>(l2, c2, ECL2,
        A, d_in[11], d_in[13], flag, hWb, ed);
    k_aggregate<<<dim3(ECL1 * 32 / 256), b256, 0, stream>>>(l1, c1, ECL1,
        rstartB, degB, csrB, (const int*)nullptr, 0, hWb, ed, prm + 64, A);
    k_transform1<<<dim3((ECL1 + 255) / 256), b256, 0, stream>>>(l1, c1, ECL1,
        A, d_in[15], d_in[17], flag, hWb, ed);
    k_aggregate<<<dim3(1), b256, 0, stream>>>(l3, c3, 8,
        (const int*)nullptr, (const int*)nullptr, eA, cA, ECA, hWb, ed, prm + 128, A);

    k_tail<<<dim3(1), b256, 0, stream>>>(
        d_in[2], d_in[3], d_in[4], d_in[5], tgt,
        d_in[19], d_in[20], d_in[21], d_in[22],
        d_in[23], d_in[24], d_in[25], d_in[26],
        d_in[27], d_in[28], d_in[29], d_in[30],
        d_in[31], d_in[32], d_in[33], d_in[34],
        d_in[35], d_in[36],
        d_in[37], d_in[38],
        d_in[39], d_in[40],
        d_in[41], d_in[42],
        d_in[43], d_in[44],
        d_in[45], d_in[46],
        flag, A, d_out);
}

// Round 13
// 296.037 us; speedup vs baseline: 2.0823x; 1.1614x over previous
//
#include <hip/hip_runtime.h>
#include <hip/hip_bf16.h>
#include <stdint.h>
#include <math.h>

#define NN   100000
#define EE   3200000
#define FIN  5
#define SHD  32
#define NH   8
#define TCH  21
#define TRH  22
#define SEQL 14

// frontier / filtered-edge capacities (dependency-cone pruning)
#define ECA   1024     // in-edges of tgt (layer-3 row)
#define ECL1  1024     // F1 node list
#define ECB   16384    // edges into F1 (layer-2 aggregation)
#define ECL2  8192     // F2 node list
#define ECC   131072   // edges into F2 (layer-1 aggregation)

// chunked scan geometry
#define BCHK2 4096
#define NBC2  ((EE + BCHK2 - 1) / BCHK2)
#define NBW   ((NN + 31) / 32)    // 3125 bitmap words
#define NBWP  3200                // padded (800 uint4)

typedef __hip_bfloat16 bf16;
typedef __attribute__((ext_vector_type(2))) float f32x2;

__device__ __forceinline__ float b2f(bf16 v) { return __bfloat162float(v); }
__device__ __forceinline__ float sigm(float x) { return 1.f / (1.f + __expf(-x)); }
__device__ __forceinline__ float ldw(const void* p, int i, int f) {
    return f ? ((const float*)p)[i] : __bfloat162float(((const bf16*)p)[i]);
}
__device__ __forceinline__ float relu_nan(float v) {
    return (v == v) ? ((v > 0.f) ? v : 0.f) : v;
}
__device__ __forceinline__ unsigned short f2b(float v) {
    bf16 b = __float2bfloat16(v);
    return *reinterpret_cast<unsigned short*>(&b);
}
__device__ __forceinline__ float cvf(float v) { return v; }
__device__ __forceinline__ float cvf(bf16 v) { return __bfloat162float(v); }
__device__ __forceinline__ void cp(float* dst, const void* src, int n,
                                   int t0, int stride, int f) {
    if (f) {
        const float* s = (const float*)src;
        for (int i = t0; i < n; i += stride) dst[i] = s[i];
    } else {
        const bf16* s = (const bf16*)src;
        for (int i = t0; i < n; i += stride) dst[i] = b2f(s[i]);
    }
}

// ---- dtype detect + f32 param pre-convert (identifier-named, 1 wave) ------
__global__ void PatternAwareSTGAT_94489281309_kernel(const unsigned int* xw, int* flag,
        const void* as0, const void* b0, const void* as1, const void* b1,
        const void* as2, const void* b2, float* prm) {
    int tid = threadIdx.x;   // 64
    int sane = 0;
    for (int i = 0; i < 64; i++) {
        unsigned int lo = xw[i] & 0xFFFFu;
        int e = (int)((lo >> 7) & 0xFF);
        if (e >= 110 && e <= 135) sane++;
    }
    int f = (sane >= 32) ? 0 : 1;
    if (tid == 0) flag[0] = f;
    const void* asp[3] = {as0, as1, as2};
    const void* bp[3]  = {b0, b1, b2};
    for (int l = 0; l < 3; l++)
        prm[l * 64 + tid] = (tid < 32) ? ldw(asp[l], tid, f) : ldw(bp[l], tid - 32, f);
}

// ---------------- Chunked filtered edge scan (round-13) ---------------------
// Round-12's version was still latency-bound (43us, VALU 3%, occ 16%):
// 16 un-unrolled dependent-load iterations/thread + 13 staging iterations +
// 46KB LDS capping occupancy at 3 blocks/CU. Fixes (all session-proven):
//  (a) each thread owns 16 contiguous edges as 4 independent int4 loads ->
//      ONE vmcnt drain (EE%16==0 so a thread is all-or-nothing);
//  (b) bitmap staged as 4 unrolled uint4 loads/thread -> one drain;
//  (c) ss/sd match-stage (32KB LDS) replaced by shfl block-prefix + direct
//      global writes -> LDS ~13KB -> 8 blocks/CU (wave-limited).
// bm == nullptr -> predicate is (d == tgt) (scan A).
__global__ __launch_bounds__(256) void k_scan2(
        const int* __restrict__ ei, const unsigned* __restrict__ bm,
        const int* __restrict__ tgtp,
        int* __restrict__ es, int* __restrict__ edd,
        int* __restrict__ cnt, int* __restrict__ deg, int cap) {
    __shared__ unsigned sbm[NBWP];
    __shared__ int wsum[4];
    __shared__ int sbase;
    int tid = threadIdx.x;
    const bool useBm = (bm != nullptr);
    int tgtv = useBm ? -1 : tgtp[0];
    if (useBm) {
        const uint4* b4 = (const uint4*)bm;
        uint4* s4 = (uint4*)sbm;
        uint4 t0 = b4[tid];
        uint4 t1 = b4[tid + 256];
        uint4 t2 = (tid + 512 < NBWP / 4) ? b4[tid + 512] : make_uint4(0,0,0,0);
        uint4 t3 = (tid + 768 < NBWP / 4) ? b4[tid + 768] : make_uint4(0,0,0,0);
        s4[tid] = t0;
        s4[tid + 256] = t1;
        if (tid + 512 < NBWP / 4) s4[tid + 512] = t2;
        if (tid + 768 < NBWP / 4) s4[tid + 768] = t3;
    }
    __syncthreads();

    int e0 = blockIdx.x * BCHK2 + tid * 16;
    unsigned mask = 0;
    int dv[16];
    if (e0 < EE) {   // EE%16==0 and e0%16==0 -> full 16 edges valid
        const int4* dd4 = (const int4*)(ei + EE + e0);
        int4 a = dd4[0];
        int4 b = dd4[1];
        int4 c = dd4[2];
        int4 d = dd4[3];
        dv[0]=a.x; dv[1]=a.y; dv[2]=a.z; dv[3]=a.w;
        dv[4]=b.x; dv[5]=b.y; dv[6]=b.z; dv[7]=b.w;
        dv[8]=c.x; dv[9]=c.y; dv[10]=c.z; dv[11]=c.w;
        dv[12]=d.x; dv[13]=d.y; dv[14]=d.z; dv[15]=d.w;
#pragma unroll
        for (int j = 0; j < 16; j++) {
            bool mm = useBm ? (((sbm[dv[j] >> 5] >> (dv[j] & 31)) & 1u) != 0u)
                            : (dv[j] == tgtv);
            if (mm) mask |= (1u << j);
        }
    }
    int m = __popc(mask);

    // exclusive block prefix of m (wave shfl + 4-entry LDS)
    int lane = tid & 63, wv = tid >> 6;
    int pre = m;
#pragma unroll
    for (int off = 1; off < 64; off <<= 1) {
        int v = __shfl_up(pre, off, 64);
        if (lane >= off) pre += v;
    }
    if (lane == 63) wsum[wv] = pre;
    __syncthreads();
    int wbase = 0;
#pragma unroll
    for (int q = 0; q < 4; q++) if (q < wv) wbase += wsum[q];
    int myoff = wbase + pre - m;
    if (tid == 0) {
        int tot = wsum[0] + wsum[1] + wsum[2] + wsum[3];
        sbase = (tot > 0) ? atomicAdd(cnt, tot) : 0;
    }
    __syncthreads();
    if (m > 0) {
        int off = sbase + myoff;
#pragma unroll
        for (int j = 0; j < 16; j++) {
            if (mask & (1u << j)) {
                int e = e0 + j;
                int dval = dv[j];
                int s = ei[e];
                if (off < cap) { es[off] = s; edd[off] = dval; }
                if (deg) atomicAdd(&deg[dval], 1);
                off++;
            }
        }
    }
}

// build F1 list (dedup via bitmap atomicOr) + seed l3 = {tgt}
__global__ void k_mark1(const int* __restrict__ eA, const int* __restrict__ cA,
                        const int* __restrict__ tgtp,
                        unsigned* __restrict__ bm1, int* __restrict__ l1,
                        int* __restrict__ c1,
                        int* __restrict__ l3, int* __restrict__ c3) {
    int n = cA[0]; if (n > ECA) n = ECA;
    for (int i = threadIdx.x; i < n; i += 256) {
        int s = eA[i];
        unsigned bit = 1u << (s & 31);
        unsigned old = atomicOr(&bm1[s >> 5], bit);
        if (!(old & bit)) {
            int p = atomicAdd(c1, 1);
            if (p < ECL1) l1[p] = s;
        }
    }
    if (threadIdx.x == 0) {
        int t = tgtp[0];
        unsigned bit = 1u << (t & 31);
        unsigned old = atomicOr(&bm1[t >> 5], bit);
        if (!(old & bit)) {
            int p = atomicAdd(c1, 1);
            if (p < ECL1) l1[p] = t;
        }
        l3[0] = t; c3[0] = 1;
    }
}

// exclusive prefix of deg over list -> rstart (LDS-chunked, 1 block);
// optionally seed next-level node set (bitmap + list).
__global__ void k_prefix(const int* __restrict__ list, const int* __restrict__ cp, int cap,
                         const int* __restrict__ deg, int* __restrict__ rstart,
                         unsigned* __restrict__ bmN, int* __restrict__ lN,
                         int* __restrict__ cN, int capN) {
    __shared__ int sdd[256];
    __shared__ int sbase;
    int n = cp[0]; if (n > cap) n = cap;
    if (threadIdx.x == 0) sbase = 0;
    __syncthreads();
    for (int b = 0; b < n; b += 256) {
        int i = b + threadIdx.x;
        int nd = (i < n) ? list[i] : -1;
        sdd[threadIdx.x] = (nd >= 0) ? deg[nd] : 0;
        __syncthreads();
        if (threadIdx.x == 0) {
            int acc = sbase;
            for (int j = 0; j < 256; j++) { int v = sdd[j]; sdd[j] = acc; acc += v; }
            sbase = acc;
        }
        __syncthreads();
        if (nd >= 0) rstart[nd] = sdd[threadIdx.x];
        __syncthreads();
    }
    if (bmN) {
        for (int i = threadIdx.x; i < n; i += 256) {
            int nd = list[i];
            unsigned bit = 1u << (nd & 31);
            unsigned old = atomicOr(&bmN[nd >> 5], bit);
            if (!(old & bit)) {
                int p = atomicAdd(cN, 1);
                if (p < capN) lN[p] = nd;
            }
        }
    }
}

// scatter filtered pairs into per-dst rows; optionally collect srcs into
// next-level node set (bitmap dedup).
__global__ __launch_bounds__(256) void k_scatter(const int* __restrict__ es,
                                                 const int* __restrict__ edd,
                                                 const int* __restrict__ cp, int cap,
                                                 const int* __restrict__ rstart,
                                                 int* __restrict__ fill, int* __restrict__ csr,
                                                 unsigned* __restrict__ bmN,
                                                 int* __restrict__ lN,
                                                 int* __restrict__ cN, int capN) {
    int m = cp[0]; if (m > cap) m = cap;
    for (int i = blockIdx.x * 256 + threadIdx.x; i < m; i += gridDim.x * 256) {
        int s = es[i], d = edd[i];
        int p = atomicAdd(&fill[d], 1);
        csr[rstart[d] + p] = s;
        if (bmN) {
            unsigned bit = 1u << (s & 31);
            unsigned old = atomicOr(&bmN[s >> 5], bit);
            if (!(old & bit)) {
                int q = atomicAdd(cN, 1);
                if (q < capN) lN[q] = s;
            }
        }
    }
}

// ---------------- GAT transform (layer 0: raw input, DIN=5, full N) ---------
__global__ void k_transform0(const void* x, const void* W, const void* ad_,
                             const int* flag, unsigned short* hWb, float* ed) {
    __shared__ float sW[FIN * SHD];
    __shared__ float sad[SHD];
    int tid = threadIdx.x;
    int f = flag[0];
    cp(sW, W, FIN * SHD, tid, 256, f);
    if (tid >= 192 && tid < 192 + SHD) sad[tid - 192] = ldw(ad_, tid - 192, f);
    __syncthreads();
    int n = blockIdx.x * 256 + tid;
    if (n >= NN) return;
    float xr[FIN];
    if (f) {
        const float* xp = (const float*)x + (size_t)n * FIN;
        for (int k = 0; k < FIN; k++) xr[k] = xp[k];
    } else {
        const bf16* xp = (const bf16*)x + (size_t)n * FIN;
        for (int k = 0; k < FIN; k++) xr[k] = b2f(xp[k]);
    }
    float o[SHD];
    for (int j = 0; j < SHD; j++) o[j] = 0.f;
    for (int k = 0; k < FIN; k++) {
        float xv = xr[k];
        for (int j = 0; j < SHD; j++) o[j] += xv * sW[k * SHD + j];
    }
    ushort4* row = (ushort4*)(hWb + (size_t)n * SHD);
    for (int q = 0; q < 8; q++) {
        ushort4 v; v.x = f2b(o[q*4]); v.y = f2b(o[q*4+1]); v.z = f2b(o[q*4+2]); v.w = f2b(o[q*4+3]);
        row[q] = v;
    }
    for (int h = 0; h < NH; h++) {
        float e2 = 0.f;
        for (int c = 0; c < 4; c++) e2 += o[h * 4 + c] * sad[h * 4 + c];
        ed[(size_t)n * NH + h] = e2;
    }
}

// ---------------- GAT transform (layers 2/3: list-driven, DIN=32) -----------
__global__ void k_transform1(const int* __restrict__ list, const int* __restrict__ cntp,
                             int cap,
                             const float* x, const void* W, const void* ad_,
                             const int* flag, unsigned short* hWb, float* ed) {
    __shared__ float sW[SHD * SHD];
    __shared__ float sad[SHD];
    int tid = threadIdx.x;
    int f = flag[0];
    cp(sW, W, SHD * SHD, tid, 256, f);
    if (tid >= 192 && tid < 192 + SHD) sad[tid - 192] = ldw(ad_, tid - 192, f);
    __syncthreads();
    int cnt = cntp[0]; if (cnt > cap) cnt = cap;
    int ii = blockIdx.x * 256 + tid;
    if (ii >= cnt) return;
    int n = list[ii];
    float xr[SHD];
    const float4* xp4 = (const float4*)(x + (size_t)n * SHD);
#pragma unroll
    for (int q = 0; q < 8; q++) {
        float4 v = xp4[q];
        xr[q*4] = v.x; xr[q*4+1] = v.y; xr[q*4+2] = v.z; xr[q*4+3] = v.w;
    }
    float o[SHD];
    for (int j = 0; j < SHD; j++) o[j] = 0.f;
    for (int k = 0; k < SHD; k++) {
        float xv = xr[k];
        for (int j = 0; j < SHD; j++) o[j] += xv * sW[k * SHD + j];
    }
    ushort4* row = (ushort4*)(hWb + (size_t)n * SHD);
    for (int q = 0; q < 8; q++) {
        ushort4 v; v.x = f2b(o[q*4]); v.y = f2b(o[q*4+1]); v.z = f2b(o[q*4+2]); v.w = f2b(o[q*4+3]);
        row[q] = v;
    }
    for (int h = 0; h < NH; h++) {
        float e2 = 0.f;
        for (int c = 0; c < 4; c++) e2 += o[h * 4 + c] * sad[h * 4 + c];
        ed[(size_t)n * NH + h] = e2;
    }
}

// ------- GAT aggregation: list-driven, 2 entries/wave, 6-deep pipeline ------
// ovr != null: single-row mode (base=0, deg=*ovr) for the layer-3 tgt row.
__global__ void k_aggregate(const int* __restrict__ list, const int* __restrict__ cntp,
                            int cap,
                            const int* __restrict__ rstart, const int* __restrict__ rdeg,
                            const int* __restrict__ csr,
                            const int* __restrict__ ovr, int ovrCap,
                            const unsigned short* __restrict__ hWb,
                            const float* __restrict__ ed,
                            const float* __restrict__ prm,
                            float* __restrict__ out) {
    int gid = blockIdx.x * 256 + threadIdx.x;
    int lane = threadIdx.x & 63;
    int cnt = cntp[0]; if (cnt > cap) cnt = cap;
    int idx = (gid >> 6) * 2 + (lane >> 5);
    if (idx >= cnt) return;
    int n = list[idx];
    int l32 = lane & 31;
    int h = l32 & 7, k = l32 >> 3;
    float4 asv = *(const float4*)(prm + h * 4);
    float ednh = ed[(size_t)n * NH + h];
    int base, deg;
    if (ovr) { base = 0; deg = ovr[0]; if (deg > ovrCap) deg = ovrCap; }
    else     { base = rstart[n]; deg = rdeg[n]; }
    float den = 0.f;
    f32x2 acc01 = {0.f, 0.f}, acc23 = {0.f, 0.f};
    int t = k;
    int s0 = -1, s1 = -1, s2 = -1, s3 = -1, s4 = -1, s5 = -1;
    if (t <= deg)      s0 = (t == 0) ? n : __builtin_nontemporal_load(csr + base + t - 1);
    if (t + 4 <= deg)  s1 = __builtin_nontemporal_load(csr + base + t + 3);
    if (t + 8 <= deg)  s2 = __builtin_nontemporal_load(csr + base + t + 7);
    if (t + 12 <= deg) s3 = __builtin_nontemporal_load(csr + base + t + 11);
    if (t + 16 <= deg) s4 = __builtin_nontemporal_load(csr + base + t + 15);
    if (t + 20 <= deg) s5 = __builtin_nontemporal_load(csr + base + t + 19);
    while (s0 >= 0) {
        uint2 hv0 = *(const uint2*)(hWb + (size_t)s0 * SHD + h * 4);
        bool b1 = (s1 >= 0), b2 = (s2 >= 0), b3 = (s3 >= 0), b4 = (s4 >= 0), b5 = (s5 >= 0);
        uint2 hv1, hv2, hv3, hv4, hv5;
        if (b1) hv1 = *(const uint2*)(hWb + (size_t)s1 * SHD + h * 4);
        if (b2) hv2 = *(const uint2*)(hWb + (size_t)s2 * SHD + h * 4);
        if (b3) hv3 = *(const uint2*)(hWb + (size_t)s3 * SHD + h * 4);
        if (b4) hv4 = *(const uint2*)(hWb + (size_t)s4 * SHD + h * 4);
        if (b5) hv5 = *(const uint2*)(hWb + (size_t)s5 * SHD + h * 4);
        int tn = t + 24;
        int p0 = -1, p1 = -1, p2 = -1, p3 = -1, p4 = -1, p5 = -1;
        if (tn <= deg)      p0 = __builtin_nontemporal_load(csr + base + tn - 1);
        if (tn + 4 <= deg)  p1 = __builtin_nontemporal_load(csr + base + tn + 3);
        if (tn + 8 <= deg)  p2 = __builtin_nontemporal_load(csr + base + tn + 7);
        if (tn + 12 <= deg) p3 = __builtin_nontemporal_load(csr + base + tn + 11);
        if (tn + 16 <= deg) p4 = __builtin_nontemporal_load(csr + base + tn + 15);
        if (tn + 20 <= deg) p5 = __builtin_nontemporal_load(csr + base + tn + 19);
        {
            f32x2 h01, h23;
            h01.x = __uint_as_float(hv0.x << 16);
            h01.y = __uint_as_float(hv0.x & 0xffff0000u);
            h23.x = __uint_as_float(hv0.y << 16);
            h23.y = __uint_as_float(hv0.y & 0xffff0000u);
            f32x2 d2 = h01 * (f32x2){asv.x, asv.y} + h23 * (f32x2){asv.z, asv.w};
            float e = d2.x + d2.y + ednh;
            e = fmaxf(e, 0.2f * e);
            float a = __expf(e);
            den += a;
            f32x2 av = {a, a};
            acc01 += av * h01;
            acc23 += av * h23;
        }
        if (b1) {
            f32x2 h01, h23;
            h01.x = __uint_as_float(hv1.x << 16);
            h01.y = __uint_as_float(hv1.x & 0xffff0000u);
            h23.x = __uint_as_float(hv1.y << 16);
            h23.y = __uint_as_float(hv1.y & 0xffff0000u);
            f32x2 d2 = h01 * (f32x2){asv.x, asv.y} + h23 * (f32x2){asv.z, asv.w};
            float e = d2.x + d2.y + ednh;
            e = fmaxf(e, 0.2f * e);
            float a = __expf(e);
            den += a;
            f32x2 av = {a, a};
            acc01 += av * h01;
            acc23 += av * h23;
        }
        if (b2) {
            f32x2 h01, h23;
            h01.x = __uint_as_float(hv2.x << 16);
            h01.y = __uint_as_float(hv2.x & 0xffff0000u);
            h23.x = __uint_as_float(hv2.y << 16);
            h23.y = __uint_as_float(hv2.y & 0xffff0000u);
            f32x2 d2 = h01 * (f32x2){asv.x, asv.y} + h23 * (f32x2){asv.z, asv.w};
            float e = d2.x + d2.y + ednh;
            e = fmaxf(e, 0.2f * e);
            float a = __expf(e);
            den += a;
            f32x2 av = {a, a};
            acc01 += av * h01;
            acc23 += av * h23;
        }
        if (b3) {
            f32x2 h01, h23;
            h01.x = __uint_as_float(hv3.x << 16);
            h01.y = __uint_as_float(hv3.x & 0xffff0000u);
            h23.x = __uint_as_float(hv3.y << 16);
            h23.y = __uint_as_float(hv3.y & 0xffff0000u);
            f32x2 d2 = h01 * (f32x2){asv.x, asv.y} + h23 * (f32x2){asv.z, asv.w};
            float e = d2.x + d2.y + ednh;
            e = fmaxf(e, 0.2f * e);
            float a = __expf(e);
            den += a;
            f32x2 av = {a, a};
            acc01 += av * h01;
            acc23 += av * h23;
        }
        if (b4) {
            f32x2 h01, h23;
            h01.x = __uint_as_float(hv4.x << 16);
            h01.y = __uint_as_float(hv4.x & 0xffff0000u);
            h23.x = __uint_as_float(hv4.y << 16);
            h23.y = __uint_as_float(hv4.y & 0xffff0000u);
            f32x2 d2 = h01 * (f32x2){asv.x, asv.y} + h23 * (f32x2){asv.z, asv.w};
            float e = d2.x + d2.y + ednh;
            e = fmaxf(e, 0.2f * e);
            float a = __expf(e);
            den += a;
            f32x2 av = {a, a};
            acc01 += av * h01;
            acc23 += av * h23;
        }
        if (b5) {
            f32x2 h01, h23;
            h01.x = __uint_as_float(hv5.x << 16);
            h01.y = __uint_as_float(hv5.x & 0xffff0000u);
            h23.x = __uint_as_float(hv5.y << 16);
            h23.y = __uint_as_float(hv5.y & 0xffff0000u);
            f32x2 d2 = h01 * (f32x2){asv.x, asv.y} + h23 * (f32x2){asv.z, asv.w};
            float e = d2.x + d2.y + ednh;
            e = fmaxf(e, 0.2f * e);
            float a = __expf(e);
            den += a;
            f32x2 av = {a, a};
            acc01 += av * h01;
            acc23 += av * h23;
        }
        s0 = p0; s1 = p1; s2 = p2; s3 = p3; s4 = p4; s5 = p5; t = tn;
    }
    for (int off = 16; off >= 8; off >>= 1) {
        den      += __shfl_down(den, off, 32);
        acc01.x  += __shfl_down(acc01.x, off, 32);
        acc01.y  += __shfl_down(acc01.y, off, 32);
        acc23.x  += __shfl_down(acc23.x, off, 32);
        acc23.y  += __shfl_down(acc23.y, off, 32);
    }
    if (k == 0) {
        float inv = 1.f / (den + 1e-16f);
        float4 bv = *(const float4*)(prm + 32 + h * 4);
        float v0 = acc01.x * inv + bv.x;
        float v1 = acc01.y * inv + bv.y;
        float v2 = acc23.x * inv + bv.z;
        float v3 = acc23.y * inv + bv.w;
        v0 = (v0 > 0.f) ? v0 : expm1f(v0);
        v1 = (v1 > 0.f) ? v1 : expm1f(v1);
        v2 = (v2 > 0.f) ? v2 : expm1f(v2);
        v3 = (v3 > 0.f) ? v3 : expm1f(v3);
        *(float4*)(out + (size_t)n * SHD + h * 4) = make_float4(v0, v1, v2, v3);
    }
}

// ---------------- Temporal tail ---------------------------------------------
// Round-5-verified design. LSTM weights pinned in registers via asm("+v")
// (defeats remat); L2 warm sweep + MLP matvecs use 8-wide batched loads.
template<typename T>
__device__ __forceinline__ void lstm_load_regs(
        const T* Wih0, const T* Whh0, const T* bih0, const T* bhh0,
        const T* Wih1, const T* Whh1, const T* bih1, const T* bhh1,
        const T* xin, int l, bool bl, float* xs,
        float& wa, float& ba, float& wb, float& bb, float& ba2, float& bb2,
        float* Wa, float* Wb, float* Ua, float* Va, float* Ub, float* Vb) {
#pragma unroll
    for (int t = 0; t < SEQL; t++) xs[t] = cvf(xin[t]);
    wa = cvf(Wih0[l]);
    ba = cvf(bih0[l]) + cvf(bhh0[l]);
    wb = bl ? cvf(Wih0[64 + l]) : 0.f;
    bb = bl ? (cvf(bih0[64 + l]) + cvf(bhh0[64 + l])) : 0.f;
    ba2 = cvf(bih1[l]) + cvf(bhh1[l]);
    bb2 = bl ? (cvf(bih1[64 + l]) + cvf(bhh1[64 + l])) : 0.f;
#pragma unroll
    for (int j = 0; j < 21; j++) {
        Wa[j] = cvf(Whh0[l * 21 + j]);
        Wb[j] = bl ? cvf(Whh0[(64 + l) * 21 + j]) : 0.f;
        Ua[j] = cvf(Wih1[l * 21 + j]);
        Va[j] = cvf(Whh1[l * 21 + j]);
        Ub[j] = bl ? cvf(Wih1[(64 + l) * 21 + j]) : 0.f;
        Vb[j] = bl ? cvf(Whh1[(64 + l) * 21 + j]) : 0.f;
    }
}

__device__ __forceinline__ void warm_sweep(const void* p, int nbytes, int t2) {
    const uint4* s = (const uint4*)p;
    int nv = nbytes >> 4;
    unsigned acc = 0;
    for (int i = t2; i < nv; i += 1024) {
        uint4 v0 = s[i];
        uint4 v1 = (i + 128 < nv) ? s[i + 128] : make_uint4(0,0,0,0);
        uint4 v2 = (i + 256 < nv) ? s[i + 256] : make_uint4(0,0,0,0);
        uint4 v3 = (i + 384 < nv) ? s[i + 384] : make_uint4(0,0,0,0);
        uint4 v4 = (i + 512 < nv) ? s[i + 512] : make_uint4(0,0,0,0);
        uint4 v5 = (i + 640 < nv) ? s[i + 640] : make_uint4(0,0,0,0);
        uint4 v6 = (i + 768 < nv) ? s[i + 768] : make_uint4(0,0,0,0);
        uint4 v7 = (i + 896 < nv) ? s[i + 896] : make_uint4(0,0,0,0);
        acc ^= v0.x ^ v1.x ^ v2.x ^ v3.x ^ v4.x ^ v5.x ^ v6.x ^ v7.x;
    }
    asm volatile("" :: "v"(acc));
}

template<typename T>
__device__ __forceinline__ float matvec_t(const T* W, const float* vin,
                                          float bias, int n, int col, int ncol) {
    float acc = bias;
    int k2 = 0;
    for (; k2 + 8 <= n; k2 += 8) {
        float w0 = cvf(W[(k2 + 0) * ncol + col]);
        float w1 = cvf(W[(k2 + 1) * ncol + col]);
        float w2 = cvf(W[(k2 + 2) * ncol + col]);
        float w3 = cvf(W[(k2 + 3) * ncol + col]);
        float w4 = cvf(W[(k2 + 4) * ncol + col]);
        float w5 = cvf(W[(k2 + 5) * ncol + col]);
        float w6 = cvf(W[(k2 + 6) * ncol + col]);
        float w7 = cvf(W[(k2 + 7) * ncol + col]);
        acc += vin[k2 + 0] * w0; acc += vin[k2 + 1] * w1;
        acc += vin[k2 + 2] * w2; acc += vin[k2 + 3] * w3;
        acc += vin[k2 + 4] * w4; acc += vin[k2 + 5] * w5;
        acc += vin[k2 + 6] * w6; acc += vin[k2 + 7] * w7;
    }
    for (; k2 < n; k2++) acc += vin[k2] * cvf(W[k2 * ncol + col]);
    return acc;
}
__device__ __forceinline__ float matvec(const void* W, const float* vin,
                                        float bias, int n, int col, int ncol, int f) {
    return f ? matvec_t<float>((const float*)W, vin, bias, n, col, ncol)
             : matvec_t<bf16>((const bf16*)W, vin, bias, n, col, ncol);
}

__global__ __launch_bounds__(256, 1)
void k_tail(const void* trend, const void* seasonal, const void* residual,
                       const void* cv, const int* tgtp,
                       const void* tWih0, const void* tWhh0, const void* tbih0, const void* tbhh0,
                       const void* tWih1, const void* tWhh1, const void* tbih1, const void* tbhh1,
                       const void* sWih0, const void* sWhh0, const void* sbih0, const void* sbhh0,
                       const void* sWih1, const void* sWhh1, const void* sbih1, const void* sbhh1,
                       const void* res_W, const void* res_b,
                       const void* pg_W, const void* pg_b,
                       const void* f1_W, const void* f1_b,
                       const void* ln_g, const void* ln_b,
                       const void* f2_W, const void* f2_b,
                       const void* f3_W, const void* f3_b,
                       const int* flag, const float* A, void* out) {
    __shared__ __align__(16) float SH1[2][24];
    __shared__ __align__(16) float SH2[2][24];
    __shared__ float comb[97];
    __shared__ float gf[96];
    __shared__ float h1v[64];
    __shared__ float h2s[32];
    __shared__ float sbias[336];  // pg_b@0 f1_b@96 f2_b@160 f3_b@192 ln_g@208 ln_b@272
    __shared__ float stats[2];
    const int tid = threadIdx.x;
    const int f = flag[0];
    const int w = tid >> 6, l = tid & 63;

    if (tid < 96) {
        if (tid < 48) SH1[tid / 24][tid % 24] = 0.f;
        else { int u = tid - 48; SH2[u / 24][u % 24] = 0.f; }
    }
    __syncthreads();

    if (w < 2) {
        const void* Wih0 = w ? sWih0 : tWih0;
        const void* Whh0 = w ? sWhh0 : tWhh0;
        const void* bih0 = w ? sbih0 : tbih0;
        const void* bhh0 = w ? sbhh0 : tbhh0;
        const void* Wih1 = w ? sWih1 : tWih1;
        const void* Whh1 = w ? sWhh1 : tWhh1;
        const void* bih1 = w ? sbih1 : tbih1;
        const void* bhh1 = w ? sbhh1 : tbhh1;
        const void* xin  = w ? seasonal : trend;
        const bool bl = (l < 20);
        float xs[SEQL];
        float wa, ba, wb, bb, ba2, bb2;
        float Wa[21], Wb[21], Ua[21], Va[21], Ub[21], Vb[21];
        if (f) {
            lstm_load_regs<float>((const float*)Wih0, (const float*)Whh0,
                (const float*)bih0, (const float*)bhh0,
                (const float*)Wih1, (const float*)Whh1,
                (const float*)bih1, (const float*)bhh1,
                (const float*)xin, l, bl, xs, wa, ba, wb, bb, ba2, bb2,
                Wa, Wb, Ua, Va, Ub, Vb);
        } else {
            lstm_load_regs<bf16>((const bf16*)Wih0, (const bf16*)Whh0,
                (const bf16*)bih0, (const bf16*)bhh0,
                (const bf16*)Wih1, (const bf16*)Whh1,
                (const bf16*)bih1, (const bf16*)bhh1,
                (const bf16*)xin, l, bl, xs, wa, ba, wb, bb, ba2, bb2,
                Wa, Wb, Ua, Va, Ub, Vb);
        }
#pragma unroll
        for (int j = 0; j < 21; j++) {
            asm volatile("" : "+v"(Wa[j]), "+v"(Wb[j]));
            asm volatile("" : "+v"(Ua[j]), "+v"(Va[j]));
            asm volatile("" : "+v"(Ub[j]), "+v"(Vb[j]));
        }
#pragma unroll
        for (int t = 0; t < SEQL; t++) asm volatile("" : "+v"(xs[t]));
        asm volatile("" : "+v"(wa), "+v"(ba));
        asm volatile("" : "+v"(wb), "+v"(bb));
        asm volatile("" : "+v"(ba2), "+v"(bb2));

        float h1r = 0.f, c1v = 0.f, h2r = 0.f, c2v = 0.f;
#pragma unroll 1
        for (int t = 0; t < SEQL; t++) {
            float aa = ba + xs[t] * wa;
            float ab = bb + xs[t] * wb;
#pragma unroll
            for (int q = 0; q < 5; q++) {
                float4 v = *(const float4*)&SH1[w][q * 4];
                aa += v.x * Wa[q*4];   ab += v.x * Wb[q*4];
                aa += v.y * Wa[q*4+1]; ab += v.y * Wb[q*4+1];
                aa += v.z * Wa[q*4+2]; ab += v.z * Wb[q*4+2];
                aa += v.w * Wa[q*4+3]; ab += v.w * Wb[q*4+3];
            }
            { float v20 = SH1[w][20]; aa += v20 * Wa[20]; ab += v20 * Wb[20]; }
            float fj = __shfl(aa, 21 + l);
            float gj = __shfl(aa, 42 + l);
            float oa = __shfl(aa, 63);
            float ob = __shfl(ab, (l == 0) ? 0 : (l - 1));
            float oj = (l == 0) ? oa : ob;
            if (l < 21) {
                c1v = sigm(fj) * c1v + sigm(aa) * tanhf(gj);
                h1r = sigm(oj) * tanhf(c1v);
                SH1[w][l] = h1r;
            }
            __threadfence_block();
            float a2 = ba2, b2v = bb2;
#pragma unroll
            for (int q = 0; q < 5; q++) {
                float4 u = *(const float4*)&SH1[w][q * 4];
                float4 v = *(const float4*)&SH2[w][q * 4];
                a2  += u.x * Ua[q*4]   + v.x * Va[q*4];
                b2v += u.x * Ub[q*4]   + v.x * Vb[q*4];
                a2  += u.y * Ua[q*4+1] + v.y * Va[q*4+1];
                b2v += u.y * Ub[q*4+1] + v.y * Vb[q*4+1];
                a2  += u.z * Ua[q*4+2] + v.z * Va[q*4+2];
                b2v += u.z * Ub[q*4+2] + v.z * Vb[q*4+2];
                a2  += u.w * Ua[q*4+3] + v.w * Va[q*4+3];
                b2v += u.w * Ub[q*4+3] + v.w * Vb[q*4+3];
            }
            { float u20 = SH1[w][20], v20 = SH2[w][20];
              a2  += u20 * Ua[20] + v20 * Va[20];
              b2v += u20 * Ub[20] + v20 * Vb[20]; }
            float fj2 = __shfl(a2, 21 + l);
            float gj2 = __shfl(a2, 42 + l);
            float oa2 = __shfl(a2, 63);
            float ob2 = __shfl(b2v, (l == 0) ? 0 : (l - 1));
            float oj2 = (l == 0) ? oa2 : ob2;
            if (l < 21) {
                c2v = sigm(fj2) * c2v + sigm(a2) * tanhf(gj2);
                h2r = sigm(oj2) * tanhf(c2v);
                SH2[w][l] = h2r;
            }
            __threadfence_block();
        }
        if (l < 21) comb[(w == 0 ? 32 : 53) + l] = h2r;
    } else {
        int t2 = tid - 128;   // 0..127
        if (t2 < TRH)
            comb[74 + t2] = relu_nan(ldw(residual, SEQL - 1, f) * ldw(res_W, t2, f)
                                     + ldw(res_b, t2, f));
        if (t2 == TRH) comb[96] = ldw(cv, 0, f);
        if (t2 >= 32 && t2 < 64) {
            int tgt = tgtp[0];
            comb[t2 - 32] = A[(size_t)tgt * SHD + (t2 - 32)];
        }
        for (int i = t2; i < 336; i += 128) {
            float v;
            if (i < 96)       v = ldw(pg_b, i, f);
            else if (i < 160) v = ldw(f1_b, i - 96, f);
            else if (i < 192) v = ldw(f2_b, i - 160, f);
            else if (i < 206) v = ldw(f3_b, i - 192, f);
            else if (i < 208) v = 0.f;
            else if (i < 272) v = ldw(ln_g, i - 208, f);
            else              v = ldw(ln_b, i - 272, f);
            sbias[i] = v;
        }
        int esz = f ? 4 : 2;
        warm_sweep(pg_W, 9312 * esz, t2);
        warm_sweep(f1_W, 6144 * esz, t2);
        warm_sweep(f2_W, 2048 * esz, t2);
        warm_sweep(f3_W,  448 * esz, t2);
    }
    __syncthreads();

    if (tid < 96)
        gf[tid] = comb[tid] * sigm(matvec(pg_W, comb, sbias[tid], 97, tid, 96, f));
    __syncthreads();
    if (tid < 64)
        h1v[tid] = matvec(f1_W, gf, sbias[96 + tid], 96, tid, 64, f);
    __syncthreads();
    if (tid == 0) {
        float mu = 0.f;
        for (int j = 0; j < 64; j++) mu += h1v[j];
        mu /= 64.f;
        float var = 0.f;
        for (int j = 0; j < 64; j++) { float d = h1v[j] - mu; var += d * d; }
        var /= 64.f;
        stats[0] = mu; stats[1] = rsqrtf(var + 1e-5f);
    }
    __syncthreads();
    if (tid < 64)
        h1v[tid] = relu_nan((h1v[tid] - stats[0]) * stats[1] * sbias[208 + tid] + sbias[272 + tid]);
    __syncthreads();
    if (tid < 32)
        h2s[tid] = relu_nan(matvec(f2_W, h1v, sbias[160 + tid], 64, tid, 32, f));
    __syncthreads();
    if (tid < SEQL) {
        float acc = matvec(f3_W, h2s, sbias[192 + tid], 32, tid, 14, f);
        if (acc != acc) acc = 3333.0f;
        if (f) ((float*)out)[tid] = acc;
        else   ((bf16*)out)[tid] = __float2bfloat16(acc);
    }
}

// ---------------- host helpers ----------------
static inline unsigned short h_f2bf(float f) {
    union { float f; unsigned u; } x; x.f = f;
    return (unsigned short)(x.u >> 16);
}
static unsigned short g_diag[SEQL];

// ---------------- launch ----------------
extern "C" void kernel_launch(void* const* d_in, const int* in_sizes, int n_in,
                              void* d_out, int out_size, void* d_ws, size_t ws_size,
                              hipStream_t stream) {
    const int* ei  = (const int*)d_in[1];
    const int* tgt = (const int*)d_in[6];

    const size_t HWB  = sizeof(unsigned short) * (size_t)NN * SHD;
    const size_t EDB  = sizeof(float) * (size_t)NN * NH;
    const size_t AB   = sizeof(float) * (size_t)NN * SHD;
    // zeroed region: cnts(16) + bm1,bm2 (2*NBWP) + degB,fillB,degC,fillC (4N)
    const size_t ZER  = sizeof(int) * (size_t)(16 + 2 * NBWP + 4 * NN);
    const size_t RSTB = sizeof(int) * (size_t)(2 * NN);
    const size_t LSTB = sizeof(int) * (size_t)(2 * ECA + ECL1 + 8 + ECL2
                                               + 3 * ECB + 3 * ECC);
    const size_t NEED = 256 + 1024 + ZER + RSTB + LSTB + 512 + HWB + EDB + AB;
    if (ws_size < NEED) {
        for (int i = 0; i < SEQL; i++) g_diag[i] = h_f2bf(7777.0f);
        hipMemcpyAsync(d_out, g_diag, SEQL * sizeof(unsigned short),
                       hipMemcpyHostToDevice, stream);
        return;
    }

    char* p = (char*)d_ws;
    int*   flag = (int*)p;   p += 256;
    float* prm  = (float*)p; p += 1024;
    int* cnts  = (int*)p; p += sizeof(int) * 16;   // cA,c1,cB,c2,cC,c3
    unsigned* bm1 = (unsigned*)p; p += sizeof(int) * NBWP;
    unsigned* bm2 = (unsigned*)p; p += sizeof(int) * NBWP;
    int* degB  = (int*)p; p += sizeof(int) * NN;
    int* fillB = (int*)p; p += sizeof(int) * NN;
    int* degC  = (int*)p; p += sizeof(int) * NN;
    int* fillC = (int*)p; p += sizeof(int) * NN;
    int* rstartB = (int*)p; p += sizeof(int) * NN;
    int* rstartC = (int*)p; p += sizeof(int) * NN;
    int* eA   = (int*)p; p += sizeof(int) * ECA;
    int* eAd  = (int*)p; p += sizeof(int) * ECA;
    int* l1   = (int*)p; p += sizeof(int) * ECL1;
    int* l3   = (int*)p; p += sizeof(int) * 8;
    int* l2   = (int*)p; p += sizeof(int) * ECL2;
    int* eBs  = (int*)p; p += sizeof(int) * ECB;
    int* eBd  = (int*)p; p += sizeof(int) * ECB;
    int* csrB = (int*)p; p += sizeof(int) * ECB;
    int* eCs  = (int*)p; p += sizeof(int) * ECC;
    int* eCd  = (int*)p; p += sizeof(int) * ECC;
    int* csrC = (int*)p; p += sizeof(int) * ECC;
    p = (char*)(((uintptr_t)p + 255) & ~(uintptr_t)255);
    unsigned short* hWb = (unsigned short*)p; p += HWB;
    float* ed = (float*)p; p += EDB;
    float* A  = (float*)p; p += AB;
    int* cA = cnts; int* c1 = cnts + 1; int* cB = cnts + 2;
    int* c2 = cnts + 3; int* cC = cnts + 4; int* c3 = cnts + 5;

    dim3 b256(256);
    dim3 gN((NN + 255) / 256);
    dim3 gScan(NBC2);

    PatternAwareSTGAT_94489281309_kernel<<<dim3(1), dim3(64), 0, stream>>>(
        (const unsigned int*)d_in[0], flag,
        d_in[8], d_in[10], d_in[12], d_in[14], d_in[16], d_in[18], prm);

    hipMemsetAsync(cnts, 0, ZER, stream);

    // frontier build: chunked scans w/ LDS bitmap membership
    k_scan2<<<gScan, b256, 0, stream>>>(ei, (const unsigned*)nullptr, tgt,
                                        eA, eAd, cA, (int*)nullptr, ECA);
    k_mark1<<<dim3(1), b256, 0, stream>>>(eA, cA, tgt, bm1, l1, c1, l3, c3);
    k_scan2<<<gScan, b256, 0, stream>>>(ei, bm1, tgt, eBs, eBd, cB, degB, ECB);
    k_prefix<<<dim3(1), b256, 0, stream>>>(l1, c1, ECL1, degB, rstartB,
                                           bm2, l2, c2, ECL2);
    k_scatter<<<dim3(64), b256, 0, stream>>>(eBs, eBd, cB, ECB, rstartB, fillB, csrB,
                                             bm2, l2, c2, ECL2);
    k_scan2<<<gScan, b256, 0, stream>>>(ei, bm2, tgt, eCs, eCd, cC, degC, ECC);
    k_prefix<<<dim3(1), b256, 0, stream>>>(l2, c2, ECL2, degC, rstartC,
                                           (unsigned*)nullptr, (int*)nullptr,
                                           (int*)nullptr, 0);
    k_scatter<<<dim3(512), b256, 0, stream>>>(eCs, eCd, cC, ECC, rstartC, fillC, csrC,
                                              (unsigned*)nullptr, (int*)nullptr,
                                              (int*)nullptr, 0);

    // GAT layers over the dependency cone
    k_transform0<<<gN, b256, 0, stream>>>(d_in[0], d_in[7], d_in[9], flag, hWb, ed);
    k_aggregate<<<dim3(ECL2 * 32 / 256), b256, 0, stream>>>(l2, c2, ECL2,
        rstartC, degC, csrC, (const int*)nullptr, 0, hWb, ed, prm, A);
    k_transform1<<<dim3(ECL2 / 256), b256, 0, stream>>>(l2, c2, ECL2,
        A, d_in[11], d_in[13], flag, hWb, ed);
    k_aggregate<<<dim3(ECL1 * 32 / 256), b256, 0, stream>>>(l1, c1, ECL1,
        rstartB, degB, csrB, (const int*)nullptr, 0, hWb, ed, prm + 64, A);
    k_transform1<<<dim3((ECL1 + 255) / 256), b256, 0, stream>>>(l1, c1, ECL1,
        A, d_in[15], d_in[17], flag, hWb, ed);
    k_aggregate<<<dim3(1), b256, 0, stream>>>(l3, c3, 8,
        (const int*)nullptr, (const int*)nullptr, eA, cA, ECA, hWb, ed, prm + 128, A);

    k_tail<<<dim3(1), b256, 0, stream>>>(
        d_in[2], d_in[3], d_in[4], d_in[5], tgt,
        d_in[19], d_in[20], d_in[21], d_in[22],
        d_in[23], d_in[24], d_in[25], d_in[26],
        d_in[27], d_in[28], d_in[29], d_in[30],
        d_in[31], d_in[32], d_in[33], d_in[34],
        d_in[35], d_in[36],
        d_in[37], d_in[38],
        d_in[39], d_in[40],
        d_in[41], d_in[42],
        d_in[43], d_in[44],
        d_in[45], d_in[46],
        flag, A, d_out);
}

// Round 14
// 255.565 us; speedup vs baseline: 2.4120x; 1.1584x over previous
//
#include <hip/hip_runtime.h>
#include <hip/hip_bf16.h>
#include <stdint.h>
#include <math.h>

#define NN   100000
#define EE   3200000
#define FIN  5
#define SHD  32
#define NH   8
#define TCH  21
#define TRH  22
#define SEQL 14

// frontier capacities (dependency-cone pruning)
#define ECA   1024     // in-edges of tgt (layer-3 row)
#define ECL1  1024     // F1 node list
#define ECL2  8192     // F2 node list
#define RSTR  96       // per-node row stride (graph max in-deg ~59 << 96)

// chunked scan geometry
#define BCHK2 4096
#define NBC2  ((EE + BCHK2 - 1) / BCHK2)
#define NBW   ((NN + 31) / 32)    // 3125 bitmap words
#define NBWP  3200                // padded (800 uint4)

typedef __hip_bfloat16 bf16;
typedef __attribute__((ext_vector_type(2))) float f32x2;

__device__ __forceinline__ float b2f(bf16 v) { return __bfloat162float(v); }
__device__ __forceinline__ float sigm(float x) { return 1.f / (1.f + __expf(-x)); }
__device__ __forceinline__ float ldw(const void* p, int i, int f) {
    return f ? ((const float*)p)[i] : __bfloat162float(((const bf16*)p)[i]);
}
__device__ __forceinline__ float relu_nan(float v) {
    return (v == v) ? ((v > 0.f) ? v : 0.f) : v;
}
__device__ __forceinline__ unsigned short f2b(float v) {
    bf16 b = __float2bfloat16(v);
    return *reinterpret_cast<unsigned short*>(&b);
}
__device__ __forceinline__ float cvf(float v) { return v; }
__device__ __forceinline__ float cvf(bf16 v) { return __bfloat162float(v); }
__device__ __forceinline__ void cp(float* dst, const void* src, int n,
                                   int t0, int stride, int f) {
    if (f) {
        const float* s = (const float*)src;
        for (int i = t0; i < n; i += stride) dst[i] = s[i];
    } else {
        const bf16* s = (const bf16*)src;
        for (int i = t0; i < n; i += stride) dst[i] = b2f(s[i]);
    }
}

// ---- dtype detect + f32 param pre-convert (identifier-named, 1 wave) ------
__global__ void PatternAwareSTGAT_94489281309_kernel(const unsigned int* xw, int* flag,
        const void* as0, const void* b0, const void* as1, const void* b1,
        const void* as2, const void* b2, float* prm) {
    int tid = threadIdx.x;   // 64
    int sane = 0;
    for (int i = 0; i < 64; i++) {
        unsigned int lo = xw[i] & 0xFFFFu;
        int e = (int)((lo >> 7) & 0xFF);
        if (e >= 110 && e <= 135) sane++;
    }
    int f = (sane >= 32) ? 0 : 1;
    if (tid == 0) flag[0] = f;
    const void* asp[3] = {as0, as1, as2};
    const void* bp[3]  = {b0, b1, b2};
    for (int l = 0; l < 3; l++)
        prm[l * 64 + tid] = (tid < 32) ? ldw(asp[l], tid, f) : ldw(bp[l], tid - 32, f);
}

// ---------------- Fused frontier scans (round-14) ---------------------------
// Round-13's scan fix worked (scans off top-5); the remaining frontier cost
// is 5 serialized bookkeeping dispatches (mark1, prefix x2, scatter x2).
// Fold everything into the scans: scanA seeds bm1/l1 AND bm2/l2 (F1<=F2) via
// atomicOr dedup; scanB/C scatter matched edges DIRECTLY into fixed-stride
// per-node rows (rows[d*96 + fill[d]++]), killing the prefix/scatter pair.
// Stride 96 >> graph max in-degree (~59). Row order = atomic-append,
// nondeterministic — same property as all 13 passing rounds.
__global__ __launch_bounds__(256) void k_scanA(
        const int* __restrict__ ei, const int* __restrict__ tgtp,
        int* __restrict__ eA, int* __restrict__ cA,
        unsigned* __restrict__ bm1, int* __restrict__ l1, int* __restrict__ c1,
        unsigned* __restrict__ bm2, int* __restrict__ l2, int* __restrict__ c2,
        int* __restrict__ l3, int* __restrict__ c3) {
    int tid = threadIdx.x;
    int tgtv = tgtp[0];
    if (blockIdx.x == 0 && tid == 0) {
        unsigned bit = 1u << (tgtv & 31);
        unsigned old = atomicOr(&bm1[tgtv >> 5], bit);
        if (!(old & bit)) { int p = atomicAdd(c1, 1); if (p < ECL1) l1[p] = tgtv; }
        old = atomicOr(&bm2[tgtv >> 5], bit);
        if (!(old & bit)) { int p = atomicAdd(c2, 1); if (p < ECL2) l2[p] = tgtv; }
        l3[0] = tgtv; c3[0] = 1;
    }
    int e0 = blockIdx.x * BCHK2 + tid * 16;
    if (e0 >= EE) return;   // EE%16==0 -> full 16 edges per active thread
    const int4* dd4 = (const int4*)(ei + EE + e0);
    int4 a = dd4[0], b = dd4[1], c = dd4[2], d = dd4[3];
    int dv[16];
    dv[0]=a.x; dv[1]=a.y; dv[2]=a.z; dv[3]=a.w;
    dv[4]=b.x; dv[5]=b.y; dv[6]=b.z; dv[7]=b.w;
    dv[8]=c.x; dv[9]=c.y; dv[10]=c.z; dv[11]=c.w;
    dv[12]=d.x; dv[13]=d.y; dv[14]=d.z; dv[15]=d.w;
    unsigned mask = 0;
#pragma unroll
    for (int j = 0; j < 16; j++) if (dv[j] == tgtv) mask |= (1u << j);
    if (!mask) return;
#pragma unroll
    for (int j = 0; j < 16; j++) {
        if (mask & (1u << j)) {
            int s = ei[e0 + j];
            int p = atomicAdd(cA, 1);
            if (p < ECA) eA[p] = s;
            unsigned bit = 1u << (s & 31);
            unsigned old = atomicOr(&bm1[s >> 5], bit);
            if (!(old & bit)) { int q = atomicAdd(c1, 1); if (q < ECL1) l1[q] = s; }
            old = atomicOr(&bm2[s >> 5], bit);
            if (!(old & bit)) { int q = atomicAdd(c2, 1); if (q < ECL2) l2[q] = s; }
        }
    }
}

// bitmap-filtered scan with direct fixed-stride row scatter; optionally
// seeds the next-level node set (bmN/lN dedup).
__global__ __launch_bounds__(256) void k_scanR(
        const int* __restrict__ ei, const unsigned* __restrict__ bm,
        int* __restrict__ fill, int* __restrict__ rows,
        unsigned* __restrict__ bmN, int* __restrict__ lN,
        int* __restrict__ cN, int capN) {
    __shared__ unsigned sbm[NBWP];
    int tid = threadIdx.x;
    {   // batched bitmap stage: 4 independent uint4 loads -> one drain
        const uint4* b4 = (const uint4*)bm;
        uint4* s4 = (uint4*)sbm;
        uint4 t0 = b4[tid];
        uint4 t1 = b4[tid + 256];
        uint4 t2 = (tid + 512 < NBWP / 4) ? b4[tid + 512] : make_uint4(0,0,0,0);
        uint4 t3 = (tid + 768 < NBWP / 4) ? b4[tid + 768] : make_uint4(0,0,0,0);
        s4[tid] = t0;
        s4[tid + 256] = t1;
        if (tid + 512 < NBWP / 4) s4[tid + 512] = t2;
        if (tid + 768 < NBWP / 4) s4[tid + 768] = t3;
    }
    __syncthreads();
    int e0 = blockIdx.x * BCHK2 + tid * 16;
    if (e0 >= EE) return;
    const int4* dd4 = (const int4*)(ei + EE + e0);
    int4 a = dd4[0], b = dd4[1], c = dd4[2], d = dd4[3];
    int dv[16];
    dv[0]=a.x; dv[1]=a.y; dv[2]=a.z; dv[3]=a.w;
    dv[4]=b.x; dv[5]=b.y; dv[6]=b.z; dv[7]=b.w;
    dv[8]=c.x; dv[9]=c.y; dv[10]=c.z; dv[11]=c.w;
    dv[12]=d.x; dv[13]=d.y; dv[14]=d.z; dv[15]=d.w;
    unsigned mask = 0;
#pragma unroll
    for (int j = 0; j < 16; j++)
        if ((sbm[dv[j] >> 5] >> (dv[j] & 31)) & 1u) mask |= (1u << j);
    if (!mask) return;
#pragma unroll
    for (int j = 0; j < 16; j++) {
        if (mask & (1u << j)) {
            int dn = dv[j];
            int s = ei[e0 + j];
            int p = atomicAdd(&fill[dn], 1);
            if (p < RSTR) rows[(size_t)dn * RSTR + p] = s;
            if (bmN) {
                unsigned bit = 1u << (s & 31);
                unsigned old = atomicOr(&bmN[s >> 5], bit);
                if (!(old & bit)) {
                    int q = atomicAdd(cN, 1);
                    if (q < capN) lN[q] = s;
                }
            }
        }
    }
}

// ---------------- GAT transform (layer 0: raw input, DIN=5, full N) ---------
__global__ void k_transform0(const void* x, const void* W, const void* ad_,
                             const int* flag, unsigned short* hWb, float* ed) {
    __shared__ float sW[FIN * SHD];
    __shared__ float sad[SHD];
    int tid = threadIdx.x;
    int f = flag[0];
    cp(sW, W, FIN * SHD, tid, 256, f);
    if (tid >= 192 && tid < 192 + SHD) sad[tid - 192] = ldw(ad_, tid - 192, f);
    __syncthreads();
    int n = blockIdx.x * 256 + tid;
    if (n >= NN) return;
    float xr[FIN];
    if (f) {
        const float* xp = (const float*)x + (size_t)n * FIN;
        for (int k = 0; k < FIN; k++) xr[k] = xp[k];
    } else {
        const bf16* xp = (const bf16*)x + (size_t)n * FIN;
        for (int k = 0; k < FIN; k++) xr[k] = b2f(xp[k]);
    }
    float o[SHD];
    for (int j = 0; j < SHD; j++) o[j] = 0.f;
    for (int k = 0; k < FIN; k++) {
        float xv = xr[k];
        for (int j = 0; j < SHD; j++) o[j] += xv * sW[k * SHD + j];
    }
    ushort4* row = (ushort4*)(hWb + (size_t)n * SHD);
    for (int q = 0; q < 8; q++) {
        ushort4 v; v.x = f2b(o[q*4]); v.y = f2b(o[q*4+1]); v.z = f2b(o[q*4+2]); v.w = f2b(o[q*4+3]);
        row[q] = v;
    }
    for (int h = 0; h < NH; h++) {
        float e2 = 0.f;
        for (int c = 0; c < 4; c++) e2 += o[h * 4 + c] * sad[h * 4 + c];
        ed[(size_t)n * NH + h] = e2;
    }
}

// ---------------- GAT transform (layers 2/3: list-driven, DIN=32) -----------
__global__ void k_transform1(const int* __restrict__ list, const int* __restrict__ cntp,
                             int cap,
                             const float* x, const void* W, const void* ad_,
                             const int* flag, unsigned short* hWb, float* ed) {
    __shared__ float sW[SHD * SHD];
    __shared__ float sad[SHD];
    int tid = threadIdx.x;
    int f = flag[0];
    cp(sW, W, SHD * SHD, tid, 256, f);
    if (tid >= 192 && tid < 192 + SHD) sad[tid - 192] = ldw(ad_, tid - 192, f);
    __syncthreads();
    int cnt = cntp[0]; if (cnt > cap) cnt = cap;
    int ii = blockIdx.x * 256 + tid;
    if (ii >= cnt) return;
    int n = list[ii];
    float xr[SHD];
    const float4* xp4 = (const float4*)(x + (size_t)n * SHD);
#pragma unroll
    for (int q = 0; q < 8; q++) {
        float4 v = xp4[q];
        xr[q*4] = v.x; xr[q*4+1] = v.y; xr[q*4+2] = v.z; xr[q*4+3] = v.w;
    }
    float o[SHD];
    for (int j = 0; j < SHD; j++) o[j] = 0.f;
    for (int k = 0; k < SHD; k++) {
        float xv = xr[k];
        for (int j = 0; j < SHD; j++) o[j] += xv * sW[k * SHD + j];
    }
    ushort4* row = (ushort4*)(hWb + (size_t)n * SHD);
    for (int q = 0; q < 8; q++) {
        ushort4 v; v.x = f2b(o[q*4]); v.y = f2b(o[q*4+1]); v.z = f2b(o[q*4+2]); v.w = f2b(o[q*4+3]);
        row[q] = v;
    }
    for (int h = 0; h < NH; h++) {
        float e2 = 0.f;
        for (int c = 0; c < 4; c++) e2 += o[h * 4 + c] * sad[h * 4 + c];
        ed[(size_t)n * NH + h] = e2;
    }
}

// ------- GAT aggregation: list-driven, 2 entries/wave, 6-deep pipeline ------
// Normal mode: base = n*RSTR (fixed-stride rows), deg = min(rdeg[n], RSTR).
// ovr != null: single-row mode (base=0, deg=*ovr) for the layer-3 tgt row.
__global__ void k_aggregate(const int* __restrict__ list, const int* __restrict__ cntp,
                            int cap,
                            const int* __restrict__ rdeg,
                            const int* __restrict__ csr,
                            const int* __restrict__ ovr, int ovrCap,
                            const unsigned short* __restrict__ hWb,
                            const float* __restrict__ ed,
                            const float* __restrict__ prm,
                            float* __restrict__ out) {
    int gid = blockIdx.x * 256 + threadIdx.x;
    int lane = threadIdx.x & 63;
    int cnt = cntp[0]; if (cnt > cap) cnt = cap;
    int idx = (gid >> 6) * 2 + (lane >> 5);
    if (idx >= cnt) return;
    int n = list[idx];
    int l32 = lane & 31;
    int h = l32 & 7, k = l32 >> 3;
    float4 asv = *(const float4*)(prm + h * 4);
    float ednh = ed[(size_t)n * NH + h];
    int base, deg;
    if (ovr) { base = 0; deg = ovr[0]; if (deg > ovrCap) deg = ovrCap; }
    else     { base = n * RSTR; deg = rdeg[n]; if (deg > RSTR) deg = RSTR; }
    float den = 0.f;
    f32x2 acc01 = {0.f, 0.f}, acc23 = {0.f, 0.f};
    int t = k;
    int s0 = -1, s1 = -1, s2 = -1, s3 = -1, s4 = -1, s5 = -1;
    if (t <= deg)      s0 = (t == 0) ? n : __builtin_nontemporal_load(csr + base + t - 1);
    if (t + 4 <= deg)  s1 = __builtin_nontemporal_load(csr + base + t + 3);
    if (t + 8 <= deg)  s2 = __builtin_nontemporal_load(csr + base + t + 7);
    if (t + 12 <= deg) s3 = __builtin_nontemporal_load(csr + base + t + 11);
    if (t + 16 <= deg) s4 = __builtin_nontemporal_load(csr + base + t + 15);
    if (t + 20 <= deg) s5 = __builtin_nontemporal_load(csr + base + t + 19);
    while (s0 >= 0) {
        uint2 hv0 = *(const uint2*)(hWb + (size_t)s0 * SHD + h * 4);
        bool b1 = (s1 >= 0), b2 = (s2 >= 0), b3 = (s3 >= 0), b4 = (s4 >= 0), b5 = (s5 >= 0);
        uint2 hv1, hv2, hv3, hv4, hv5;
        if (b1) hv1 = *(const uint2*)(hWb + (size_t)s1 * SHD + h * 4);
        if (b2) hv2 = *(const uint2*)(hWb + (size_t)s2 * SHD + h * 4);
        if (b3) hv3 = *(const uint2*)(hWb + (size_t)s3 * SHD + h * 4);
        if (b4) hv4 = *(const uint2*)(hWb + (size_t)s4 * SHD + h * 4);
        if (b5) hv5 = *(const uint2*)(hWb + (size_t)s5 * SHD + h * 4);
        int tn = t + 24;
        int p0 = -1, p1 = -1, p2 = -1, p3 = -1, p4 = -1, p5 = -1;
        if (tn <= deg)      p0 = __builtin_nontemporal_load(csr + base + tn - 1);
        if (tn + 4 <= deg)  p1 = __builtin_nontemporal_load(csr + base + tn + 3);
        if (tn + 8 <= deg)  p2 = __builtin_nontemporal_load(csr + base + tn + 7);
        if (tn + 12 <= deg) p3 = __builtin_nontemporal_load(csr + base + tn + 11);
        if (tn + 16 <= deg) p4 = __builtin_nontemporal_load(csr + base + tn + 15);
        if (tn + 20 <= deg) p5 = __builtin_nontemporal_load(csr + base + tn + 19);
        {
            f32x2 h01, h23;
            h01.x = __uint_as_float(hv0.x << 16);
            h01.y = __uint_as_float(hv0.x & 0xffff0000u);
            h23.x = __uint_as_float(hv0.y << 16);
            h23.y = __uint_as_float(hv0.y & 0xffff0000u);
            f32x2 d2 = h01 * (f32x2){asv.x, asv.y} + h23 * (f32x2){asv.z, asv.w};
            float e = d2.x + d2.y + ednh;
            e = fmaxf(e, 0.2f * e);
            float a = __expf(e);
            den += a;
            f32x2 av = {a, a};
            acc01 += av * h01;
            acc23 += av * h23;
        }
        if (b1) {
            f32x2 h01, h23;
            h01.x = __uint_as_float(hv1.x << 16);
            h01.y = __uint_as_float(hv1.x & 0xffff0000u);
            h23.x = __uint_as_float(hv1.y << 16);
            h23.y = __uint_as_float(hv1.y & 0xffff0000u);
            f32x2 d2 = h01 * (f32x2){asv.x, asv.y} + h23 * (f32x2){asv.z, asv.w};
            float e = d2.x + d2.y + ednh;
            e = fmaxf(e, 0.2f * e);
            float a = __expf(e);
            den += a;
            f32x2 av = {a, a};
            acc01 += av * h01;
            acc23 += av * h23;
        }
        if (b2) {
            f32x2 h01, h23;
            h01.x = __uint_as_float(hv2.x << 16);
            h01.y = __uint_as_float(hv2.x & 0xffff0000u);
            h23.x = __uint_as_float(hv2.y << 16);
            h23.y = __uint_as_float(hv2.y & 0xffff0000u);
            f32x2 d2 = h01 * (f32x2){asv.x, asv.y} + h23 * (f32x2){asv.z, asv.w};
            float e = d2.x + d2.y + ednh;
            e = fmaxf(e, 0.2f * e);
            float a = __expf(e);
            den += a;
            f32x2 av = {a, a};
            acc01 += av * h01;
            acc23 += av * h23;
        }
        if (b3) {
            f32x2 h01, h23;
            h01.x = __uint_as_float(hv3.x << 16);
            h01.y = __uint_as_float(hv3.x & 0xffff0000u);
            h23.x = __uint_as_float(hv3.y << 16);
            h23.y = __uint_as_float(hv3.y & 0xffff0000u);
            f32x2 d2 = h01 * (f32x2){asv.x, asv.y} + h23 * (f32x2){asv.z, asv.w};
            float e = d2.x + d2.y + ednh;
            e = fmaxf(e, 0.2f * e);
            float a = __expf(e);
            den += a;
            f32x2 av = {a, a};
            acc01 += av * h01;
            acc23 += av * h23;
        }
        if (b4) {
            f32x2 h01, h23;
            h01.x = __uint_as_float(hv4.x << 16);
            h01.y = __uint_as_float(hv4.x & 0xffff0000u);
            h23.x = __uint_as_float(hv4.y << 16);
            h23.y = __uint_as_float(hv4.y & 0xffff0000u);
            f32x2 d2 = h01 * (f32x2){asv.x, asv.y} + h23 * (f32x2){asv.z, asv.w};
            float e = d2.x + d2.y + ednh;
            e = fmaxf(e, 0.2f * e);
            float a = __expf(e);
            den += a;
            f32x2 av = {a, a};
            acc01 += av * h01;
            acc23 += av * h23;
        }
        if (b5) {
            f32x2 h01, h23;
            h01.x = __uint_as_float(hv5.x << 16);
            h01.y = __uint_as_float(hv5.x & 0xffff0000u);
            h23.x = __uint_as_float(hv5.y << 16);
            h23.y = __uint_as_float(hv5.y & 0xffff0000u);
            f32x2 d2 = h01 * (f32x2){asv.x, asv.y} + h23 * (f32x2){asv.z, asv.w};
            float e = d2.x + d2.y + ednh;
            e = fmaxf(e, 0.2f * e);
            float a = __expf(e);
            den += a;
            f32x2 av = {a, a};
            acc01 += av * h01;
            acc23 += av * h23;
        }
        s0 = p0; s1 = p1; s2 = p2; s3 = p3; s4 = p4; s5 = p5; t = tn;
    }
    for (int off = 16; off >= 8; off >>= 1) {
        den      += __shfl_down(den, off, 32);
        acc01.x  += __shfl_down(acc01.x, off, 32);
        acc01.y  += __shfl_down(acc01.y, off, 32);
        acc23.x  += __shfl_down(acc23.x, off, 32);
        acc23.y  += __shfl_down(acc23.y, off, 32);
    }
    if (k == 0) {
        float inv = 1.f / (den + 1e-16f);
        float4 bv = *(const float4*)(prm + 32 + h * 4);
        float v0 = acc01.x * inv + bv.x;
        float v1 = acc01.y * inv + bv.y;
        float v2 = acc23.x * inv + bv.z;
        float v3 = acc23.y * inv + bv.w;
        v0 = (v0 > 0.f) ? v0 : expm1f(v0);
        v1 = (v1 > 0.f) ? v1 : expm1f(v1);
        v2 = (v2 > 0.f) ? v2 : expm1f(v2);
        v3 = (v3 > 0.f) ? v3 : expm1f(v3);
        *(float4*)(out + (size_t)n * SHD + h * 4) = make_float4(v0, v1, v2, v3);
    }
}

// ---------------- Temporal tail ---------------------------------------------
// Round-5-verified design. LSTM weights pinned in registers via asm("+v")
// (defeats remat); L2 warm sweep + MLP matvecs use 8-wide batched loads.
template<typename T>
__device__ __forceinline__ void lstm_load_regs(
        const T* Wih0, const T* Whh0, const T* bih0, const T* bhh0,
        const T* Wih1, const T* Whh1, const T* bih1, const T* bhh1,
        const T* xin, int l, bool bl, float* xs,
        float& wa, float& ba, float& wb, float& bb, float& ba2, float& bb2,
        float* Wa, float* Wb, float* Ua, float* Va, float* Ub, float* Vb) {
#pragma unroll
    for (int t = 0; t < SEQL; t++) xs[t] = cvf(xin[t]);
    wa = cvf(Wih0[l]);
    ba = cvf(bih0[l]) + cvf(bhh0[l]);
    wb = bl ? cvf(Wih0[64 + l]) : 0.f;
    bb = bl ? (cvf(bih0[64 + l]) + cvf(bhh0[64 + l])) : 0.f;
    ba2 = cvf(bih1[l]) + cvf(bhh1[l]);
    bb2 = bl ? (cvf(bih1[64 + l]) + cvf(bhh1[64 + l])) : 0.f;
#pragma unroll
    for (int j = 0; j < 21; j++) {
        Wa[j] = cvf(Whh0[l * 21 + j]);
        Wb[j] = bl ? cvf(Whh0[(64 + l) * 21 + j]) : 0.f;
        Ua[j] = cvf(Wih1[l * 21 + j]);
        Va[j] = cvf(Whh1[l * 21 + j]);
        Ub[j] = bl ? cvf(Wih1[(64 + l) * 21 + j]) : 0.f;
        Vb[j] = bl ? cvf(Whh1[(64 + l) * 21 + j]) : 0.f;
    }
}

__device__ __forceinline__ void warm_sweep(const void* p, int nbytes, int t2) {
    const uint4* s = (const uint4*)p;
    int nv = nbytes >> 4;
    unsigned acc = 0;
    for (int i = t2; i < nv; i += 1024) {
        uint4 v0 = s[i];
        uint4 v1 = (i + 128 < nv) ? s[i + 128] : make_uint4(0,0,0,0);
        uint4 v2 = (i + 256 < nv) ? s[i + 256] : make_uint4(0,0,0,0);
        uint4 v3 = (i + 384 < nv) ? s[i + 384] : make_uint4(0,0,0,0);
        uint4 v4 = (i + 512 < nv) ? s[i + 512] : make_uint4(0,0,0,0);
        uint4 v5 = (i + 640 < nv) ? s[i + 640] : make_uint4(0,0,0,0);
        uint4 v6 = (i + 768 < nv) ? s[i + 768] : make_uint4(0,0,0,0);
        uint4 v7 = (i + 896 < nv) ? s[i + 896] : make_uint4(0,0,0,0);
        acc ^= v0.x ^ v1.x ^ v2.x ^ v3.x ^ v4.x ^ v5.x ^ v6.x ^ v7.x;
    }
    asm volatile("" :: "v"(acc));
}

template<typename T>
__device__ __forceinline__ float matvec_t(const T* W, const float* vin,
                                          float bias, int n, int col, int ncol) {
    float acc = bias;
    int k2 = 0;
    for (; k2 + 8 <= n; k2 += 8) {
        float w0 = cvf(W[(k2 + 0) * ncol + col]);
        float w1 = cvf(W[(k2 + 1) * ncol + col]);
        float w2 = cvf(W[(k2 + 2) * ncol + col]);
        float w3 = cvf(W[(k2 + 3) * ncol + col]);
        float w4 = cvf(W[(k2 + 4) * ncol + col]);
        float w5 = cvf(W[(k2 + 5) * ncol + col]);
        float w6 = cvf(W[(k2 + 6) * ncol + col]);
        float w7 = cvf(W[(k2 + 7) * ncol + col]);
        acc += vin[k2 + 0] * w0; acc += vin[k2 + 1] * w1;
        acc += vin[k2 + 2] * w2; acc += vin[k2 + 3] * w3;
        acc += vin[k2 + 4] * w4; acc += vin[k2 + 5] * w5;
        acc += vin[k2 + 6] * w6; acc += vin[k2 + 7] * w7;
    }
    for (; k2 < n; k2++) acc += vin[k2] * cvf(W[k2 * ncol + col]);
    return acc;
}
__device__ __forceinline__ float matvec(const void* W, const float* vin,
                                        float bias, int n, int col, int ncol, int f) {
    return f ? matvec_t<float>((const float*)W, vin, bias, n, col, ncol)
             : matvec_t<bf16>((const bf16*)W, vin, bias, n, col, ncol);
}

__global__ __launch_bounds__(256, 1)
void k_tail(const void* trend, const void* seasonal, const void* residual,
                       const void* cv, const int* tgtp,
                       const void* tWih0, const void* tWhh0, const void* tbih0, const void* tbhh0,
                       const void* tWih1, const void* tWhh1, const void* tbih1, const void* tbhh1,
                       const void* sWih0, const void* sWhh0, const void* sbih0, const void* sbhh0,
                       const void* sWih1, const void* sWhh1, const void* sbih1, const void* sbhh1,
                       const void* res_W, const void* res_b,
                       const void* pg_W, const void* pg_b,
                       const void* f1_W, const void* f1_b,
                       const void* ln_g, const void* ln_b,
                       const void* f2_W, const void* f2_b,
                       const void* f3_W, const void* f3_b,
                       const int* flag, const float* A, void* out) {
    __shared__ __align__(16) float SH1[2][24];
    __shared__ __align__(16) float SH2[2][24];
    __shared__ float comb[97];
    __shared__ float gf[96];
    __shared__ float h1v[64];
    __shared__ float h2s[32];
    __shared__ float sbias[336];  // pg_b@0 f1_b@96 f2_b@160 f3_b@192 ln_g@208 ln_b@272
    __shared__ float stats[2];
    const int tid = threadIdx.x;
    const int f = flag[0];
    const int w = tid >> 6, l = tid & 63;

    if (tid < 96) {
        if (tid < 48) SH1[tid / 24][tid % 24] = 0.f;
        else { int u = tid - 48; SH2[u / 24][u % 24] = 0.f; }
    }
    __syncthreads();

    if (w < 2) {
        const void* Wih0 = w ? sWih0 : tWih0;
        const void* Whh0 = w ? sWhh0 : tWhh0;
        const void* bih0 = w ? sbih0 : tbih0;
        const void* bhh0 = w ? sbhh0 : tbhh0;
        const void* Wih1 = w ? sWih1 : tWih1;
        const void* Whh1 = w ? sWhh1 : tWhh1;
        const void* bih1 = w ? sbih1 : tbih1;
        const void* bhh1 = w ? sbhh1 : tbhh1;
        const void* xin  = w ? seasonal : trend;
        const bool bl = (l < 20);
        float xs[SEQL];
        float wa, ba, wb, bb, ba2, bb2;
        float Wa[21], Wb[21], Ua[21], Va[21], Ub[21], Vb[21];
        if (f) {
            lstm_load_regs<float>((const float*)Wih0, (const float*)Whh0,
                (const float*)bih0, (const float*)bhh0,
                (const float*)Wih1, (const float*)Whh1,
                (const float*)bih1, (const float*)bhh1,
                (const float*)xin, l, bl, xs, wa, ba, wb, bb, ba2, bb2,
                Wa, Wb, Ua, Va, Ub, Vb);
        } else {
            lstm_load_regs<bf16>((const bf16*)Wih0, (const bf16*)Whh0,
                (const bf16*)bih0, (const bf16*)bhh0,
                (const bf16*)Wih1, (const bf16*)Whh1,
                (const bf16*)bih1, (const bf16*)bhh1,
                (const bf16*)xin, l, bl, xs, wa, ba, wb, bb, ba2, bb2,
                Wa, Wb, Ua, Va, Ub, Vb);
        }
#pragma unroll
        for (int j = 0; j < 21; j++) {
            asm volatile("" : "+v"(Wa[j]), "+v"(Wb[j]));
            asm volatile("" : "+v"(Ua[j]), "+v"(Va[j]));
            asm volatile("" : "+v"(Ub[j]), "+v"(Vb[j]));
        }
#pragma unroll
        for (int t = 0; t < SEQL; t++) asm volatile("" : "+v"(xs[t]));
        asm volatile("" : "+v"(wa), "+v"(ba));
        asm volatile("" : "+v"(wb), "+v"(bb));
        asm volatile("" : "+v"(ba2), "+v"(bb2));

        float h1r = 0.f, c1v = 0.f, h2r = 0.f, c2v = 0.f;
#pragma unroll 1
        for (int t = 0; t < SEQL; t++) {
            float aa = ba + xs[t] * wa;
            float ab = bb + xs[t] * wb;
#pragma unroll
            for (int q = 0; q < 5; q++) {
                float4 v = *(const float4*)&SH1[w][q * 4];
                aa += v.x * Wa[q*4];   ab += v.x * Wb[q*4];
                aa += v.y * Wa[q*4+1]; ab += v.y * Wb[q*4+1];
                aa += v.z * Wa[q*4+2]; ab += v.z * Wb[q*4+2];
                aa += v.w * Wa[q*4+3]; ab += v.w * Wb[q*4+3];
            }
            { float v20 = SH1[w][20]; aa += v20 * Wa[20]; ab += v20 * Wb[20]; }
            float fj = __shfl(aa, 21 + l);
            float gj = __shfl(aa, 42 + l);
            float oa = __shfl(aa, 63);
            float ob = __shfl(ab, (l == 0) ? 0 : (l - 1));
            float oj = (l == 0) ? oa : ob;
            if (l < 21) {
                c1v = sigm(fj) * c1v + sigm(aa) * tanhf(gj);
                h1r = sigm(oj) * tanhf(c1v);
                SH1[w][l] = h1r;
            }
            __threadfence_block();
            float a2 = ba2, b2v = bb2;
#pragma unroll
            for (int q = 0; q < 5; q++) {
                float4 u = *(const float4*)&SH1[w][q * 4];
                float4 v = *(const float4*)&SH2[w][q * 4];
                a2  += u.x * Ua[q*4]   + v.x * Va[q*4];
                b2v += u.x * Ub[q*4]   + v.x * Vb[q*4];
                a2  += u.y * Ua[q*4+1] + v.y * Va[q*4+1];
                b2v += u.y * Ub[q*4+1] + v.y * Vb[q*4+1];
                a2  += u.z * Ua[q*4+2] + v.z * Va[q*4+2];
                b2v += u.z * Ub[q*4+2] + v.z * Vb[q*4+2];
                a2  += u.w * Ua[q*4+3] + v.w * Va[q*4+3];
                b2v += u.w * Ub[q*4+3] + v.w * Vb[q*4+3];
            }
            { float u20 = SH1[w][20], v20 = SH2[w][20];
              a2  += u20 * Ua[20] + v20 * Va[20];
              b2v += u20 * Ub[20] + v20 * Vb[20]; }
            float fj2 = __shfl(a2, 21 + l);
            float gj2 = __shfl(a2, 42 + l);
            float oa2 = __shfl(a2, 63);
            float ob2 = __shfl(b2v, (l == 0) ? 0 : (l - 1));
            float oj2 = (l == 0) ? oa2 : ob2;
            if (l < 21) {
                c2v = sigm(fj2) * c2v + sigm(a2) * tanhf(gj2);
                h2r = sigm(oj2) * tanhf(c2v);
                SH2[w][l] = h2r;
            }
            __threadfence_block();
        }
        if (l < 21) comb[(w == 0 ? 32 : 53) + l] = h2r;
    } else {
        int t2 = tid - 128;   // 0..127
        if (t2 < TRH)
            comb[74 + t2] = relu_nan(ldw(residual, SEQL - 1, f) * ldw(res_W, t2, f)
                                     + ldw(res_b, t2, f));
        if (t2 == TRH) comb[96] = ldw(cv, 0, f);
        if (t2 >= 32 && t2 < 64) {
            int tgt = tgtp[0];
            comb[t2 - 32] = A[(size_t)tgt * SHD + (t2 - 32)];
        }
        for (int i = t2; i < 336; i += 128) {
            float v;
            if (i < 96)       v = ldw(pg_b, i, f);
            else if (i < 160) v = ldw(f1_b, i - 96, f);
            else if (i < 192) v = ldw(f2_b, i - 160, f);
            else if (i < 206) v = ldw(f3_b, i - 192, f);
            else if (i < 208) v = 0.f;
            else if (i < 272) v = ldw(ln_g, i - 208, f);
            else              v = ldw(ln_b, i - 272, f);
            sbias[i] = v;
        }
        int esz = f ? 4 : 2;
        warm_sweep(pg_W, 9312 * esz, t2);
        warm_sweep(f1_W, 6144 * esz, t2);
        warm_sweep(f2_W, 2048 * esz, t2);
        warm_sweep(f3_W,  448 * esz, t2);
    }
    __syncthreads();

    if (tid < 96)
        gf[tid] = comb[tid] * sigm(matvec(pg_W, comb, sbias[tid], 97, tid, 96, f));
    __syncthreads();
    if (tid < 64)
        h1v[tid] = matvec(f1_W, gf, sbias[96 + tid], 96, tid, 64, f);
    __syncthreads();
    if (tid == 0) {
        float mu = 0.f;
        for (int j = 0; j < 64; j++) mu += h1v[j];
        mu /= 64.f;
        float var = 0.f;
        for (int j = 0; j < 64; j++) { float d = h1v[j] - mu; var += d * d; }
        var /= 64.f;
        stats[0] = mu; stats[1] = rsqrtf(var + 1e-5f);
    }
    __syncthreads();
    if (tid < 64)
        h1v[tid] = relu_nan((h1v[tid] - stats[0]) * stats[1] * sbias[208 + tid] + sbias[272 + tid]);
    __syncthreads();
    if (tid < 32)
        h2s[tid] = relu_nan(matvec(f2_W, h1v, sbias[160 + tid], 64, tid, 32, f));
    __syncthreads();
    if (tid < SEQL) {
        float acc = matvec(f3_W, h2s, sbias[192 + tid], 32, tid, 14, f);
        if (acc != acc) acc = 3333.0f;
        if (f) ((float*)out)[tid] = acc;
        else   ((bf16*)out)[tid] = __float2bfloat16(acc);
    }
}

// ---------------- host helpers ----------------
static inline unsigned short h_f2bf(float f) {
    union { float f; unsigned u; } x; x.f = f;
    return (unsigned short)(x.u >> 16);
}
static unsigned short g_diag[SEQL];

// ---------------- launch ----------------
extern "C" void kernel_launch(void* const* d_in, const int* in_sizes, int n_in,
                              void* d_out, int out_size, void* d_ws, size_t ws_size,
                              hipStream_t stream) {
    const int* ei  = (const int*)d_in[1];
    const int* tgt = (const int*)d_in[6];

    const size_t HWB  = sizeof(unsigned short) * (size_t)NN * SHD;
    const size_t EDB  = sizeof(float) * (size_t)NN * NH;
    const size_t AB   = sizeof(float) * (size_t)NN * SHD;
    // zeroed region: cnts(16) + bm1,bm2 (2*NBWP) + fillB,fillC (2N)
    const size_t ZER  = sizeof(int) * (size_t)(16 + 2 * NBWP + 2 * NN);
    const size_t ROWB = sizeof(int) * (size_t)NN * RSTR;   // x2 (B and C)
    const size_t LSTB = sizeof(int) * (size_t)(ECA + ECL1 + 8 + ECL2);
    const size_t NEED = 256 + 1024 + ZER + LSTB + 2 * ROWB + 512 + HWB + EDB + AB;
    if (ws_size < NEED) {
        for (int i = 0; i < SEQL; i++) g_diag[i] = h_f2bf(7777.0f);
        hipMemcpyAsync(d_out, g_diag, SEQL * sizeof(unsigned short),
                       hipMemcpyHostToDevice, stream);
        return;
    }

    char* p = (char*)d_ws;
    int*   flag = (int*)p;   p += 256;
    float* prm  = (float*)p; p += 1024;
    int* cnts  = (int*)p; p += sizeof(int) * 16;   // cA,c1,c2,c3
    unsigned* bm1 = (unsigned*)p; p += sizeof(int) * NBWP;
    unsigned* bm2 = (unsigned*)p; p += sizeof(int) * NBWP;
    int* fillB = (int*)p; p += sizeof(int) * NN;
    int* fillC = (int*)p; p += sizeof(int) * NN;
    int* eA   = (int*)p; p += sizeof(int) * ECA;
    int* l1   = (int*)p; p += sizeof(int) * ECL1;
    int* l3   = (int*)p; p += sizeof(int) * 8;
    int* l2   = (int*)p; p += sizeof(int) * ECL2;
    int* rowsB = (int*)p; p += ROWB;
    int* rowsC = (int*)p; p += ROWB;
    p = (char*)(((uintptr_t)p + 255) & ~(uintptr_t)255);
    unsigned short* hWb = (unsigned short*)p; p += HWB;
    float* ed = (float*)p; p += EDB;
    float* A  = (float*)p; p += AB;
    int* cA = cnts; int* c1 = cnts + 1; int* c2 = cnts + 2; int* c3 = cnts + 3;

    dim3 b256(256);
    dim3 gN((NN + 255) / 256);
    dim3 gScan(NBC2);

    PatternAwareSTGAT_94489281309_kernel<<<dim3(1), dim3(64), 0, stream>>>(
        (const unsigned int*)d_in[0], flag,
        d_in[8], d_in[10], d_in[12], d_in[14], d_in[16], d_in[18], prm);

    hipMemsetAsync(cnts, 0, ZER, stream);

    // frontier build: 3 fused scans (was 8 dispatches in round-13)
    k_scanA<<<gScan, b256, 0, stream>>>(ei, tgt, eA, cA,
                                        bm1, l1, c1, bm2, l2, c2, l3, c3);
    k_scanR<<<gScan, b256, 0, stream>>>(ei, bm1, fillB, rowsB,
                                        bm2, l2, c2, ECL2);
    k_scanR<<<gScan, b256, 0, stream>>>(ei, bm2, fillC, rowsC,
                                        (unsigned*)nullptr, (int*)nullptr,
                                        (int*)nullptr, 0);

    // GAT layers over the dependency cone
    k_transform0<<<gN, b256, 0, stream>>>(d_in[0], d_in[7], d_in[9], flag, hWb, ed);
    k_aggregate<<<dim3(ECL2 * 32 / 256), b256, 0, stream>>>(l2, c2, ECL2,
        fillC, rowsC, (const int*)nullptr, 0, hWb, ed, prm, A);
    k_transform1<<<dim3(ECL2 / 256), b256, 0, stream>>>(l2, c2, ECL2,
        A, d_in[11], d_in[13], flag, hWb, ed);
    k_aggregate<<<dim3(ECL1 * 32 / 256), b256, 0, stream>>>(l1, c1, ECL1,
        fillB, rowsB, (const int*)nullptr, 0, hWb, ed, prm + 64, A);
    k_transform1<<<dim3((ECL1 + 255) / 256), b256, 0, stream>>>(l1, c1, ECL1,
        A, d_in[15], d_in[17], flag, hWb, ed);
    k_aggregate<<<dim3(1), b256, 0, stream>>>(l3, c3, 8,
        (const int*)nullptr, eA, cA, ECA, hWb, ed, prm + 128, A);

    k_tail<<<dim3(1), b256, 0, stream>>>(
        d_in[2], d_in[3], d_in[4], d_in[5], tgt,
        d_in[19], d_in[20], d_in[21], d_in[22],
        d_in[23], d_in[24], d_in[25], d_in[26],
        d_in[27], d_in[28], d_in[29], d_in[30],
        d_in[31], d_in[32], d_in[33], d_in[34],
        d_in[35], d_in[36],
        d_in[37], d_in[38],
        d_in[39], d_in[40],
        d_in[41], d_in[42],
        d_in[43], d_in[44],
        d_in[45], d_in[46],
        flag, A, d_out);
}

// Round 15
// 246.023 us; speedup vs baseline: 2.5056x; 1.0388x over previous
//
#include <hip/hip_runtime.h>
#include <hip/hip_bf16.h>
#include <stdint.h>
#include <math.h>

#define NN   100000
#define EE   3200000
#define FIN  5
#define SHD  32
#define NH   8
#define TCH  21
#define TRH  22
#define SEQL 14

// frontier capacities (dependency-cone pruning)
#define ECL1  1024     // F1 node list
#define ECL2  8192     // F2 node list
#define RSTR  96       // per-node row stride (graph max in-deg ~59 << 96)

// chunked scan geometry
#define BCHK2 4096
#define NBC2  ((EE + BCHK2 - 1) / BCHK2)
#define NBW   ((NN + 31) / 32)    // 3125 bitmap words
#define NBWP  3200                // padded (800 uint4)

typedef __hip_bfloat16 bf16;
typedef __attribute__((ext_vector_type(2))) float f32x2;

__device__ __forceinline__ float b2f(bf16 v) { return __bfloat162float(v); }
__device__ __forceinline__ float sigm(float x) { return 1.f / (1.f + __expf(-x)); }
__device__ __forceinline__ float ldw(const void* p, int i, int f) {
    return f ? ((const float*)p)[i] : __bfloat162float(((const bf16*)p)[i]);
}
__device__ __forceinline__ float relu_nan(float v) {
    return (v == v) ? ((v > 0.f) ? v : 0.f) : v;
}
__device__ __forceinline__ unsigned short f2b(float v) {
    bf16 b = __float2bfloat16(v);
    return *reinterpret_cast<unsigned short*>(&b);
}
__device__ __forceinline__ float cvf(float v) { return v; }
__device__ __forceinline__ float cvf(bf16 v) { return __bfloat162float(v); }
__device__ __forceinline__ void cp(float* dst, const void* src, int n,
                                   int t0, int stride, int f) {
    if (f) {
        const float* s = (const float*)src;
        for (int i = t0; i < n; i += stride) dst[i] = s[i];
    } else {
        const bf16* s = (const bf16*)src;
        for (int i = t0; i < n; i += stride) dst[i] = b2f(s[i]);
    }
}

// ---- dtype detect + f32 param pre-convert (identifier-named, 1 wave) ------
// Round-15: ballot instead of 64 serial dependent loads per thread (the
// session's un-unrolled-load-loop gotcha hiding in plain sight since r0).
__global__ void PatternAwareSTGAT_94489281309_kernel(const unsigned int* xw, int* flag,
        const void* as0, const void* b0, const void* as1, const void* b1,
        const void* as2, const void* b2, float* prm) {
    int tid = threadIdx.x;   // 64
    unsigned int lo = xw[tid] & 0xFFFFu;
    int e = (int)((lo >> 7) & 0xFF);
    bool ok = (e >= 110 && e <= 135);
    int sane = __popcll(__ballot(ok));
    int f = (sane >= 32) ? 0 : 1;
    if (tid == 0) flag[0] = f;
    const void* asp[3] = {as0, as1, as2};
    const void* bp[3]  = {b0, b1, b2};
    for (int l = 0; l < 3; l++)
        prm[l * 64 + tid] = (tid < 32) ? ldw(asp[l], tid, f) : ldw(bp[l], tid - 32, f);
}

// ---------------- Fused frontier scans ---------------------------------------
// scanA: dst==tgt edges seed bm1/l1 AND bm2/l2 (F1 <= F2) via atomicOr dedup.
// (eA list removed in round-15: the layer-3 row now comes from rowsB[tgt].)
__global__ __launch_bounds__(256) void k_scanA(
        const int* __restrict__ ei, const int* __restrict__ tgtp,
        unsigned* __restrict__ bm1, int* __restrict__ l1, int* __restrict__ c1,
        unsigned* __restrict__ bm2, int* __restrict__ l2, int* __restrict__ c2) {
    int tid = threadIdx.x;
    int tgtv = tgtp[0];
    if (blockIdx.x == 0 && tid == 0) {
        unsigned bit = 1u << (tgtv & 31);
        unsigned old = atomicOr(&bm1[tgtv >> 5], bit);
        if (!(old & bit)) { int p = atomicAdd(c1, 1); if (p < ECL1) l1[p] = tgtv; }
        old = atomicOr(&bm2[tgtv >> 5], bit);
        if (!(old & bit)) { int p = atomicAdd(c2, 1); if (p < ECL2) l2[p] = tgtv; }
    }
    int e0 = blockIdx.x * BCHK2 + tid * 16;
    if (e0 >= EE) return;   // EE%16==0 -> full 16 edges per active thread
    const int4* dd4 = (const int4*)(ei + EE + e0);
    int4 a = dd4[0], b = dd4[1], c = dd4[2], d = dd4[3];
    int dv[16];
    dv[0]=a.x; dv[1]=a.y; dv[2]=a.z; dv[3]=a.w;
    dv[4]=b.x; dv[5]=b.y; dv[6]=b.z; dv[7]=b.w;
    dv[8]=c.x; dv[9]=c.y; dv[10]=c.z; dv[11]=c.w;
    dv[12]=d.x; dv[13]=d.y; dv[14]=d.z; dv[15]=d.w;
    unsigned mask = 0;
#pragma unroll
    for (int j = 0; j < 16; j++) if (dv[j] == tgtv) mask |= (1u << j);
    if (!mask) return;
#pragma unroll
    for (int j = 0; j < 16; j++) {
        if (mask & (1u << j)) {
            int s = ei[e0 + j];
            unsigned bit = 1u << (s & 31);
            unsigned old = atomicOr(&bm1[s >> 5], bit);
            if (!(old & bit)) { int q = atomicAdd(c1, 1); if (q < ECL1) l1[q] = s; }
            old = atomicOr(&bm2[s >> 5], bit);
            if (!(old & bit)) { int q = atomicAdd(c2, 1); if (q < ECL2) l2[q] = s; }
        }
    }
}

// bitmap-filtered scan with direct fixed-stride row scatter; optionally
// seeds the next-level node set (bmN/lN dedup).
__global__ __launch_bounds__(256) void k_scanR(
        const int* __restrict__ ei, const unsigned* __restrict__ bm,
        int* __restrict__ fill, int* __restrict__ rows,
        unsigned* __restrict__ bmN, int* __restrict__ lN,
        int* __restrict__ cN, int capN) {
    __shared__ unsigned sbm[NBWP];
    int tid = threadIdx.x;
    {   // batched bitmap stage: 4 independent uint4 loads -> one drain
        const uint4* b4 = (const uint4*)bm;
        uint4* s4 = (uint4*)sbm;
        uint4 t0 = b4[tid];
        uint4 t1 = b4[tid + 256];
        uint4 t2 = (tid + 512 < NBWP / 4) ? b4[tid + 512] : make_uint4(0,0,0,0);
        uint4 t3 = (tid + 768 < NBWP / 4) ? b4[tid + 768] : make_uint4(0,0,0,0);
        s4[tid] = t0;
        s4[tid + 256] = t1;
        if (tid + 512 < NBWP / 4) s4[tid + 512] = t2;
        if (tid + 768 < NBWP / 4) s4[tid + 768] = t3;
    }
    __syncthreads();
    int e0 = blockIdx.x * BCHK2 + tid * 16;
    if (e0 >= EE) return;
    const int4* dd4 = (const int4*)(ei + EE + e0);
    int4 a = dd4[0], b = dd4[1], c = dd4[2], d = dd4[3];
    int dv[16];
    dv[0]=a.x; dv[1]=a.y; dv[2]=a.z; dv[3]=a.w;
    dv[4]=b.x; dv[5]=b.y; dv[6]=b.z; dv[7]=b.w;
    dv[8]=c.x; dv[9]=c.y; dv[10]=c.z; dv[11]=c.w;
    dv[12]=d.x; dv[13]=d.y; dv[14]=d.z; dv[15]=d.w;
    unsigned mask = 0;
#pragma unroll
    for (int j = 0; j < 16; j++)
        if ((sbm[dv[j] >> 5] >> (dv[j] & 31)) & 1u) mask |= (1u << j);
    if (!mask) return;
#pragma unroll
    for (int j = 0; j < 16; j++) {
        if (mask & (1u << j)) {
            int dn = dv[j];
            int s = ei[e0 + j];
            int p = atomicAdd(&fill[dn], 1);
            if (p < RSTR) rows[(size_t)dn * RSTR + p] = s;
            if (bmN) {
                unsigned bit = 1u << (s & 31);
                unsigned old = atomicOr(&bmN[s >> 5], bit);
                if (!(old & bit)) {
                    int q = atomicAdd(cN, 1);
                    if (q < capN) lN[q] = s;
                }
            }
        }
    }
}

// ---------------- GAT transform (layer 0: raw input, DIN=5, full N) ---------
__global__ void k_transform0(const void* x, const void* W, const void* ad_,
                             const int* flag, unsigned short* hWb, float* ed) {
    __shared__ float sW[FIN * SHD];
    __shared__ float sad[SHD];
    int tid = threadIdx.x;
    int f = flag[0];
    cp(sW, W, FIN * SHD, tid, 256, f);
    if (tid >= 192 && tid < 192 + SHD) sad[tid - 192] = ldw(ad_, tid - 192, f);
    __syncthreads();
    int n = blockIdx.x * 256 + tid;
    if (n >= NN) return;
    float xr[FIN];
    if (f) {
        const float* xp = (const float*)x + (size_t)n * FIN;
        for (int k = 0; k < FIN; k++) xr[k] = xp[k];
    } else {
        const bf16* xp = (const bf16*)x + (size_t)n * FIN;
        for (int k = 0; k < FIN; k++) xr[k] = b2f(xp[k]);
    }
    float o[SHD];
    for (int j = 0; j < SHD; j++) o[j] = 0.f;
    for (int k = 0; k < FIN; k++) {
        float xv = xr[k];
        for (int j = 0; j < SHD; j++) o[j] += xv * sW[k * SHD + j];
    }
    ushort4* row = (ushort4*)(hWb + (size_t)n * SHD);
    for (int q = 0; q < 8; q++) {
        ushort4 v; v.x = f2b(o[q*4]); v.y = f2b(o[q*4+1]); v.z = f2b(o[q*4+2]); v.w = f2b(o[q*4+3]);
        row[q] = v;
    }
    for (int h = 0; h < NH; h++) {
        float e2 = 0.f;
        for (int c = 0; c < 4; c++) e2 += o[h * 4 + c] * sad[h * 4 + c];
        ed[(size_t)n * NH + h] = e2;
    }
}

// ---------------- GAT transform (layers 2/3: list-driven, DIN=32) -----------
__global__ void k_transform1(const int* __restrict__ list, const int* __restrict__ cntp,
                             int cap,
                             const float* x, const void* W, const void* ad_,
                             const int* flag, unsigned short* hWb, float* ed) {
    __shared__ float sW[SHD * SHD];
    __shared__ float sad[SHD];
    int tid = threadIdx.x;
    int f = flag[0];
    cp(sW, W, SHD * SHD, tid, 256, f);
    if (tid >= 192 && tid < 192 + SHD) sad[tid - 192] = ldw(ad_, tid - 192, f);
    __syncthreads();
    int cnt = cntp[0]; if (cnt > cap) cnt = cap;
    int ii = blockIdx.x * 256 + tid;
    if (ii >= cnt) return;
    int n = list[ii];
    float xr[SHD];
    const float4* xp4 = (const float4*)(x + (size_t)n * SHD);
#pragma unroll
    for (int q = 0; q < 8; q++) {
        float4 v = xp4[q];
        xr[q*4] = v.x; xr[q*4+1] = v.y; xr[q*4+2] = v.z; xr[q*4+3] = v.w;
    }
    float o[SHD];
    for (int j = 0; j < SHD; j++) o[j] = 0.f;
    for (int k = 0; k < SHD; k++) {
        float xv = xr[k];
        for (int j = 0; j < SHD; j++) o[j] += xv * sW[k * SHD + j];
    }
    ushort4* row = (ushort4*)(hWb + (size_t)n * SHD);
    for (int q = 0; q < 8; q++) {
        ushort4 v; v.x = f2b(o[q*4]); v.y = f2b(o[q*4+1]); v.z = f2b(o[q*4+2]); v.w = f2b(o[q*4+3]);
        row[q] = v;
    }
    for (int h = 0; h < NH; h++) {
        float e2 = 0.f;
        for (int c = 0; c < 4; c++) e2 += o[h * 4 + c] * sad[h * 4 + c];
        ed[(size_t)n * NH + h] = e2;
    }
}

// ------- GAT aggregation: list-driven, 2 entries/wave, 6-deep pipeline ------
// base = n*RSTR (fixed-stride rows), deg = min(fill[n], RSTR).
__global__ void k_aggregate(const int* __restrict__ list, const int* __restrict__ cntp,
                            int cap,
                            const int* __restrict__ rdeg,
                            const int* __restrict__ csr,
                            const unsigned short* __restrict__ hWb,
                            const float* __restrict__ ed,
                            const float* __restrict__ prm,
                            float* __restrict__ out) {
    int gid = blockIdx.x * 256 + threadIdx.x;
    int lane = threadIdx.x & 63;
    int cnt = cntp[0]; if (cnt > cap) cnt = cap;
    int idx = (gid >> 6) * 2 + (lane >> 5);
    if (idx >= cnt) return;
    int n = list[idx];
    int l32 = lane & 31;
    int h = l32 & 7, k = l32 >> 3;
    float4 asv = *(const float4*)(prm + h * 4);
    float ednh = ed[(size_t)n * NH + h];
    int base = n * RSTR;
    int deg = rdeg[n]; if (deg > RSTR) deg = RSTR;
    float den = 0.f;
    f32x2 acc01 = {0.f, 0.f}, acc23 = {0.f, 0.f};
    int t = k;
    int s0 = -1, s1 = -1, s2 = -1, s3 = -1, s4 = -1, s5 = -1;
    if (t <= deg)      s0 = (t == 0) ? n : __builtin_nontemporal_load(csr + base + t - 1);
    if (t + 4 <= deg)  s1 = __builtin_nontemporal_load(csr + base + t + 3);
    if (t + 8 <= deg)  s2 = __builtin_nontemporal_load(csr + base + t + 7);
    if (t + 12 <= deg) s3 = __builtin_nontemporal_load(csr + base + t + 11);
    if (t + 16 <= deg) s4 = __builtin_nontemporal_load(csr + base + t + 15);
    if (t + 20 <= deg) s5 = __builtin_nontemporal_load(csr + base + t + 19);
    while (s0 >= 0) {
        uint2 hv0 = *(const uint2*)(hWb + (size_t)s0 * SHD + h * 4);
        bool b1 = (s1 >= 0), b2 = (s2 >= 0), b3 = (s3 >= 0), b4 = (s4 >= 0), b5 = (s5 >= 0);
        uint2 hv1, hv2, hv3, hv4, hv5;
        if (b1) hv1 = *(const uint2*)(hWb + (size_t)s1 * SHD + h * 4);
        if (b2) hv2 = *(const uint2*)(hWb + (size_t)s2 * SHD + h * 4);
        if (b3) hv3 = *(const uint2*)(hWb + (size_t)s3 * SHD + h * 4);
        if (b4) hv4 = *(const uint2*)(hWb + (size_t)s4 * SHD + h * 4);
        if (b5) hv5 = *(const uint2*)(hWb + (size_t)s5 * SHD + h * 4);
        int tn = t + 24;
        int p0 = -1, p1 = -1, p2 = -1, p3 = -1, p4 = -1, p5 = -1;
        if (tn <= deg)      p0 = __builtin_nontemporal_load(csr + base + tn - 1);
        if (tn + 4 <= deg)  p1 = __builtin_nontemporal_load(csr + base + tn + 3);
        if (tn + 8 <= deg)  p2 = __builtin_nontemporal_load(csr + base + tn + 7);
        if (tn + 12 <= deg) p3 = __builtin_nontemporal_load(csr + base + tn + 11);
        if (tn + 16 <= deg) p4 = __builtin_nontemporal_load(csr + base + tn + 15);
        if (tn + 20 <= deg) p5 = __builtin_nontemporal_load(csr + base + tn + 19);
        {
            f32x2 h01, h23;
            h01.x = __uint_as_float(hv0.x << 16);
            h01.y = __uint_as_float(hv0.x & 0xffff0000u);
            h23.x = __uint_as_float(hv0.y << 16);
            h23.y = __uint_as_float(hv0.y & 0xffff0000u);
            f32x2 d2 = h01 * (f32x2){asv.x, asv.y} + h23 * (f32x2){asv.z, asv.w};
            float e = d2.x + d2.y + ednh;
            e = fmaxf(e, 0.2f * e);
            float a = __expf(e);
            den += a;
            f32x2 av = {a, a};
            acc01 += av * h01;
            acc23 += av * h23;
        }
        if (b1) {
            f32x2 h01, h23;
            h01.x = __uint_as_float(hv1.x << 16);
            h01.y = __uint_as_float(hv1.x & 0xffff0000u);
            h23.x = __uint_as_float(hv1.y << 16);
            h23.y = __uint_as_float(hv1.y & 0xffff0000u);
            f32x2 d2 = h01 * (f32x2){asv.x, asv.y} + h23 * (f32x2){asv.z, asv.w};
            float e = d2.x + d2.y + ednh;
            e = fmaxf(e, 0.2f * e);
            float a = __expf(e);
            den += a;
            f32x2 av = {a, a};
            acc01 += av * h01;
            acc23 += av * h23;
        }
        if (b2) {
            f32x2 h01, h23;
            h01.x = __uint_as_float(hv2.x << 16);
            h01.y = __uint_as_float(hv2.x & 0xffff0000u);
            h23.x = __uint_as_float(hv2.y << 16);
            h23.y = __uint_as_float(hv2.y & 0xffff0000u);
            f32x2 d2 = h01 * (f32x2){asv.x, asv.y} + h23 * (f32x2){asv.z, asv.w};
            float e = d2.x + d2.y + ednh;
            e = fmaxf(e, 0.2f * e);
            float a = __expf(e);
            den += a;
            f32x2 av = {a, a};
            acc01 += av * h01;
            acc23 += av * h23;
        }
        if (b3) {
            f32x2 h01, h23;
            h01.x = __uint_as_float(hv3.x << 16);
            h01.y = __uint_as_float(hv3.x & 0xffff0000u);
            h23.x = __uint_as_float(hv3.y << 16);
            h23.y = __uint_as_float(hv3.y & 0xffff0000u);
            f32x2 d2 = h01 * (f32x2){asv.x, asv.y} + h23 * (f32x2){asv.z, asv.w};
            float e = d2.x + d2.y + ednh;
            e = fmaxf(e, 0.2f * e);
            float a = __expf(e);
            den += a;
            f32x2 av = {a, a};
            acc01 += av * h01;
            acc23 += av * h23;
        }
        if (b4) {
            f32x2 h01, h23;
            h01.x = __uint_as_float(hv4.x << 16);
            h01.y = __uint_as_float(hv4.x & 0xffff0000u);
            h23.x = __uint_as_float(hv4.y << 16);
            h23.y = __uint_as_float(hv4.y & 0xffff0000u);
            f32x2 d2 = h01 * (f32x2){asv.x, asv.y} + h23 * (f32x2){asv.z, asv.w};
            float e = d2.x + d2.y + ednh;
            e = fmaxf(e, 0.2f * e);
            float a = __expf(e);
            den += a;
            f32x2 av = {a, a};
            acc01 += av * h01;
            acc23 += av * h23;
        }
        if (b5) {
            f32x2 h01, h23;
            h01.x = __uint_as_float(hv5.x << 16);
            h01.y = __uint_as_float(hv5.x & 0xffff0000u);
            h23.x = __uint_as_float(hv5.y << 16);
            h23.y = __uint_as_float(hv5.y & 0xffff0000u);
            f32x2 d2 = h01 * (f32x2){asv.x, asv.y} + h23 * (f32x2){asv.z, asv.w};
            float e = d2.x + d2.y + ednh;
            e = fmaxf(e, 0.2f * e);
            float a = __expf(e);
            den += a;
            f32x2 av = {a, a};
            acc01 += av * h01;
            acc23 += av * h23;
        }
        s0 = p0; s1 = p1; s2 = p2; s3 = p3; s4 = p4; s5 = p5; t = tn;
    }
    for (int off = 16; off >= 8; off >>= 1) {
        den      += __shfl_down(den, off, 32);
        acc01.x  += __shfl_down(acc01.x, off, 32);
        acc01.y  += __shfl_down(acc01.y, off, 32);
        acc23.x  += __shfl_down(acc23.x, off, 32);
        acc23.y  += __shfl_down(acc23.y, off, 32);
    }
    if (k == 0) {
        float inv = 1.f / (den + 1e-16f);
        float4 bv = *(const float4*)(prm + 32 + h * 4);
        float v0 = acc01.x * inv + bv.x;
        float v1 = acc01.y * inv + bv.y;
        float v2 = acc23.x * inv + bv.z;
        float v3 = acc23.y * inv + bv.w;
        v0 = (v0 > 0.f) ? v0 : expm1f(v0);
        v1 = (v1 > 0.f) ? v1 : expm1f(v1);
        v2 = (v2 > 0.f) ? v2 : expm1f(v2);
        v3 = (v3 > 0.f) ? v3 : expm1f(v3);
        *(float4*)(out + (size_t)n * SHD + h * 4) = make_float4(v0, v1, v2, v3);
    }
}

// ---------------- Temporal tail ---------------------------------------------
// Round-5-verified LSTM design. Round-15: the layer-3 (tgt-row) aggregation
// is fused in — wave 2's lanes 0-31 run the identical 6-deep pipeline over
// rowsB[tgt] (concurrent with the LSTM waves) and write comb[0..31] directly,
// removing one dispatch and the A round-trip for the final GAT layer.
template<typename T>
__device__ __forceinline__ void lstm_load_regs(
        const T* Wih0, const T* Whh0, const T* bih0, const T* bhh0,
        const T* Wih1, const T* Whh1, const T* bih1, const T* bhh1,
        const T* xin, int l, bool bl, float* xs,
        float& wa, float& ba, float& wb, float& bb, float& ba2, float& bb2,
        float* Wa, float* Wb, float* Ua, float* Va, float* Ub, float* Vb) {
#pragma unroll
    for (int t = 0; t < SEQL; t++) xs[t] = cvf(xin[t]);
    wa = cvf(Wih0[l]);
    ba = cvf(bih0[l]) + cvf(bhh0[l]);
    wb = bl ? cvf(Wih0[64 + l]) : 0.f;
    bb = bl ? (cvf(bih0[64 + l]) + cvf(bhh0[64 + l])) : 0.f;
    ba2 = cvf(bih1[l]) + cvf(bhh1[l]);
    bb2 = bl ? (cvf(bih1[64 + l]) + cvf(bhh1[64 + l])) : 0.f;
#pragma unroll
    for (int j = 0; j < 21; j++) {
        Wa[j] = cvf(Whh0[l * 21 + j]);
        Wb[j] = bl ? cvf(Whh0[(64 + l) * 21 + j]) : 0.f;
        Ua[j] = cvf(Wih1[l * 21 + j]);
        Va[j] = cvf(Whh1[l * 21 + j]);
        Ub[j] = bl ? cvf(Wih1[(64 + l) * 21 + j]) : 0.f;
        Vb[j] = bl ? cvf(Whh1[(64 + l) * 21 + j]) : 0.f;
    }
}

__device__ __forceinline__ void warm_sweep(const void* p, int nbytes, int t2) {
    const uint4* s = (const uint4*)p;
    int nv = nbytes >> 4;
    unsigned acc = 0;
    for (int i = t2; i < nv; i += 1024) {
        uint4 v0 = s[i];
        uint4 v1 = (i + 128 < nv) ? s[i + 128] : make_uint4(0,0,0,0);
        uint4 v2 = (i + 256 < nv) ? s[i + 256] : make_uint4(0,0,0,0);
        uint4 v3 = (i + 384 < nv) ? s[i + 384] : make_uint4(0,0,0,0);
        uint4 v4 = (i + 512 < nv) ? s[i + 512] : make_uint4(0,0,0,0);
        uint4 v5 = (i + 640 < nv) ? s[i + 640] : make_uint4(0,0,0,0);
        uint4 v6 = (i + 768 < nv) ? s[i + 768] : make_uint4(0,0,0,0);
        uint4 v7 = (i + 896 < nv) ? s[i + 896] : make_uint4(0,0,0,0);
        acc ^= v0.x ^ v1.x ^ v2.x ^ v3.x ^ v4.x ^ v5.x ^ v6.x ^ v7.x;
    }
    asm volatile("" :: "v"(acc));
}

template<typename T>
__device__ __forceinline__ float matvec_t(const T* W, const float* vin,
                                          float bias, int n, int col, int ncol) {
    float acc = bias;
    int k2 = 0;
    for (; k2 + 8 <= n; k2 += 8) {
        float w0 = cvf(W[(k2 + 0) * ncol + col]);
        float w1 = cvf(W[(k2 + 1) * ncol + col]);
        float w2 = cvf(W[(k2 + 2) * ncol + col]);
        float w3 = cvf(W[(k2 + 3) * ncol + col]);
        float w4 = cvf(W[(k2 + 4) * ncol + col]);
        float w5 = cvf(W[(k2 + 5) * ncol + col]);
        float w6 = cvf(W[(k2 + 6) * ncol + col]);
        float w7 = cvf(W[(k2 + 7) * ncol + col]);
        acc += vin[k2 + 0] * w0; acc += vin[k2 + 1] * w1;
        acc += vin[k2 + 2] * w2; acc += vin[k2 + 3] * w3;
        acc += vin[k2 + 4] * w4; acc += vin[k2 + 5] * w5;
        acc += vin[k2 + 6] * w6; acc += vin[k2 + 7] * w7;
    }
    for (; k2 < n; k2++) acc += vin[k2] * cvf(W[k2 * ncol + col]);
    return acc;
}
__device__ __forceinline__ float matvec(const void* W, const float* vin,
                                        float bias, int n, int col, int ncol, int f) {
    return f ? matvec_t<float>((const float*)W, vin, bias, n, col, ncol)
             : matvec_t<bf16>((const bf16*)W, vin, bias, n, col, ncol);
}

__global__ __launch_bounds__(256, 1)
void k_tail(const void* trend, const void* seasonal, const void* residual,
                       const void* cv, const int* tgtp,
                       const void* tWih0, const void* tWhh0, const void* tbih0, const void* tbhh0,
                       const void* tWih1, const void* tWhh1, const void* tbih1, const void* tbhh1,
                       const void* sWih0, const void* sWhh0, const void* sbih0, const void* sbhh0,
                       const void* sWih1, const void* sWhh1, const void* sbih1, const void* sbhh1,
                       const void* res_W, const void* res_b,
                       const void* pg_W, const void* pg_b,
                       const void* f1_W, const void* f1_b,
                       const void* ln_g, const void* ln_b,
                       const void* f2_W, const void* f2_b,
                       const void* f3_W, const void* f3_b,
                       const int* flag,
                       const int* __restrict__ rowsB, const int* __restrict__ fillB,
                       const unsigned short* __restrict__ hWb,
                       const float* __restrict__ ed,
                       const float* __restrict__ prm3,
                       void* out) {
    __shared__ __align__(16) float SH1[2][24];
    __shared__ __align__(16) float SH2[2][24];
    __shared__ __align__(16) float comb[100];
    __shared__ float gf[96];
    __shared__ float h1v[64];
    __shared__ float h2s[32];
    __shared__ float sbias[336];  // pg_b@0 f1_b@96 f2_b@160 f3_b@192 ln_g@208 ln_b@272
    __shared__ float stats[2];
    const int tid = threadIdx.x;
    const int f = flag[0];
    const int w = tid >> 6, l = tid & 63;

    if (tid < 96) {
        if (tid < 48) SH1[tid / 24][tid % 24] = 0.f;
        else { int u = tid - 48; SH2[u / 24][u % 24] = 0.f; }
    }
    __syncthreads();

    if (w < 2) {
        const void* Wih0 = w ? sWih0 : tWih0;
        const void* Whh0 = w ? sWhh0 : tWhh0;
        const void* bih0 = w ? sbih0 : tbih0;
        const void* bhh0 = w ? sbhh0 : tbhh0;
        const void* Wih1 = w ? sWih1 : tWih1;
        const void* Whh1 = w ? sWhh1 : tWhh1;
        const void* bih1 = w ? sbih1 : tbih1;
        const void* bhh1 = w ? sbhh1 : tbhh1;
        const void* xin  = w ? seasonal : trend;
        const bool bl = (l < 20);
        float xs[SEQL];
        float wa, ba, wb, bb, ba2, bb2;
        float Wa[21], Wb[21], Ua[21], Va[21], Ub[21], Vb[21];
        if (f) {
            lstm_load_regs<float>((const float*)Wih0, (const float*)Whh0,
                (const float*)bih0, (const float*)bhh0,
                (const float*)Wih1, (const float*)Whh1,
                (const float*)bih1, (const float*)bhh1,
                (const float*)xin, l, bl, xs, wa, ba, wb, bb, ba2, bb2,
                Wa, Wb, Ua, Va, Ub, Vb);
        } else {
            lstm_load_regs<bf16>((const bf16*)Wih0, (const bf16*)Whh0,
                (const bf16*)bih0, (const bf16*)bhh0,
                (const bf16*)Wih1, (const bf16*)Whh1,
                (const bf16*)bih1, (const bf16*)bhh1,
                (const bf16*)xin, l, bl, xs, wa, ba, wb, bb, ba2, bb2,
                Wa, Wb, Ua, Va, Ub, Vb);
        }
#pragma unroll
        for (int j = 0; j < 21; j++) {
            asm volatile("" : "+v"(Wa[j]), "+v"(Wb[j]));
            asm volatile("" : "+v"(Ua[j]), "+v"(Va[j]));
            asm volatile("" : "+v"(Ub[j]), "+v"(Vb[j]));
        }
#pragma unroll
        for (int t = 0; t < SEQL; t++) asm volatile("" : "+v"(xs[t]));
        asm volatile("" : "+v"(wa), "+v"(ba));
        asm volatile("" : "+v"(wb), "+v"(bb));
        asm volatile("" : "+v"(ba2), "+v"(bb2));

        float h1r = 0.f, c1v = 0.f, h2r = 0.f, c2v = 0.f;
#pragma unroll 1
        for (int t = 0; t < SEQL; t++) {
            float aa = ba + xs[t] * wa;
            float ab = bb + xs[t] * wb;
#pragma unroll
            for (int q = 0; q < 5; q++) {
                float4 v = *(const float4*)&SH1[w][q * 4];
                aa += v.x * Wa[q*4];   ab += v.x * Wb[q*4];
                aa += v.y * Wa[q*4+1]; ab += v.y * Wb[q*4+1];
                aa += v.z * Wa[q*4+2]; ab += v.z * Wb[q*4+2];
                aa += v.w * Wa[q*4+3]; ab += v.w * Wb[q*4+3];
            }
            { float v20 = SH1[w][20]; aa += v20 * Wa[20]; ab += v20 * Wb[20]; }
            float fj = __shfl(aa, 21 + l);
            float gj = __shfl(aa, 42 + l);
            float oa = __shfl(aa, 63);
            float ob = __shfl(ab, (l == 0) ? 0 : (l - 1));
            float oj = (l == 0) ? oa : ob;
            if (l < 21) {
                c1v = sigm(fj) * c1v + sigm(aa) * tanhf(gj);
                h1r = sigm(oj) * tanhf(c1v);
                SH1[w][l] = h1r;
            }
            __threadfence_block();
            float a2 = ba2, b2v = bb2;
#pragma unroll
            for (int q = 0; q < 5; q++) {
                float4 u = *(const float4*)&SH1[w][q * 4];
                float4 v = *(const float4*)&SH2[w][q * 4];
                a2  += u.x * Ua[q*4]   + v.x * Va[q*4];
                b2v += u.x * Ub[q*4]   + v.x * Vb[q*4];
                a2  += u.y * Ua[q*4+1] + v.y * Va[q*4+1];
                b2v += u.y * Ub[q*4+1] + v.y * Vb[q*4+1];
                a2  += u.z * Ua[q*4+2] + v.z * Va[q*4+2];
                b2v += u.z * Ub[q*4+2] + v.z * Vb[q*4+2];
                a2  += u.w * Ua[q*4+3] + v.w * Va[q*4+3];
                b2v += u.w * Ub[q*4+3] + v.w * Vb[q*4+3];
            }
            { float u20 = SH1[w][20], v20 = SH2[w][20];
              a2  += u20 * Ua[20] + v20 * Va[20];
              b2v += u20 * Ub[20] + v20 * Vb[20]; }
            float fj2 = __shfl(a2, 21 + l);
            float gj2 = __shfl(a2, 42 + l);
            float oa2 = __shfl(a2, 63);
            float ob2 = __shfl(b2v, (l == 0) ? 0 : (l - 1));
            float oj2 = (l == 0) ? oa2 : ob2;
            if (l < 21) {
                c2v = sigm(fj2) * c2v + sigm(a2) * tanhf(gj2);
                h2r = sigm(oj2) * tanhf(c2v);
                SH2[w][l] = h2r;
            }
            __threadfence_block();
        }
        if (l < 21) comb[(w == 0 ? 32 : 53) + l] = h2r;
    } else {
        int t2 = tid - 128;   // 0..127
        if (t2 < TRH)
            comb[74 + t2] = relu_nan(ldw(residual, SEQL - 1, f) * ldw(res_W, t2, f)
                                     + ldw(res_b, t2, f));
        if (t2 == TRH) comb[96] = ldw(cv, 0, f);
        for (int i = t2; i < 336; i += 128) {
            float v;
            if (i < 96)       v = ldw(pg_b, i, f);
            else if (i < 160) v = ldw(f1_b, i - 96, f);
            else if (i < 192) v = ldw(f2_b, i - 160, f);
            else if (i < 206) v = ldw(f3_b, i - 192, f);
            else if (i < 208) v = 0.f;
            else if (i < 272) v = ldw(ln_g, i - 208, f);
            else              v = ldw(ln_b, i - 272, f);
            sbias[i] = v;
        }
        int esz = f ? 4 : 2;
        warm_sweep(pg_W, 9312 * esz, t2);
        warm_sweep(f1_W, 6144 * esz, t2);
        warm_sweep(f2_W, 2048 * esz, t2);
        warm_sweep(f3_W,  448 * esz, t2);

        // ---- fused layer-3 aggregation: tgt row -> comb[0..31] ----
        if (w == 2 && l < 32) {
            int tgt = tgtp[0];
            int h = l & 7, k = l >> 3;
            float4 asv = *(const float4*)(prm3 + h * 4);
            float ednh = ed[(size_t)tgt * NH + h];
            int base = tgt * RSTR;
            int deg = fillB[tgt]; if (deg > RSTR) deg = RSTR;
            float den = 0.f;
            f32x2 acc01 = {0.f, 0.f}, acc23 = {0.f, 0.f};
            int t = k;
            int s0 = -1, s1 = -1, s2 = -1, s3 = -1, s4 = -1, s5 = -1;
            if (t <= deg)      s0 = (t == 0) ? tgt : rowsB[base + t - 1];
            if (t + 4 <= deg)  s1 = rowsB[base + t + 3];
            if (t + 8 <= deg)  s2 = rowsB[base + t + 7];
            if (t + 12 <= deg) s3 = rowsB[base + t + 11];
            if (t + 16 <= deg) s4 = rowsB[base + t + 15];
            if (t + 20 <= deg) s5 = rowsB[base + t + 19];
            while (s0 >= 0) {
                uint2 hv0 = *(const uint2*)(hWb + (size_t)s0 * SHD + h * 4);
                bool b1 = (s1 >= 0), b2 = (s2 >= 0), b3 = (s3 >= 0),
                     b4 = (s4 >= 0), b5 = (s5 >= 0);
                uint2 hv1, hv2, hv3, hv4, hv5;
                if (b1) hv1 = *(const uint2*)(hWb + (size_t)s1 * SHD + h * 4);
                if (b2) hv2 = *(const uint2*)(hWb + (size_t)s2 * SHD + h * 4);
                if (b3) hv3 = *(const uint2*)(hWb + (size_t)s3 * SHD + h * 4);
                if (b4) hv4 = *(const uint2*)(hWb + (size_t)s4 * SHD + h * 4);
                if (b5) hv5 = *(const uint2*)(hWb + (size_t)s5 * SHD + h * 4);
                int tn = t + 24;
                int p0 = -1, p1 = -1, p2 = -1, p3 = -1, p4 = -1, p5 = -1;
                if (tn <= deg)      p0 = rowsB[base + tn - 1];
                if (tn + 4 <= deg)  p1 = rowsB[base + tn + 3];
                if (tn + 8 <= deg)  p2 = rowsB[base + tn + 7];
                if (tn + 12 <= deg) p3 = rowsB[base + tn + 11];
                if (tn + 16 <= deg) p4 = rowsB[base + tn + 15];
                if (tn + 20 <= deg) p5 = rowsB[base + tn + 19];
                {
                    f32x2 h01, h23;
                    h01.x = __uint_as_float(hv0.x << 16);
                    h01.y = __uint_as_float(hv0.x & 0xffff0000u);
                    h23.x = __uint_as_float(hv0.y << 16);
                    h23.y = __uint_as_float(hv0.y & 0xffff0000u);
                    f32x2 d2 = h01 * (f32x2){asv.x, asv.y} + h23 * (f32x2){asv.z, asv.w};
                    float e = d2.x + d2.y + ednh;
                    e = fmaxf(e, 0.2f * e);
                    float a = __expf(e);
                    den += a;
                    f32x2 av = {a, a};
                    acc01 += av * h01;
                    acc23 += av * h23;
                }
                if (b1) {
                    f32x2 h01, h23;
                    h01.x = __uint_as_float(hv1.x << 16);
                    h01.y = __uint_as_float(hv1.x & 0xffff0000u);
                    h23.x = __uint_as_float(hv1.y << 16);
                    h23.y = __uint_as_float(hv1.y & 0xffff0000u);
                    f32x2 d2 = h01 * (f32x2){asv.x, asv.y} + h23 * (f32x2){asv.z, asv.w};
                    float e = d2.x + d2.y + ednh;
                    e = fmaxf(e, 0.2f * e);
                    float a = __expf(e);
                    den += a;
                    f32x2 av = {a, a};
                    acc01 += av * h01;
                    acc23 += av * h23;
                }
                if (b2) {
                    f32x2 h01, h23;
                    h01.x = __uint_as_float(hv2.x << 16);
                    h01.y = __uint_as_float(hv2.x & 0xffff0000u);
                    h23.x = __uint_as_float(hv2.y << 16);
                    h23.y = __uint_as_float(hv2.y & 0xffff0000u);
                    f32x2 d2 = h01 * (f32x2){asv.x, asv.y} + h23 * (f32x2){asv.z, asv.w};
                    float e = d2.x + d2.y + ednh;
                    e = fmaxf(e, 0.2f * e);
                    float a = __expf(e);
                    den += a;
                    f32x2 av = {a, a};
                    acc01 += av * h01;
                    acc23 += av * h23;
                }
                if (b3) {
                    f32x2 h01, h23;
                    h01.x = __uint_as_float(hv3.x << 16);
                    h01.y = __uint_as_float(hv3.x & 0xffff0000u);
                    h23.x = __uint_as_float(hv3.y << 16);
                    h23.y = __uint_as_float(hv3.y & 0xffff0000u);
                    f32x2 d2 = h01 * (f32x2){asv.x, asv.y} + h23 * (f32x2){asv.z, asv.w};
                    float e = d2.x + d2.y + ednh;
                    e = fmaxf(e, 0.2f * e);
                    float a = __expf(e);
                    den += a;
                    f32x2 av = {a, a};
                    acc01 += av * h01;
                    acc23 += av * h23;
                }
                if (b4) {
                    f32x2 h01, h23;
                    h01.x = __uint_as_float(hv4.x << 16);
                    h01.y = __uint_as_float(hv4.x & 0xffff0000u);
                    h23.x = __uint_as_float(hv4.y << 16);
                    h23.y = __uint_as_float(hv4.y & 0xffff0000u);
                    f32x2 d2 = h01 * (f32x2){asv.x, asv.y} + h23 * (f32x2){asv.z, asv.w};
                    float e = d2.x + d2.y + ednh;
                    e = fmaxf(e, 0.2f * e);
                    float a = __expf(e);
                    den += a;
                    f32x2 av = {a, a};
                    acc01 += av * h01;
                    acc23 += av * h23;
                }
                if (b5) {
                    f32x2 h01, h23;
                    h01.x = __uint_as_float(hv5.x << 16);
                    h01.y = __uint_as_float(hv5.x & 0xffff0000u);
                    h23.x = __uint_as_float(hv5.y << 16);
                    h23.y = __uint_as_float(hv5.y & 0xffff0000u);
                    f32x2 d2 = h01 * (f32x2){asv.x, asv.y} + h23 * (f32x2){asv.z, asv.w};
                    float e = d2.x + d2.y + ednh;
                    e = fmaxf(e, 0.2f * e);
                    float a = __expf(e);
                    den += a;
                    f32x2 av = {a, a};
                    acc01 += av * h01;
                    acc23 += av * h23;
                }
                s0 = p0; s1 = p1; s2 = p2; s3 = p3; s4 = p4; s5 = p5; t = tn;
            }
            for (int off = 16; off >= 8; off >>= 1) {
                den      += __shfl_down(den, off, 32);
                acc01.x  += __shfl_down(acc01.x, off, 32);
                acc01.y  += __shfl_down(acc01.y, off, 32);
                acc23.x  += __shfl_down(acc23.x, off, 32);
                acc23.y  += __shfl_down(acc23.y, off, 32);
            }
            if (k == 0) {
                float inv = 1.f / (den + 1e-16f);
                float4 bv = *(const float4*)(prm3 + 32 + h * 4);
                float v0 = acc01.x * inv + bv.x;
                float v1 = acc01.y * inv + bv.y;
                float v2 = acc23.x * inv + bv.z;
                float v3 = acc23.y * inv + bv.w;
                v0 = (v0 > 0.f) ? v0 : expm1f(v0);
                v1 = (v1 > 0.f) ? v1 : expm1f(v1);
                v2 = (v2 > 0.f) ? v2 : expm1f(v2);
                v3 = (v3 > 0.f) ? v3 : expm1f(v3);
                *(float4*)(&comb[h * 4]) = make_float4(v0, v1, v2, v3);
            }
        }
    }
    __syncthreads();

    if (tid < 96)
        gf[tid] = comb[tid] * sigm(matvec(pg_W, comb, sbias[tid], 97, tid, 96, f));
    __syncthreads();
    if (tid < 64)
        h1v[tid] = matvec(f1_W, gf, sbias[96 + tid], 96, tid, 64, f);
    __syncthreads();
    if (tid == 0) {
        float mu = 0.f;
        for (int j = 0; j < 64; j++) mu += h1v[j];
        mu /= 64.f;
        float var = 0.f;
        for (int j = 0; j < 64; j++) { float d = h1v[j] - mu; var += d * d; }
        var /= 64.f;
        stats[0] = mu; stats[1] = rsqrtf(var + 1e-5f);
    }
    __syncthreads();
    if (tid < 64)
        h1v[tid] = relu_nan((h1v[tid] - stats[0]) * stats[1] * sbias[208 + tid] + sbias[272 + tid]);
    __syncthreads();
    if (tid < 32)
        h2s[tid] = relu_nan(matvec(f2_W, h1v, sbias[160 + tid], 64, tid, 32, f));
    __syncthreads();
    if (tid < SEQL) {
        float acc = matvec(f3_W, h2s, sbias[192 + tid], 32, tid, 14, f);
        if (acc != acc) acc = 3333.0f;
        if (f) ((float*)out)[tid] = acc;
        else   ((bf16*)out)[tid] = __float2bfloat16(acc);
    }
}

// ---------------- host helpers ----------------
static inline unsigned short h_f2bf(float f) {
    union { float f; unsigned u; } x; x.f = f;
    return (unsigned short)(x.u >> 16);
}
static unsigned short g_diag[SEQL];

// ---------------- launch ----------------
extern "C" void kernel_launch(void* const* d_in, const int* in_sizes, int n_in,
                              void* d_out, int out_size, void* d_ws, size_t ws_size,
                              hipStream_t stream) {
    const int* ei  = (const int*)d_in[1];
    const int* tgt = (const int*)d_in[6];

    const size_t HWB  = sizeof(unsigned short) * (size_t)NN * SHD;
    const size_t EDB  = sizeof(float) * (size_t)NN * NH;
    const size_t AB   = sizeof(float) * (size_t)NN * SHD;
    // zeroed region: cnts(16) + bm1,bm2 (2*NBWP) + fillB,fillC (2N)
    const size_t ZER  = sizeof(int) * (size_t)(16 + 2 * NBWP + 2 * NN);
    const size_t ROWB = sizeof(int) * (size_t)NN * RSTR;   // x2 (B and C)
    const size_t LSTB = sizeof(int) * (size_t)(ECL1 + ECL2);
    const size_t NEED = 256 + 1024 + ZER + LSTB + 2 * ROWB + 512 + HWB + EDB + AB;
    if (ws_size < NEED) {
        for (int i = 0; i < SEQL; i++) g_diag[i] = h_f2bf(7777.0f);
        hipMemcpyAsync(d_out, g_diag, SEQL * sizeof(unsigned short),
                       hipMemcpyHostToDevice, stream);
        return;
    }

    char* p = (char*)d_ws;
    int*   flag = (int*)p;   p += 256;
    float* prm  = (float*)p; p += 1024;
    int* cnts  = (int*)p; p += sizeof(int) * 16;   // c1, c2
    unsigned* bm1 = (unsigned*)p; p += sizeof(int) * NBWP;
    unsigned* bm2 = (unsigned*)p; p += sizeof(int) * NBWP;
    int* fillB = (int*)p; p += sizeof(int) * NN;
    int* fillC = (int*)p; p += sizeof(int) * NN;
    int* l1   = (int*)p; p += sizeof(int) * ECL1;
    int* l2   = (int*)p; p += sizeof(int) * ECL2;
    int* rowsB = (int*)p; p += ROWB;
    int* rowsC = (int*)p; p += ROWB;
    p = (char*)(((uintptr_t)p + 255) & ~(uintptr_t)255);
    unsigned short* hWb = (unsigned short*)p; p += HWB;
    float* ed = (float*)p; p += EDB;
    float* A  = (float*)p; p += AB;
    int* c1 = cnts; int* c2 = cnts + 1;

    dim3 b256(256);
    dim3 gN((NN + 255) / 256);
    dim3 gScan(NBC2);

    PatternAwareSTGAT_94489281309_kernel<<<dim3(1), dim3(64), 0, stream>>>(
        (const unsigned int*)d_in[0], flag,
        d_in[8], d_in[10], d_in[12], d_in[14], d_in[16], d_in[18], prm);

    hipMemsetAsync(cnts, 0, ZER, stream);

    // frontier build: 3 fused scans
    k_scanA<<<gScan, b256, 0, stream>>>(ei, tgt, bm1, l1, c1, bm2, l2, c2);
    k_scanR<<<gScan, b256, 0, stream>>>(ei, bm1, fillB, rowsB,
                                        bm2, l2, c2, ECL2);
    k_scanR<<<gScan, b256, 0, stream>>>(ei, bm2, fillC, rowsC,
                                        (unsigned*)nullptr, (int*)nullptr,
                                        (int*)nullptr, 0);

    // GAT layers over the dependency cone (layer-3 agg fused into k_tail)
    k_transform0<<<gN, b256, 0, stream>>>(d_in[0], d_in[7], d_in[9], flag, hWb, ed);
    k_aggregate<<<dim3(ECL2 * 32 / 256), b256, 0, stream>>>(l2, c2, ECL2,
        fillC, rowsC, hWb, ed, prm, A);
    k_transform1<<<dim3(ECL2 / 256), b256, 0, stream>>>(l2, c2, ECL2,
        A, d_in[11], d_in[13], flag, hWb, ed);
    k_aggregate<<<dim3(ECL1 * 32 / 256), b256, 0, stream>>>(l1, c1, ECL1,
        fillB, rowsB, hWb, ed, prm + 64, A);
    k_transform1<<<dim3((ECL1 + 255) / 256), b256, 0, stream>>>(l1, c1, ECL1,
        A, d_in[15], d_in[17], flag, hWb, ed);

    k_tail<<<dim3(1), b256, 0, stream>>>(
        d_in[2], d_in[3], d_in[4], d_in[5], tgt,
        d_in[19], d_in[20], d_in[21], d_in[22],
        d_in[23], d_in[24], d_in[25], d_in[26],
        d_in[27], d_in[28], d_in[29], d_in[30],
        d_in[31], d_in[32], d_in[33], d_in[34],
        d_in[35], d_in[36],
        d_in[37], d_in[38],
        d_in[39], d_in[40],
        d_in[41], d_in[42],
        d_in[43], d_in[44],
        d_in[45], d_in[46],
        flag, rowsB, fillB, hWb, ed, prm + 128, d_out);
}